// Round 6
// baseline (41238.989 us; speedup 1.0000x reference)
//
#include <hip/hip_runtime.h>

typedef unsigned short u16;

__device__ __forceinline__ float b2f(u16 h){ return __uint_as_float(((unsigned)h)<<16); }
__device__ __forceinline__ float ldx(const void* p, size_t i, int isf){
  return isf ? ((const float*)p)[i] : b2f(((const u16*)p)[i]);
}

// ---------- dtype probe: flag[0]=1 if float inputs are f32, 0 if bf16 ----------
__global__ __launch_bounds__(256) void k_probe_f(const u16* __restrict__ p, int* __restrict__ flag){
  __shared__ int red[256];
  const int tid = threadIdx.x;
  int diff = 0;
  for (int i=tid; i<4096; i+=256){
    float lo = b2f(p[2*i]), hi = b2f(p[2*i+1]);
    float alo = fabsf(lo), ahi = fabsf(hi);
    int bad_lo = (alo==0.f || (alo>=1e-20f && alo<=1e20f)) ? 0 : 1;
    int bad_hi = (ahi==0.f || (ahi>=1e-20f && ahi<=1e20f)) ? 0 : 1;
    diff += bad_lo - bad_hi;
  }
  red[tid]=diff; __syncthreads();
  for (int s=128;s>0;s>>=1){ if(tid<s) red[tid]+=red[tid+s]; __syncthreads(); }
  if (tid==0) flag[0] = (red[0] > 1024) ? 1 : 0;
}

// ---------- edge-index width probe: flag[1]=1 if int64, 0 if int32 ----------
__global__ __launch_bounds__(256) void k_probe_ei(const unsigned* __restrict__ p, int* __restrict__ flag){
  __shared__ int red[256];
  const int tid = threadIdx.x;
  int nz = 0;
  for (int i=tid; i<4096; i+=256) nz += (p[2*i+1] != 0u) ? 1 : 0;
  red[tid]=nz; __syncthreads();
  for (int s=128;s>0;s>>=1){ if(tid<s) red[tid]+=red[tid+s]; __syncthreads(); }
  if (tid==0) flag[1] = (red[0] < 64) ? 1 : 0;
}

// ---------- edge-index canonicalization to int32 (clamped) ----------
__global__ __launch_bounds__(256) void k_cvt_ei(const void* __restrict__ p, int* __restrict__ ei32,
                                                int n2E, int N, const int* __restrict__ flag){
  int i = blockIdx.x*256 + threadIdx.x;
  if (i>=n2E) return;
  long long v = flag[1] ? ((const long long*)p)[i] : (long long)((const int*)p)[i];
  int x = (int)v;
  if (x < 0) x = 0;
  if (x >= N) x = N-1;
  ei32[i] = x;
}

// ---------- per-dst incoming-degree count ----------
__global__ __launch_bounds__(256) void k_cnt(const int* __restrict__ ei32, int E,
                                             float* __restrict__ cnt, int eb, int ec){
  int t = blockIdx.x*256 + threadIdx.x;
  if (t>=ec) return;
  atomicAdd(&cnt[ei32[(size_t)E+eb+t]], 1.f);
}

// ---------- GVP0 vector half: vh[le][d][h] (stride 65), vn[le][h]; h<65 ----------
__global__ __launch_bounds__(256) void k_evh0(
    const void* __restrict__ node_v, const void* __restrict__ edge_v,
    const int* __restrict__ ei32, int E, const void* __restrict__ wh,
    float* __restrict__ vh, float* __restrict__ vn,
    const int* __restrict__ flag, int eb, int ec)
{
  int t = blockIdx.x*256 + threadIdx.x;
  int le = t/65, h = t - le*65;
  if (le>=ec) return;
  const int isf = *flag;
  int ge = eb+le, src = ei32[ge], dst = ei32[(size_t)E+ge];
  float a0=0.f,a1=0.f,a2=0.f;
  for (int i=0;i<32;++i){
    float w = ldx(wh, (size_t)h*65+i, isf);
    a0 += ldx(node_v, (size_t)src*96+i*3+0, isf)*w;
    a1 += ldx(node_v, (size_t)src*96+i*3+1, isf)*w;
    a2 += ldx(node_v, (size_t)src*96+i*3+2, isf)*w;
  }
  {
    float w = ldx(wh, (size_t)h*65+32, isf);
    a0 += ldx(edge_v, (size_t)ge*3+0, isf)*w;
    a1 += ldx(edge_v, (size_t)ge*3+1, isf)*w;
    a2 += ldx(edge_v, (size_t)ge*3+2, isf)*w;
  }
  for (int i=0;i<32;++i){
    float w = ldx(wh, (size_t)h*65+33+i, isf);
    a0 += ldx(node_v, (size_t)dst*96+i*3+0, isf)*w;
    a1 += ldx(node_v, (size_t)dst*96+i*3+1, isf)*w;
    a2 += ldx(node_v, (size_t)dst*96+i*3+2, isf)*w;
  }
  vh[((size_t)le*3+0)*65+h]=a0;
  vh[((size_t)le*3+1)*65+h]=a1;
  vh[((size_t)le*3+2)*65+h]=a2;
  vn[(size_t)le*65+h] = sqrtf(fmaxf(a0*a0+a1*a1+a2*a2, 1e-8f));
}

// ---------- GVP0 scalar: sout[le][o<128] = relu(b + ms.W[o,:288] + vn.W[o,288:353]) ----------
__global__ __launch_bounds__(256) void k_es0(
    const void* __restrict__ node_s, const void* __restrict__ edge_s,
    const int* __restrict__ ei32, int E,
    const void* __restrict__ w, const void* __restrict__ bias,
    const float* __restrict__ vn, float* __restrict__ sout,
    const int* __restrict__ flag, int eb, int ec)
{
  int t = blockIdx.x*256 + threadIdx.x;
  int le = t>>7, o = t&127;
  if (le>=ec) return;
  const int isf = *flag;
  int ge = eb+le, src = ei32[ge], dst = ei32[(size_t)E+ge];
  float acc = ldx(bias, o, isf);
  const size_t wr = (size_t)o*353;
  for (int k=0;k<128;++k) acc += ldx(node_s,(size_t)src*128+k,isf)*ldx(w,wr+k,isf);
  for (int k=0;k<32;++k)  acc += ldx(edge_s,(size_t)ge*32+k,isf)*ldx(w,wr+128+k,isf);
  for (int k=0;k<128;++k) acc += ldx(node_s,(size_t)dst*128+k,isf)*ldx(w,wr+160+k,isf);
  for (int h=0;h<65;++h)  acc += vn[(size_t)le*65+h]*ldx(w,wr+288+h,isf);
  sout[(size_t)le*128+o] = fmaxf(acc, 0.f);
}

// ---------- generic edge vector half: vprev [EC][96] d-major, wh [32][32] ----------
__global__ __launch_bounds__(256) void k_evh(
    const float* __restrict__ vprev, const void* __restrict__ wh,
    float* __restrict__ vh, float* __restrict__ vn,
    const int* __restrict__ flag, int ec)
{
  int t = blockIdx.x*256 + threadIdx.x;
  int le = t>>5, h = t&31;
  if (le>=ec) return;
  const int isf = *flag;
  float a0=0.f,a1=0.f,a2=0.f;
  for (int i=0;i<32;++i){
    float w = ldx(wh,(size_t)h*32+i,isf);
    a0 += vprev[(size_t)le*96+i]*w;
    a1 += vprev[(size_t)le*96+32+i]*w;
    a2 += vprev[(size_t)le*96+64+i]*w;
  }
  vh[((size_t)le*3+0)*65+h]=a0;
  vh[((size_t)le*3+1)*65+h]=a1;
  vh[((size_t)le*3+2)*65+h]=a2;
  vn[(size_t)le*65+h] = sqrtf(fmaxf(a0*a0+a1*a1+a2*a2, 1e-8f));
}

// ---------- generic edge scalar: w [128][160] ----------
__global__ __launch_bounds__(256) void k_es(
    const float* __restrict__ sprev, const float* __restrict__ vn,
    const void* __restrict__ w, const void* __restrict__ bias,
    const int* __restrict__ ei32, int E,
    float* __restrict__ sout, float* __restrict__ agg_s,
    const int* __restrict__ flag, int eb, int ec, int RELU, int ATOMIC)
{
  int t = blockIdx.x*256 + threadIdx.x;
  int le = t>>7, o = t&127;
  if (le>=ec) return;
  const int isf = *flag;
  float acc = ldx(bias, o, isf);
  const size_t wr = (size_t)o*160;
  for (int k=0;k<128;++k) acc += sprev[(size_t)le*128+k]*ldx(w,wr+k,isf);
  for (int h=0;h<32;++h)  acc += vn[(size_t)le*65+h]*ldx(w,wr+128+h,isf);
  if (RELU) acc = fmaxf(acc, 0.f);
  if (ATOMIC) atomicAdd(&agg_s[(size_t)ei32[(size_t)E+eb+le]*128+o], acc);
  else sout[(size_t)le*128+o] = acc;
}

// ---------- edge vector out: vh stride 65 (H used), wv [32][H] ----------
__global__ __launch_bounds__(256) void k_evv(
    const float* __restrict__ vh, const void* __restrict__ wv,
    const int* __restrict__ ei32, int E,
    float* __restrict__ vout, float* __restrict__ agg_v,
    const int* __restrict__ flag, int eb, int ec, int H, int ACTS, int ATOMIC)
{
  int t = blockIdx.x*256 + threadIdx.x;
  int le = t>>5, vo = t&31;
  if (le>=ec) return;
  const int isf = *flag;
  float x0=0.f,x1=0.f,x2=0.f;
  for (int h=0;h<H;++h){
    float w = ldx(wv,(size_t)vo*H+h,isf);
    x0 += vh[((size_t)le*3+0)*65+h]*w;
    x1 += vh[((size_t)le*3+1)*65+h]*w;
    x2 += vh[((size_t)le*3+2)*65+h]*w;
  }
  if (ACTS){
    float nn = sqrtf(fmaxf(x0*x0+x1*x1+x2*x2, 1e-8f));
    float sg = 1.f/(1.f + __expf(-nn));
    x0*=sg; x1*=sg; x2*=sg;
  }
  if (ATOMIC){
    int dn = ei32[(size_t)E+eb+le];
    atomicAdd(&agg_v[(size_t)dn*96+vo*3+0], x0);
    atomicAdd(&agg_v[(size_t)dn*96+vo*3+1], x1);
    atomicAdd(&agg_v[(size_t)dn*96+vo*3+2], x2);
  } else {
    vout[(size_t)le*96+vo]      = x0;
    vout[(size_t)le*96+32+vo]   = x1;
    vout[(size_t)le*96+64+vo]   = x2;
  }
}

// ---------- residual + tuple LayerNorm after aggregation (per node) ----------
__global__ __launch_bounds__(256) void k_ln0(
    const void* __restrict__ node_s, const void* __restrict__ node_v,
    const float* __restrict__ agg_s, const float* __restrict__ agg_v,
    const float* __restrict__ cnt,
    const void* __restrict__ g, const void* __restrict__ b,
    float* __restrict__ s_mid, float* __restrict__ v_mid,
    const int* __restrict__ flag, int N)
{
  int n = blockIdx.x*256 + threadIdx.x;
  if (n>=N) return;
  const int isf = *flag;
  const float inv = 1.f/fmaxf(cnt[n], 1.f);
  float sum=0.f, ss=0.f;
  for (int i=0;i<128;++i){
    float x = ldx(node_s,(size_t)n*128+i,isf) + agg_s[(size_t)n*128+i]*inv;
    sum += x; ss += x*x;
  }
  const float mu = sum*(1.f/128.f);
  const float var = fmaxf(ss*(1.f/128.f) - mu*mu, 0.f);
  const float rstd = rsqrtf(var + 1e-5f);
  for (int i=0;i<128;++i){
    float x = ldx(node_s,(size_t)n*128+i,isf) + agg_s[(size_t)n*128+i]*inv;
    s_mid[(size_t)n*128+i] = (x-mu)*rstd*ldx(g,i,isf) + ldx(b,i,isf);
  }
  float vs=0.f;
  for (int vo=0;vo<32;++vo){
    float y0 = ldx(node_v,(size_t)n*96+vo*3+0,isf) + agg_v[(size_t)n*96+vo*3+0]*inv;
    float y1 = ldx(node_v,(size_t)n*96+vo*3+1,isf) + agg_v[(size_t)n*96+vo*3+1]*inv;
    float y2 = ldx(node_v,(size_t)n*96+vo*3+2,isf) + agg_v[(size_t)n*96+vo*3+2]*inv;
    vs += fmaxf(y0*y0+y1*y1+y2*y2, 1e-8f);
  }
  const float scale = rsqrtf(vs*(1.f/32.f));
  for (int vo=0;vo<32;++vo){
    float y0 = ldx(node_v,(size_t)n*96+vo*3+0,isf) + agg_v[(size_t)n*96+vo*3+0]*inv;
    float y1 = ldx(node_v,(size_t)n*96+vo*3+1,isf) + agg_v[(size_t)n*96+vo*3+1]*inv;
    float y2 = ldx(node_v,(size_t)n*96+vo*3+2,isf) + agg_v[(size_t)n*96+vo*3+2]*inv;
    v_mid[(size_t)n*96+vo]      = y0*scale;
    v_mid[(size_t)n*96+32+vo]   = y1*scale;
    v_mid[(size_t)n*96+64+vo]   = y2*scale;
  }
}

// ---------- node vector half (chunk-local): vsrc [nc][3*IN] d-major, wh [H][IN] ----------
__global__ __launch_bounds__(256) void k_fvh(
    const float* __restrict__ vsrc, const void* __restrict__ wh,
    float* __restrict__ vh, float* __restrict__ vn,
    const int* __restrict__ flag, int nc, int IN, int H)
{
  int t = blockIdx.x*256 + threadIdx.x;
  int n = t/H, h = t - n*H;
  if (n>=nc) return;
  const int isf = *flag;
  float a0=0.f,a1=0.f,a2=0.f;
  for (int i=0;i<IN;++i){
    float w = ldx(wh,(size_t)h*IN+i,isf);
    a0 += vsrc[(size_t)n*3*IN + i]*w;
    a1 += vsrc[(size_t)n*3*IN + IN + i]*w;
    a2 += vsrc[(size_t)n*3*IN + 2*IN + i]*w;
  }
  vh[(size_t)n*3*H + h]       = a0;
  vh[(size_t)n*3*H + H + h]   = a1;
  vh[(size_t)n*3*H + 2*H + h] = a2;
  vn[(size_t)n*H + h] = sqrtf(fmaxf(a0*a0+a1*a1+a2*a2, 1e-8f));
}

// ---------- node scalar (chunk-local) ----------
__global__ __launch_bounds__(256) void k_fs(
    const float* __restrict__ s1, const float* __restrict__ vn,
    const void* __restrict__ w, const void* __restrict__ bias,
    float* __restrict__ out, const int* __restrict__ flag,
    int nc, int K1, int K2, int O, int RELU)
{
  int t = blockIdx.x*256 + threadIdx.x;
  int n = t/O, o = t - n*O;
  if (n>=nc) return;
  const int isf = *flag;
  float acc = ldx(bias, o, isf);
  const size_t wr = (size_t)o*(K1+K2);
  for (int k=0;k<K1;++k) acc += s1[(size_t)n*K1+k]*ldx(w,wr+k,isf);
  for (int h=0;h<K2;++h) acc += vn[(size_t)n*K2+h]*ldx(w,wr+K1+h,isf);
  if (RELU) acc = fmaxf(acc, 0.f);
  out[(size_t)n*O+o] = acc;
}

// ---------- node vector out (chunk-local) ----------
__global__ __launch_bounds__(256) void k_fvv(
    const float* __restrict__ vh, const void* __restrict__ wv,
    float* __restrict__ out, const int* __restrict__ flag,
    int nc, int H, int VO, int ACTS)
{
  int t = blockIdx.x*256 + threadIdx.x;
  int n = t/VO, vo = t - n*VO;
  if (n>=nc) return;
  const int isf = *flag;
  float x0=0.f,x1=0.f,x2=0.f;
  for (int h=0;h<H;++h){
    float w = ldx(wv,(size_t)vo*H+h,isf);
    x0 += vh[(size_t)n*3*H + h]*w;
    x1 += vh[(size_t)n*3*H + H + h]*w;
    x2 += vh[(size_t)n*3*H + 2*H + h]*w;
  }
  if (ACTS){
    float nn = sqrtf(fmaxf(x0*x0+x1*x1+x2*x2, 1e-8f));
    float sg = 1.f/(1.f + __expf(-nn));
    x0*=sg; x1*=sg; x2*=sg;
  }
  out[(size_t)n*3*VO + vo]        = x0;
  out[(size_t)n*3*VO + VO + vo]   = x1;
  out[(size_t)n*3*VO + 2*VO + vo] = x2;
}

// ---------- final residual + tuple LayerNorm -> FLOAT32 out (chunk: nodes nb..nb+nc) ----------
__global__ __launch_bounds__(256) void k_ln1(
    const float* __restrict__ s1, const float* __restrict__ fs1,
    const float* __restrict__ v1, const float* __restrict__ fv1,
    const void* __restrict__ g, const void* __restrict__ b,
    float* __restrict__ out, const int* __restrict__ flag, int nb, int nc, int N)
{
  int ln = blockIdx.x*256 + threadIdx.x;
  if (ln>=nc) return;
  const int isf = *flag;
  const int n = nb + ln;
  float sum=0.f, ss=0.f;
  for (int i=0;i<128;++i){
    float x = s1[(size_t)ln*128+i] + fs1[(size_t)ln*128+i];
    sum += x; ss += x*x;
  }
  const float mu = sum*(1.f/128.f);
  const float var = fmaxf(ss*(1.f/128.f) - mu*mu, 0.f);
  const float rstd = rsqrtf(var + 1e-5f);
  for (int i=0;i<128;++i){
    float x = s1[(size_t)ln*128+i] + fs1[(size_t)ln*128+i];
    out[(size_t)n*128+i] = (x-mu)*rstd*ldx(g,i,isf) + ldx(b,i,isf);
  }
  float vs=0.f;
  for (int vo=0;vo<32;++vo){
    float y0 = v1[(size_t)ln*96+vo]    + fv1[(size_t)ln*96+vo];
    float y1 = v1[(size_t)ln*96+32+vo] + fv1[(size_t)ln*96+32+vo];
    float y2 = v1[(size_t)ln*96+64+vo] + fv1[(size_t)ln*96+64+vo];
    vs += fmaxf(y0*y0+y1*y1+y2*y2, 1e-8f);
  }
  const float scale = rsqrtf(vs*(1.f/32.f));
  const size_t base = (size_t)N*128 + (size_t)n*96;
  for (int vo=0;vo<32;++vo){
    float y0 = v1[(size_t)ln*96+vo]    + fv1[(size_t)ln*96+vo];
    float y1 = v1[(size_t)ln*96+32+vo] + fv1[(size_t)ln*96+32+vo];
    float y2 = v1[(size_t)ln*96+64+vo] + fv1[(size_t)ln*96+64+vo];
    out[base + vo*3 + 0] = y0*scale;   // output v layout [N][32][3], f32
    out[base + vo*3 + 1] = y1*scale;
    out[base + vo*3 + 2] = y2*scale;
  }
}

extern "C" void kernel_launch(void* const* d_in, const int* in_sizes, int n_in,
                              void* d_out, int out_size, void* d_ws, size_t ws_size,
                              hipStream_t stream)
{
  (void)n_in; (void)out_size;
  // ---- input-order detection: dict order vs alphabetical, via size signatures ----
  int IX[29]; for (int i=0;i<29;++i) IX[i]=i;
  {
    bool dict_ok = false, alpha_ok = false;
    if (in_sizes[0]%128==0 && in_sizes[4]%2==0){
      long N_ = in_sizes[0]/128, E_ = in_sizes[4]/2;
      dict_ok = (in_sizes[1]==96*N_) && (in_sizes[2]==32*E_) && (in_sizes[3]==3*E_)
             && (in_sizes[5]==4225) && (in_sizes[6]==45184)
             && (in_sizes[20]==98304) && (in_sizes[24]==73728);
    }
    if (!dict_ok && in_sizes[27]%128==0 && in_sizes[0]%2==0){
      long N_ = in_sizes[27]/128, E_ = in_sizes[0]/2;
      alpha_ok = (in_sizes[28]==96*N_) && (in_sizes[1]==32*E_) && (in_sizes[2]==3*E_)
              && (in_sizes[15]==4225) && (in_sizes[17]==45184)
              && (in_sizes[5]==98304) && (in_sizes[9]==73728);
    }
    if (!dict_ok && alpha_ok){
      const int ALT[29] = {27,28,1,2,0, 15,17,16,18, 19,21,20,22, 23,25,24,26,
                           12,11, 3,5,4,6, 7,9,8,10, 14,13};
      for (int i=0;i<29;++i) IX[i]=ALT[i];
    }
  }
  auto IN = [&](int i)->const void*{ return d_in[IX[i]]; };
  const int N = in_sizes[IX[0]]/128;
  const int E = in_sizes[IX[4]]/2;

  size_t off = 0;
  auto alloc = [&](size_t bytes)->char*{
    size_t o = (off + 255) & ~(size_t)255;
    off = o + bytes;
    return (char*)d_ws + o;
  };
  // persistent (~20 MB)
  int*   flags = (int*)alloc(256);
  float* agg_s = (float*)alloc((size_t)N*128*4);
  float* agg_v = (float*)alloc((size_t)N*96*4);
  float* cnt   = (float*)alloc((size_t)N*4);
  size_t aggBytes = (size_t)((char*)(cnt+N) - (char*)agg_s);
  float* s_mid = (float*)alloc((size_t)N*128*4);
  float* v_mid = (float*)alloc((size_t)N*96*4);
  int*   ei32  = (int*)alloc((size_t)2*E*4);
  const size_t persist_end = off;

  // chunk sizing within ws_size
  const size_t perEdge = (size_t)(195+65+128+128+96+96)*4;   // 2832 B
  const size_t perNode = (size_t)(192+64+512+192+128+96)*4;  // 4736 B
  size_t avail = (ws_size > persist_end + (1u<<20)) ? (ws_size - persist_end - (1u<<20)) : 0;
  long NC = (long)((avail/4) / perNode);
  if (NC < 512) NC = 512;
  if (NC > N) NC = N;
  size_t edge_avail = (avail > (size_t)NC*perNode) ? (avail - (size_t)NC*perNode) : 0;
  long EC = (long)(edge_avail / perEdge);
  if (EC < 1024) EC = 1024;
  if (EC > E) EC = E;

  float* vhE = (float*)alloc((size_t)EC*195*4);
  float* vnE = (float*)alloc((size_t)EC*65*4);
  float* sA  = (float*)alloc((size_t)EC*128*4);
  float* sB  = (float*)alloc((size_t)EC*128*4);
  float* vA  = (float*)alloc((size_t)EC*96*4);
  float* vB  = (float*)alloc((size_t)EC*96*4);
  float* vhf = (float*)alloc((size_t)NC*192*4);
  float* vnf = (float*)alloc((size_t)NC*64*4);
  float* fs0 = (float*)alloc((size_t)NC*512*4);
  float* fv0 = (float*)alloc((size_t)NC*192*4);
  float* fs1 = (float*)alloc((size_t)NC*128*4);
  float* fv1 = (float*)alloc((size_t)NC*96*4);

  hipMemsetAsync(agg_s, 0, aggBytes, stream);
  k_probe_f<<<dim3(1), dim3(256), 0, stream>>>((const u16*)IN(0), flags);
  k_probe_ei<<<dim3(1), dim3(256), 0, stream>>>((const unsigned*)IN(4), flags);
  k_cvt_ei<<<dim3((2*E+255)/256), dim3(256), 0, stream>>>(IN(4), ei32, 2*E, N, flags);

  const int nchE = (int)((E + EC - 1)/EC);
  for (int c=0; c<nchE; ++c){
    const int eb = c*(int)EC;
    int ec = E - eb; if (ec > (int)EC) ec = (int)EC;
    if (ec <= 0) break;
    dim3 g65(((size_t)ec*65 + 255)/256);
    dim3 g128(((size_t)ec*128 + 255)/256);
    dim3 g32(((size_t)ec*32 + 255)/256);
    dim3 g1(((size_t)ec + 255)/256);
    // GVP0
    k_evh0<<<g65,256,0,stream>>>(IN(1), IN(3), ei32, E, IN(5), vhE, vnE, flags, eb, ec);
    k_es0<<<g128,256,0,stream>>>(IN(0), IN(2), ei32, E, IN(6), IN(7), vnE, sA, flags, eb, ec);
    k_evv<<<g32,256,0,stream>>>(vhE, IN(8), ei32, E, vA, (float*)nullptr, flags, eb, ec, 65, 1, 0);
    // GVP1
    k_evh<<<g32,256,0,stream>>>(vA, IN(9), vhE, vnE, flags, ec);
    k_es<<<g128,256,0,stream>>>(sA, vnE, IN(10), IN(11), ei32, E, sB, (float*)nullptr, flags, eb, ec, 1, 0);
    k_evv<<<g32,256,0,stream>>>(vhE, IN(12), ei32, E, vB, (float*)nullptr, flags, eb, ec, 32, 1, 0);
    // GVP2 (no acts) -> atomic mean-aggregation
    k_evh<<<g32,256,0,stream>>>(vB, IN(13), vhE, vnE, flags, ec);
    k_es<<<g128,256,0,stream>>>(sB, vnE, IN(14), IN(15), ei32, E, (float*)nullptr, agg_s, flags, eb, ec, 0, 1);
    k_evv<<<g32,256,0,stream>>>(vhE, IN(16), ei32, E, (float*)nullptr, agg_v, flags, eb, ec, 32, 0, 1);
    k_cnt<<<g1,256,0,stream>>>(ei32, E, cnt, eb, ec);
  }

  k_ln0<<<dim3(((size_t)N+255)/256),256,0,stream>>>(IN(0), IN(1), agg_s, agg_v, cnt,
      IN(17), IN(18), s_mid, v_mid, flags, N);

  const int nchN = (int)((N + NC - 1)/NC);
  for (int c=0; c<nchN; ++c){
    const int nb = c*(int)NC;
    int nc = N - nb; if (nc > (int)NC) nc = (int)NC;
    if (nc <= 0) break;
    // FF GVP0: v_mid(32) -> vh(64), vn(64); s: cat(s_mid 128, vn 64) @ ff0_wsw[512][192], relu+gate
    k_fvh<<<dim3(((size_t)nc*64+255)/256),256,0,stream>>>(v_mid + (size_t)nb*96, IN(19), vhf, vnf, flags, nc, 32, 64);
    k_fs<<<dim3(((size_t)nc*512+255)/256),256,0,stream>>>(s_mid + (size_t)nb*128, vnf, IN(20), IN(21), fs0, flags, nc, 128, 64, 512, 1);
    k_fvv<<<dim3(((size_t)nc*64+255)/256),256,0,stream>>>(vhf, IN(22), fv0, flags, nc, 64, 64, 1);
    // FF GVP1: fv0(64) -> vh(64), vn(64); s: cat(fs0 512, vn 64) @ ff1_wsw[128][576], no acts
    k_fvh<<<dim3(((size_t)nc*64+255)/256),256,0,stream>>>(fv0, IN(23), vhf, vnf, flags, nc, 64, 64);
    k_fs<<<dim3(((size_t)nc*128+255)/256),256,0,stream>>>(fs0, vnf, IN(24), IN(25), fs1, flags, nc, 512, 64, 128, 0);
    k_fvv<<<dim3(((size_t)nc*32+255)/256),256,0,stream>>>(vhf, IN(26), fv1, flags, nc, 64, 32, 0);
    k_ln1<<<dim3(((size_t)nc+255)/256),256,0,stream>>>(s_mid + (size_t)nb*128, fs1, v_mid + (size_t)nb*96, fv1,
        IN(27), IN(28), (float*)d_out, flags, nb, nc, N);
  }
}

// Round 7
// 3143.995 us; speedup vs baseline: 13.1167x; 13.1167x over previous
//
#include <hip/hip_runtime.h>

typedef unsigned short u16;

__device__ __forceinline__ float b2f(u16 h){ return __uint_as_float(((unsigned)h)<<16); }
__device__ __forceinline__ float ldx(const void* p, size_t i, int isf){
  return isf ? ((const float*)p)[i] : b2f(((const u16*)p)[i]);
}

// WT arena offsets (f32 elements)
#define O_WH0   0        // [65][66]  wh0_t[k*66+h]
#define O_WSW0  4290     // [353][128]
#define O_WV0   49474    // [65][32]
#define O_WH1   51554    // [32][32]
#define O_WSW1  52578    // [160][128]
#define O_WV1   73058    // [32][32]
#define O_WH2   74082    // [32][32]
#define O_WSW2  75106    // [160][128]
#define O_WV2   95586    // [32][32]
#define O_FF0H  96610    // [32][64]
#define O_FF0S  98658    // [192][512]
#define O_FF0V  196962   // [64][64]
#define O_FF1H  201058   // [64][64]
#define O_FF1S  205154   // [576][128]
#define O_FF1V  278882   // [64][32]
#define O_B0    280930
#define O_B1    281058
#define O_B2    281186
#define O_FB0   281314
#define O_FB1   281826
#define O_LN0G  281954
#define O_LN0B  282082
#define O_LN1G  282210
#define O_LN1B  282338
#define WT_TOTAL 282466

// ---------- dtype probe: flag[0]=1 if float inputs are f32 ----------
__global__ __launch_bounds__(256) void k_probe_f(const u16* __restrict__ p, int* __restrict__ flag){
  __shared__ int red[256];
  const int tid = threadIdx.x;
  int diff = 0;
  for (int i=tid; i<4096; i+=256){
    float lo = b2f(p[2*i]), hi = b2f(p[2*i+1]);
    float alo = fabsf(lo), ahi = fabsf(hi);
    int bad_lo = (alo==0.f || (alo>=1e-20f && alo<=1e20f)) ? 0 : 1;
    int bad_hi = (ahi==0.f || (ahi>=1e-20f && ahi<=1e20f)) ? 0 : 1;
    diff += bad_lo - bad_hi;
  }
  red[tid]=diff; __syncthreads();
  for (int s=128;s>0;s>>=1){ if(tid<s) red[tid]+=red[tid+s]; __syncthreads(); }
  if (tid==0) flag[0] = (red[0] > 1024) ? 1 : 0;
}

// ---------- edge-index width probe: flag[1]=1 if int64 ----------
__global__ __launch_bounds__(256) void k_probe_ei(const unsigned* __restrict__ p, int* __restrict__ flag){
  __shared__ int red[256];
  const int tid = threadIdx.x;
  int nz = 0;
  for (int i=tid; i<4096; i+=256) nz += (p[2*i+1] != 0u) ? 1 : 0;
  red[tid]=nz; __syncthreads();
  for (int s=128;s>0;s>>=1){ if(tid<s) red[tid]+=red[tid+s]; __syncthreads(); }
  if (tid==0) flag[1] = (red[0] < 64) ? 1 : 0;
}

__global__ __launch_bounds__(256) void k_cvt_ei(const void* __restrict__ p, int* __restrict__ ei32,
                                                int n2E, int N, const int* __restrict__ flag){
  int i = blockIdx.x*256 + threadIdx.x;
  if (i>=n2E) return;
  long long v = flag[1] ? ((const long long*)p)[i] : (long long)((const int*)p)[i];
  int x = (int)v;
  if (x < 0) x = 0;
  if (x >= N) x = N-1;
  ei32[i] = x;
}

// ---------- weight transpose into WT arena ----------
struct TJob { const void* src; int off, O, K, P; };
struct TJobs { TJob j[24]; int prefix[25]; };

__global__ __launch_bounds__(256) void k_transpose(TJobs J, float* __restrict__ WT,
                                                   const int* __restrict__ flag){
  int t = blockIdx.x*256 + threadIdx.x;
  if (t >= J.prefix[24]) return;
  const int isf = *flag;
  for (int i=0;i<24;i++){
    if (t < J.prefix[i+1]){
      TJob jb = J.j[i];
      int local = t - J.prefix[i];
      int k = local / jb.P, o = local - k*jb.P;
      float val = 0.f;
      if (o < jb.O) val = ldx(jb.src, (size_t)o*jb.K + k, isf);
      WT[jb.off + local] = val;
      return;
    }
  }
}

// ---------- fused 3-GVP edge message chain + atomic aggregation ----------
// 16 edges/block, 256 threads (16/edge).
#define EPB 16
__global__ __launch_bounds__(256) void k_edge_fused(
    const void* __restrict__ node_s, const void* __restrict__ node_v,
    const void* __restrict__ edge_s, const void* __restrict__ edge_v,
    const int* __restrict__ ei32, int E,
    const float* __restrict__ WT,
    float* __restrict__ agg_s, float* __restrict__ agg_v, float* __restrict__ cnt,
    const int* __restrict__ flag)
{
  __shared__ float AS[EPB][354];   // [0:128]=s_in/s_out, [128:160]=edge_s/vn1/vn2, [160:288]=s_dst, [288:353]=vn0
  __shared__ float VH[EPB*3][66];  // mv, then vh per stage
  __shared__ float VB[EPB*3][33];  // v between stages
  __shared__ int   SD[EPB][2];
  const int tid = threadIdx.x;
  const int e = tid>>4, p = tid&15;
  const int ge0 = blockIdx.x*EPB;
  const int isf = *flag;

  if (tid < EPB*2){
    int ee = tid>>1, which = tid&1;
    int g = ge0+ee;
    SD[ee][which] = (g<E) ? ei32[(size_t)which*E + g] : 0;
  }
  __syncthreads();

  // stage AS[0:288] = cat(s_src, edge_s, s_dst)
  for (int u=tid; u<EPB*288; u+=256){
    int ee = u/288, i = u - ee*288;
    int g = ge0+ee; float v = 0.f;
    if (g<E){
      if (i<128)      v = ldx(node_s, (size_t)SD[ee][0]*128 + i, isf);
      else if (i<160) v = ldx(edge_s, (size_t)g*32 + (i-128), isf);
      else            v = ldx(node_s, (size_t)SD[ee][1]*128 + (i-160), isf);
    }
    AS[ee][i] = v;
  }
  // stage mv (d-major) into VH: k<32 v_src, k=32 edge_v, 33..64 v_dst
  for (int u=tid; u<EPB*198; u+=256){
    int ee = u/198, r = u - ee*198, d = r/66, k = r - d*66;
    int g = ge0+ee; float v = 0.f;
    if (g<E && k<65){
      if (k<32)       v = ldx(node_v, (size_t)SD[ee][0]*96 + k*3 + d, isf);
      else if (k==32) v = ldx(edge_v, (size_t)g*3 + d, isf);
      else            v = ldx(node_v, (size_t)SD[ee][1]*96 + (k-33)*3 + d, isf);
    }
    VH[ee*3+d][k] = v;
  }
  __syncthreads();

  const int g = ge0 + e;
  const bool live = g < E;
  const int dst = SD[e][1];

  // ---- GVP0 vector half: vh0 = mv @ wh0^T (65x65), vn0 ----
  float a0[5], a1[5], a2[5];
  #pragma unroll
  for (int j=0;j<5;++j){ a0[j]=0.f; a1[j]=0.f; a2[j]=0.f; }
  for (int k=0;k<65;++k){
    float x0 = VH[e*3+0][k], x1 = VH[e*3+1][k], x2 = VH[e*3+2][k];
    const float* wr = WT + O_WH0 + k*66;
    #pragma unroll
    for (int j=0;j<5;++j){
      int h = p + 16*j;
      if (h < 65){ float w = wr[h]; a0[j]+=x0*w; a1[j]+=x1*w; a2[j]+=x2*w; }
    }
  }
  #pragma unroll
  for (int j=0;j<5;++j){
    int h = p + 16*j;
    if (h < 65) AS[e][288+h] = sqrtf(fmaxf(a0[j]*a0[j]+a1[j]*a1[j]+a2[j]*a2[j], 1e-8f));
  }
  __syncthreads();
  #pragma unroll
  for (int j=0;j<5;++j){
    int h = p + 16*j;
    if (h < 65){ VH[e*3+0][h]=a0[j]; VH[e*3+1][h]=a1[j]; VH[e*3+2][h]=a2[j]; }
  }
  __syncthreads();

  // ---- GVP0 scalar: s0 = relu(b0 + AS[0:353] @ wsw0_t), and v0 = gate(vh0 @ wv0^T) ----
  float s[8];
  #pragma unroll
  for (int j=0;j<8;++j) s[j] = WT[O_B0 + p + 16*j];
  for (int k=0;k<353;++k){
    float av = AS[e][k];
    const float* wr = WT + O_WSW0 + k*128 + p;
    #pragma unroll
    for (int j=0;j<8;++j) s[j] += av * wr[16*j];
  }
  #pragma unroll
  for (int j=0;j<8;++j) s[j] = fmaxf(s[j], 0.f);

  float v0[2][3];
  #pragma unroll
  for (int j=0;j<2;++j){ v0[j][0]=0.f; v0[j][1]=0.f; v0[j][2]=0.f; }
  for (int h=0;h<65;++h){
    float x0 = VH[e*3+0][h], x1 = VH[e*3+1][h], x2 = VH[e*3+2][h];
    const float* wr = WT + O_WV0 + h*32 + p;
    #pragma unroll
    for (int j=0;j<2;++j){ float w = wr[16*j]; v0[j][0]+=x0*w; v0[j][1]+=x1*w; v0[j][2]+=x2*w; }
  }
  #pragma unroll
  for (int j=0;j<2;++j){
    float nn = sqrtf(fmaxf(v0[j][0]*v0[j][0]+v0[j][1]*v0[j][1]+v0[j][2]*v0[j][2], 1e-8f));
    float sg = 1.f/(1.f + __expf(-nn));
    VB[e*3+0][p+16*j] = v0[j][0]*sg;
    VB[e*3+1][p+16*j] = v0[j][1]*sg;
    VB[e*3+2][p+16*j] = v0[j][2]*sg;
  }
  __syncthreads();
  #pragma unroll
  for (int j=0;j<8;++j) AS[e][p+16*j] = s[j];
  __syncthreads();

  // ---- GVP1: vh1 = v0 @ wh1^T (32x32), vn1; s1; v1 ----
  {
    float b[2][3];
    #pragma unroll
    for (int j=0;j<2;++j){ b[j][0]=0.f; b[j][1]=0.f; b[j][2]=0.f; }
    for (int k=0;k<32;++k){
      float x0 = VB[e*3+0][k], x1 = VB[e*3+1][k], x2 = VB[e*3+2][k];
      const float* wr = WT + O_WH1 + k*32 + p;
      #pragma unroll
      for (int j=0;j<2;++j){ float w = wr[16*j]; b[j][0]+=x0*w; b[j][1]+=x1*w; b[j][2]+=x2*w; }
    }
    #pragma unroll
    for (int j=0;j<2;++j)
      AS[e][128+p+16*j] = sqrtf(fmaxf(b[j][0]*b[j][0]+b[j][1]*b[j][1]+b[j][2]*b[j][2], 1e-8f));
    __syncthreads();
    #pragma unroll
    for (int j=0;j<2;++j){ VH[e*3+0][p+16*j]=b[j][0]; VH[e*3+1][p+16*j]=b[j][1]; VH[e*3+2][p+16*j]=b[j][2]; }
    __syncthreads();
  }
  #pragma unroll
  for (int j=0;j<8;++j) s[j] = WT[O_B1 + p + 16*j];
  for (int k=0;k<160;++k){
    float av = AS[e][k];
    const float* wr = WT + O_WSW1 + k*128 + p;
    #pragma unroll
    for (int j=0;j<8;++j) s[j] += av * wr[16*j];
  }
  #pragma unroll
  for (int j=0;j<8;++j) s[j] = fmaxf(s[j], 0.f);
  #pragma unroll
  for (int j=0;j<2;++j){ v0[j][0]=0.f; v0[j][1]=0.f; v0[j][2]=0.f; }
  for (int h=0;h<32;++h){
    float x0 = VH[e*3+0][h], x1 = VH[e*3+1][h], x2 = VH[e*3+2][h];
    const float* wr = WT + O_WV1 + h*32 + p;
    #pragma unroll
    for (int j=0;j<2;++j){ float w = wr[16*j]; v0[j][0]+=x0*w; v0[j][1]+=x1*w; v0[j][2]+=x2*w; }
  }
  #pragma unroll
  for (int j=0;j<2;++j){
    float nn = sqrtf(fmaxf(v0[j][0]*v0[j][0]+v0[j][1]*v0[j][1]+v0[j][2]*v0[j][2], 1e-8f));
    float sg = 1.f/(1.f + __expf(-nn));
    VB[e*3+0][p+16*j] = v0[j][0]*sg;
    VB[e*3+1][p+16*j] = v0[j][1]*sg;
    VB[e*3+2][p+16*j] = v0[j][2]*sg;
  }
  __syncthreads();
  #pragma unroll
  for (int j=0;j<8;++j) AS[e][p+16*j] = s[j];
  __syncthreads();

  // ---- GVP2 (no acts): vh2, vn2; s2 -> atomic agg; v2 -> atomic agg ----
  {
    float b[2][3];
    #pragma unroll
    for (int j=0;j<2;++j){ b[j][0]=0.f; b[j][1]=0.f; b[j][2]=0.f; }
    for (int k=0;k<32;++k){
      float x0 = VB[e*3+0][k], x1 = VB[e*3+1][k], x2 = VB[e*3+2][k];
      const float* wr = WT + O_WH2 + k*32 + p;
      #pragma unroll
      for (int j=0;j<2;++j){ float w = wr[16*j]; b[j][0]+=x0*w; b[j][1]+=x1*w; b[j][2]+=x2*w; }
    }
    #pragma unroll
    for (int j=0;j<2;++j)
      AS[e][128+p+16*j] = sqrtf(fmaxf(b[j][0]*b[j][0]+b[j][1]*b[j][1]+b[j][2]*b[j][2], 1e-8f));
    __syncthreads();
    #pragma unroll
    for (int j=0;j<2;++j){ VH[e*3+0][p+16*j]=b[j][0]; VH[e*3+1][p+16*j]=b[j][1]; VH[e*3+2][p+16*j]=b[j][2]; }
    __syncthreads();
  }
  #pragma unroll
  for (int j=0;j<8;++j) s[j] = WT[O_B2 + p + 16*j];
  for (int k=0;k<160;++k){
    float av = AS[e][k];
    const float* wr = WT + O_WSW2 + k*128 + p;
    #pragma unroll
    for (int j=0;j<8;++j) s[j] += av * wr[16*j];
  }
  #pragma unroll
  for (int j=0;j<2;++j){ v0[j][0]=0.f; v0[j][1]=0.f; v0[j][2]=0.f; }
  for (int h=0;h<32;++h){
    float x0 = VH[e*3+0][h], x1 = VH[e*3+1][h], x2 = VH[e*3+2][h];
    const float* wr = WT + O_WV2 + h*32 + p;
    #pragma unroll
    for (int j=0;j<2;++j){ float w = wr[16*j]; v0[j][0]+=x0*w; v0[j][1]+=x1*w; v0[j][2]+=x2*w; }
  }
  if (live){
    #pragma unroll
    for (int j=0;j<8;++j) atomicAdd(&agg_s[(size_t)dst*128 + p + 16*j], s[j]);
    #pragma unroll
    for (int j=0;j<2;++j){
      int vo = p + 16*j;
      atomicAdd(&agg_v[(size_t)dst*96 + vo*3 + 0], v0[j][0]);
      atomicAdd(&agg_v[(size_t)dst*96 + vo*3 + 1], v0[j][1]);
      atomicAdd(&agg_v[(size_t)dst*96 + vo*3 + 2], v0[j][2]);
    }
    if (p == 0) atomicAdd(&cnt[dst], 1.f);
  }
}

// ---------- residual + tuple LayerNorm after aggregation ----------
__global__ __launch_bounds__(256) void k_ln0(
    const void* __restrict__ node_s, const void* __restrict__ node_v,
    const float* __restrict__ agg_s, const float* __restrict__ agg_v,
    const float* __restrict__ cnt, const float* __restrict__ WT,
    float* __restrict__ s_mid, float* __restrict__ v_mid,
    const int* __restrict__ flag, int N)
{
  int n = blockIdx.x*256 + threadIdx.x;
  if (n>=N) return;
  const int isf = *flag;
  const float inv = 1.f/fmaxf(cnt[n], 1.f);
  float sum=0.f, ss=0.f;
  for (int i=0;i<128;++i){
    float x = ldx(node_s,(size_t)n*128+i,isf) + agg_s[(size_t)n*128+i]*inv;
    sum += x; ss += x*x;
  }
  const float mu = sum*(1.f/128.f);
  const float var = fmaxf(ss*(1.f/128.f) - mu*mu, 0.f);
  const float rstd = rsqrtf(var + 1e-5f);
  for (int i=0;i<128;++i){
    float x = ldx(node_s,(size_t)n*128+i,isf) + agg_s[(size_t)n*128+i]*inv;
    s_mid[(size_t)n*128+i] = (x-mu)*rstd*WT[O_LN0G+i] + WT[O_LN0B+i];
  }
  float vs=0.f;
  for (int vo=0;vo<32;++vo){
    float y0 = ldx(node_v,(size_t)n*96+vo*3+0,isf) + agg_v[(size_t)n*96+vo*3+0]*inv;
    float y1 = ldx(node_v,(size_t)n*96+vo*3+1,isf) + agg_v[(size_t)n*96+vo*3+1]*inv;
    float y2 = ldx(node_v,(size_t)n*96+vo*3+2,isf) + agg_v[(size_t)n*96+vo*3+2]*inv;
    vs += fmaxf(y0*y0+y1*y1+y2*y2, 1e-8f);
  }
  const float scale = rsqrtf(vs*(1.f/32.f));
  for (int vo=0;vo<32;++vo){
    float y0 = ldx(node_v,(size_t)n*96+vo*3+0,isf) + agg_v[(size_t)n*96+vo*3+0]*inv;
    float y1 = ldx(node_v,(size_t)n*96+vo*3+1,isf) + agg_v[(size_t)n*96+vo*3+1]*inv;
    float y2 = ldx(node_v,(size_t)n*96+vo*3+2,isf) + agg_v[(size_t)n*96+vo*3+2]*inv;
    v_mid[(size_t)n*96+vo]      = y0*scale;   // d-major [n][3][32]
    v_mid[(size_t)n*96+32+vo]   = y1*scale;
    v_mid[(size_t)n*96+64+vo]   = y2*scale;
  }
}

// ---------- fused node feed-forward (2 GVPs) + final LN -> d_out ----------
// 8 nodes/block, 256 threads (32/node).
#define NPB 8
__global__ __launch_bounds__(256) void k_node_fused(
    const float* __restrict__ s_mid, const float* __restrict__ v_mid,
    const float* __restrict__ WT, float* __restrict__ out, int N)
{
  __shared__ float ASn[NPB][770];  // [0:128]=s_mid, [128:192]=vn0f, [192:704]=fs0, [704:768]=vn1f
  __shared__ float VHn[NPB*3][66];
  __shared__ float Vin[NPB*3][33];
  __shared__ float Vff[NPB*3][66];
  const int tid = threadIdx.x;
  const int nd = tid>>5, p = tid&31;
  const int n0 = blockIdx.x*NPB;
  const int n = n0 + nd;
  const bool live = n < N;

  for (int u=tid; u<NPB*128; u+=256){
    int d2 = u>>7, i = u&127;
    ASn[d2][i] = (n0+d2 < N) ? s_mid[(size_t)(n0+d2)*128 + i] : 0.f;
  }
  for (int u=tid; u<NPB*96; u+=256){
    int d2 = u/96, r = u - d2*96;
    Vin[d2*3 + (r>>5)][r&31] = (n0+d2 < N) ? v_mid[(size_t)(n0+d2)*96 + r] : 0.f;
  }
  __syncthreads();

  // ff0 vh (32->64), vn0f
  {
    float a[2][3];
    #pragma unroll
    for (int j=0;j<2;++j){ a[j][0]=0.f; a[j][1]=0.f; a[j][2]=0.f; }
    for (int k=0;k<32;++k){
      float x0 = Vin[nd*3+0][k], x1 = Vin[nd*3+1][k], x2 = Vin[nd*3+2][k];
      const float* wr = WT + O_FF0H + k*64 + p;
      #pragma unroll
      for (int j=0;j<2;++j){ float w = wr[32*j]; a[j][0]+=x0*w; a[j][1]+=x1*w; a[j][2]+=x2*w; }
    }
    #pragma unroll
    for (int j=0;j<2;++j)
      ASn[nd][128+p+32*j] = sqrtf(fmaxf(a[j][0]*a[j][0]+a[j][1]*a[j][1]+a[j][2]*a[j][2], 1e-8f));
    __syncthreads();
    #pragma unroll
    for (int j=0;j<2;++j){ VHn[nd*3+0][p+32*j]=a[j][0]; VHn[nd*3+1][p+32*j]=a[j][1]; VHn[nd*3+2][p+32*j]=a[j][2]; }
    __syncthreads();
  }
  // fs0 = relu(b + cat(s_mid, vn0f) @ ff0s_t)  [192 -> 512]
  {
    float s[16];
    #pragma unroll
    for (int j=0;j<16;++j) s[j] = WT[O_FB0 + p + 32*j];
    for (int k=0;k<192;++k){
      float av = ASn[nd][k];
      const float* wr = WT + O_FF0S + k*512 + p;
      #pragma unroll
      for (int j=0;j<16;++j) s[j] += av * wr[32*j];
    }
    // fv0 = gate(vh @ ff0v_t) [64 -> 64]
    float a[2][3];
    #pragma unroll
    for (int j=0;j<2;++j){ a[j][0]=0.f; a[j][1]=0.f; a[j][2]=0.f; }
    for (int h=0;h<64;++h){
      float x0 = VHn[nd*3+0][h], x1 = VHn[nd*3+1][h], x2 = VHn[nd*3+2][h];
      const float* wr = WT + O_FF0V + h*64 + p;
      #pragma unroll
      for (int j=0;j<2;++j){ float w = wr[32*j]; a[j][0]+=x0*w; a[j][1]+=x1*w; a[j][2]+=x2*w; }
    }
    #pragma unroll
    for (int j=0;j<2;++j){
      float nn = sqrtf(fmaxf(a[j][0]*a[j][0]+a[j][1]*a[j][1]+a[j][2]*a[j][2], 1e-8f));
      float sg = 1.f/(1.f + __expf(-nn));
      Vff[nd*3+0][p+32*j] = a[j][0]*sg;
      Vff[nd*3+1][p+32*j] = a[j][1]*sg;
      Vff[nd*3+2][p+32*j] = a[j][2]*sg;
    }
    __syncthreads();
    #pragma unroll
    for (int j=0;j<16;++j) ASn[nd][192 + p + 32*j] = fmaxf(s[j], 0.f);
    __syncthreads();
  }
  // ff1 vh (64->64), vn1f
  {
    float a[2][3];
    #pragma unroll
    for (int j=0;j<2;++j){ a[j][0]=0.f; a[j][1]=0.f; a[j][2]=0.f; }
    for (int k=0;k<64;++k){
      float x0 = Vff[nd*3+0][k], x1 = Vff[nd*3+1][k], x2 = Vff[nd*3+2][k];
      const float* wr = WT + O_FF1H + k*64 + p;
      #pragma unroll
      for (int j=0;j<2;++j){ float w = wr[32*j]; a[j][0]+=x0*w; a[j][1]+=x1*w; a[j][2]+=x2*w; }
    }
    #pragma unroll
    for (int j=0;j<2;++j)
      ASn[nd][704+p+32*j] = sqrtf(fmaxf(a[j][0]*a[j][0]+a[j][1]*a[j][1]+a[j][2]*a[j][2], 1e-8f));
    __syncthreads();
    #pragma unroll
    for (int j=0;j<2;++j){ VHn[nd*3+0][p+32*j]=a[j][0]; VHn[nd*3+1][p+32*j]=a[j][1]; VHn[nd*3+2][p+32*j]=a[j][2]; }
    __syncthreads();
  }
  // fs1 = b + cat(fs0, vn1f) @ ff1s_t  [576 -> 128]  (no relu)
  float f[4];
  #pragma unroll
  for (int j=0;j<4;++j) f[j] = WT[O_FB1 + p + 32*j];
  for (int k=0;k<576;++k){
    float av = ASn[nd][192+k];
    const float* wr = WT + O_FF1S + k*128 + p;
    #pragma unroll
    for (int j=0;j<4;++j) f[j] += av * wr[32*j];
  }
  // fv1 = vh @ ff1v_t [64 -> 32] (no gate), vo = p
  float y0=0.f, y1=0.f, y2=0.f;
  for (int h=0;h<64;++h){
    float w = WT[O_FF1V + h*32 + p];
    y0 += VHn[nd*3+0][h]*w;
    y1 += VHn[nd*3+1][h]*w;
    y2 += VHn[nd*3+2][h]*w;
  }
  // final LN in-block (32 lanes per node = half-wave; shfl_xor <=16 stays inside)
  float xs[4], sum=0.f, ss=0.f;
  #pragma unroll
  for (int j=0;j<4;++j){
    xs[j] = ASn[nd][p+32*j] + f[j];
    sum += xs[j]; ss += xs[j]*xs[j];
  }
  #pragma unroll
  for (int m=1; m<32; m<<=1){ sum += __shfl_xor(sum, m); ss += __shfl_xor(ss, m); }
  const float mu = sum*(1.f/128.f);
  const float var = fmaxf(ss*(1.f/128.f) - mu*mu, 0.f);
  const float rstd = rsqrtf(var + 1e-5f);
  if (live){
    #pragma unroll
    for (int j=0;j<4;++j){
      int o = p + 32*j;
      out[(size_t)n*128 + o] = (xs[j]-mu)*rstd*WT[O_LN1G+o] + WT[O_LN1B+o];
    }
  }
  float z0 = Vin[nd*3+0][p] + y0;
  float z1 = Vin[nd*3+1][p] + y1;
  float z2 = Vin[nd*3+2][p] + y2;
  float q = fmaxf(z0*z0+z1*z1+z2*z2, 1e-8f);
  float vs = q;
  #pragma unroll
  for (int m=1; m<32; m<<=1) vs += __shfl_xor(vs, m);
  const float scale = rsqrtf(vs*(1.f/32.f));
  if (live){
    size_t base = (size_t)N*128 + (size_t)n*96 + (size_t)p*3;
    out[base+0] = z0*scale;
    out[base+1] = z1*scale;
    out[base+2] = z2*scale;
  }
}

extern "C" void kernel_launch(void* const* d_in, const int* in_sizes, int n_in,
                              void* d_out, int out_size, void* d_ws, size_t ws_size,
                              hipStream_t stream)
{
  (void)n_in; (void)out_size; (void)ws_size;
  const int N = in_sizes[0]/128;
  const int E = in_sizes[4]/2;

  size_t off = 0;
  auto alloc = [&](size_t bytes)->char*{
    size_t o = (off + 255) & ~(size_t)255;
    off = o + bytes;
    return (char*)d_ws + o;
  };
  int*   flags = (int*)alloc(256);
  float* WT    = (float*)alloc((size_t)WT_TOTAL*4);
  float* agg_s = (float*)alloc((size_t)N*128*4);
  float* agg_v = (float*)alloc((size_t)N*96*4);
  float* cnt   = (float*)alloc((size_t)N*4);
  size_t aggBytes = (size_t)((char*)(cnt+N) - (char*)agg_s);
  float* s_mid = (float*)alloc((size_t)N*128*4);
  float* v_mid = (float*)alloc((size_t)N*96*4);
  int*   ei32  = (int*)alloc((size_t)2*E*4);

  // transpose jobs: (src, off, O, K, P)
  TJobs J; int np=0, pos=0;
  auto addj = [&](const void* src, int o_, int O, int K, int P){
    J.j[np].src=src; J.j[np].off=o_; J.j[np].O=O; J.j[np].K=K; J.j[np].P=P;
    J.prefix[np]=pos; pos += K*P; ++np;
  };
  addj(d_in[5],  O_WH0,  65, 65, 66);
  addj(d_in[6],  O_WSW0, 128, 353, 128);
  addj(d_in[8],  O_WV0,  32, 65, 32);
  addj(d_in[9],  O_WH1,  32, 32, 32);
  addj(d_in[10], O_WSW1, 128, 160, 128);
  addj(d_in[12], O_WV1,  32, 32, 32);
  addj(d_in[13], O_WH2,  32, 32, 32);
  addj(d_in[14], O_WSW2, 128, 160, 128);
  addj(d_in[16], O_WV2,  32, 32, 32);
  addj(d_in[19], O_FF0H, 64, 32, 64);
  addj(d_in[20], O_FF0S, 512, 192, 512);
  addj(d_in[22], O_FF0V, 64, 64, 64);
  addj(d_in[23], O_FF1H, 64, 64, 64);
  addj(d_in[24], O_FF1S, 128, 576, 128);
  addj(d_in[26], O_FF1V, 32, 64, 32);
  addj(d_in[7],  O_B0,   128, 1, 128);
  addj(d_in[11], O_B1,   128, 1, 128);
  addj(d_in[15], O_B2,   128, 1, 128);
  addj(d_in[21], O_FB0,  512, 1, 512);
  addj(d_in[25], O_FB1,  128, 1, 128);
  addj(d_in[17], O_LN0G, 128, 1, 128);
  addj(d_in[18], O_LN0B, 128, 1, 128);
  addj(d_in[27], O_LN1G, 128, 1, 128);
  addj(d_in[28], O_LN1B, 128, 1, 128);
  J.prefix[24] = pos;

  hipMemsetAsync(agg_s, 0, aggBytes, stream);
  k_probe_f<<<dim3(1), dim3(256), 0, stream>>>((const u16*)d_in[0], flags);
  k_probe_ei<<<dim3(1), dim3(256), 0, stream>>>((const unsigned*)d_in[4], flags);
  k_cvt_ei<<<dim3((2*E+255)/256), dim3(256), 0, stream>>>(d_in[4], ei32, 2*E, N, flags);
  k_transpose<<<dim3((pos+255)/256), dim3(256), 0, stream>>>(J, WT, flags);

  k_edge_fused<<<dim3((E+EPB-1)/EPB), dim3(256), 0, stream>>>(
      d_in[0], d_in[1], d_in[2], d_in[3], ei32, E, WT, agg_s, agg_v, cnt, flags);

  k_ln0<<<dim3((N+255)/256), dim3(256), 0, stream>>>(
      d_in[0], d_in[1], agg_s, agg_v, cnt, WT, s_mid, v_mid, flags, N);

  k_node_fused<<<dim3((N+NPB-1)/NPB), dim3(256), 0, stream>>>(s_mid, v_mid, WT, (float*)d_out, N);
}

// Round 8
// 1665.612 us; speedup vs baseline: 24.7591x; 1.8876x over previous
//
#include <hip/hip_runtime.h>

typedef unsigned short u16;
typedef __attribute__((ext_vector_type(8))) short bf16x8;
typedef __attribute__((ext_vector_type(4))) float f32x4;

__device__ __forceinline__ u16 f2b(float f){
  unsigned u = __float_as_uint(f);
  unsigned r = ((u>>16)&1u) + 0x7fffu;
  return (u16)((u+r)>>16);
}

// WT arena offsets (f32 elements) -- v-path + biases + LN params
#define O_WH0   0        // [65][66]  wh0_t[k*66+h]
#define O_WV0   49474    // [65][32]
#define O_WH1   51554    // [32][32]
#define O_WV1   73058    // [32][32]
#define O_WH2   74082    // [32][32]
#define O_WV2   95586    // [32][32]
#define O_FF0H  96610    // [32][64]
#define O_FF0S  98658    // [192][512]
#define O_FF0V  196962   // [64][64]
#define O_FF1H  201058   // [64][64]
#define O_FF1S  205154   // [576][128]
#define O_FF1V  278882   // [64][32]
#define O_B0    280930
#define O_B1    281058
#define O_B2    281186
#define O_FB0   281314
#define O_FB1   281826
#define O_LN0G  281954
#define O_LN0B  282082
#define O_LN1G  282210
#define O_LN1B  282338
#define WT_TOTAL 282466

// WB bf16 arena (elements): s-path weights, original [O][K] layout, K padded
#define WB0 0        // [128][384] (wsw0, K=353 zero-padded to 384)
#define WB1 49152    // [128][160]
#define WB2 69632    // [128][160]
#define WB_TOTAL 90112

// ---------- weight transpose into WT arena (f32 source) ----------
struct TJob { const float* src; int off, O, K, P; };
struct TJobs { TJob j[24]; int prefix[25]; };

__global__ __launch_bounds__(256) void k_transpose(TJobs J, float* __restrict__ WT){
  int t = blockIdx.x*256 + threadIdx.x;
  if (t >= J.prefix[24]) return;
  for (int i=0;i<24;i++){
    if (t < J.prefix[i+1]){
      TJob jb = J.j[i];
      int local = t - J.prefix[i];
      int k = local / jb.P, o = local - k*jb.P;
      WT[jb.off + local] = (o < jb.O) ? jb.src[(size_t)o*jb.K + k] : 0.f;
      return;
    }
  }
}

// ---------- s-path weights -> bf16, original layout, K-padded ----------
__global__ __launch_bounds__(256) void k_wb(const float* __restrict__ w0,
                                            const float* __restrict__ w1,
                                            const float* __restrict__ w2,
                                            u16* __restrict__ WB){
  int t = blockIdx.x*256 + threadIdx.x;
  if (t < 128*384){
    int o = t/384, k = t - o*384;
    WB[WB0 + t] = f2b(k < 353 ? w0[(size_t)o*353 + k] : 0.f);
    return;
  }
  t -= 128*384;
  if (t < 128*160){ WB[WB1 + t] = f2b(w1[t]); return; }
  t -= 128*160;
  if (t < 128*160){ WB[WB2 + t] = f2b(w2[t]); return; }
}

// ---------- fused 3-GVP edge chain: MFMA s-path + VALU v-path + atomic agg ----------
#define EPB 16
__global__ __launch_bounds__(256) void k_edge_mfma(
    const float* __restrict__ node_s, const float* __restrict__ node_v,
    const float* __restrict__ edge_s, const float* __restrict__ edge_v,
    const int* __restrict__ ei, int E,
    const float* __restrict__ WT, const u16* __restrict__ WB,
    float* __restrict__ agg_s, float* __restrict__ agg_v, float* __restrict__ cnt)
{
  __shared__ __align__(16) u16 A[EPB][392];   // bf16 activation tile, K-pad 384, pitch 392
  __shared__ float VH[EPB*3][66];
  __shared__ float VB[EPB*3][33];
  __shared__ int   SD[EPB][2];
  const int tid = threadIdx.x;
  const int e = tid>>4, p = tid&15;      // v-path mapping: 16 threads/edge
  const int w = tid>>6, l = tid&63;      // wave id, lane
  const int ge0 = blockIdx.x*EPB;

  if (tid < EPB*2){
    int ee = tid>>1, which = tid&1;
    int g = ge0+ee;
    SD[ee][which] = (g<E) ? ei[(size_t)which*E + g] : 0;
  }
  __syncthreads();

  // gather A cols 0..287 = cat(s_src, edge_s, s_dst) as bf16; 288..391 zero (vn0 lands 288..352)
  for (int u=tid; u<EPB*392; u+=256){
    int ee = u/392, i = u - ee*392;
    int g = ge0+ee; float v = 0.f;
    if (g<E && i<288){
      if (i<128)      v = node_s[(size_t)SD[ee][0]*128 + i];
      else if (i<160) v = edge_s[(size_t)g*32 + (i-128)];
      else            v = node_s[(size_t)SD[ee][1]*128 + (i-160)];
    }
    A[ee][i] = f2b(v);
  }
  // gather mv (d-major) into VH: k<32 v_src, k=32 edge_v, 33..64 v_dst
  for (int u=tid; u<EPB*198; u+=256){
    int ee = u/198, r = u - ee*198, d = r/66, k = r - d*66;
    int g = ge0+ee; float v = 0.f;
    if (g<E && k<65){
      if (k<32)       v = node_v[(size_t)SD[ee][0]*96 + k*3 + d];
      else if (k==32) v = edge_v[(size_t)g*3 + d];
      else            v = node_v[(size_t)SD[ee][1]*96 + (k-33)*3 + d];
    }
    VH[ee*3+d][k] = v;
  }
  __syncthreads();

  const int g = ge0 + e;
  const bool live = g < E;
  const int dste = SD[e][1];

  // ---- phase 1 (VALU): vh0 = mv @ wh0^T (65x65x3), vn0 -> A[288..352] ----
  float a0[5], a1[5], a2[5];
  #pragma unroll
  for (int j=0;j<5;++j){ a0[j]=0.f; a1[j]=0.f; a2[j]=0.f; }
  for (int k=0;k<65;++k){
    float x0 = VH[e*3+0][k], x1 = VH[e*3+1][k], x2 = VH[e*3+2][k];
    const float* wr = WT + O_WH0 + k*66;
    #pragma unroll
    for (int j=0;j<5;++j){
      int h = p + 16*j;
      if (h < 65){ float wv = wr[h]; a0[j]+=x0*wv; a1[j]+=x1*wv; a2[j]+=x2*wv; }
    }
  }
  #pragma unroll
  for (int j=0;j<5;++j){
    int h = p + 16*j;
    if (h < 65) A[e][288+h] = f2b(sqrtf(fmaxf(a0[j]*a0[j]+a1[j]*a1[j]+a2[j]*a2[j], 1e-8f)));
  }
  __syncthreads();
  #pragma unroll
  for (int j=0;j<5;++j){
    int h = p + 16*j;
    if (h < 65){ VH[e*3+0][h]=a0[j]; VH[e*3+1][h]=a1[j]; VH[e*3+2][h]=a2[j]; }
  }
  __syncthreads();

  // MFMA geometry: wave w covers cols [w*32, w*32+32); lane col = n_a / n_b
  const int n_a = w*32 + (l&15);
  const int n_b = n_a + 16;
  const int kq  = (l>>4)*8;          // k-offset of this lane's 8 contiguous elements
  const int m_a = l&15;              // A-fragment row
  f32x4 ca = {0.f,0.f,0.f,0.f}, cb = {0.f,0.f,0.f,0.f};

  // ---- phase 2: MFMA s0 (K=384) + VALU v0 ----
  for (int kk=0; kk<384; kk+=32){
    bf16x8 af = *(const bf16x8*)&A[m_a][kk + kq];
    bf16x8 b1 = *(const bf16x8*)&WB[WB0 + (size_t)n_a*384 + kk + kq];
    bf16x8 b2 = *(const bf16x8*)&WB[WB0 + (size_t)n_b*384 + kk + kq];
    ca = __builtin_amdgcn_mfma_f32_16x16x32_bf16(af, b1, ca, 0, 0, 0);
    cb = __builtin_amdgcn_mfma_f32_16x16x32_bf16(af, b2, cb, 0, 0, 0);
  }
  {
    float v0[2][3];
    #pragma unroll
    for (int j=0;j<2;++j){ v0[j][0]=0.f; v0[j][1]=0.f; v0[j][2]=0.f; }
    for (int h=0;h<65;++h){
      float x0 = VH[e*3+0][h], x1 = VH[e*3+1][h], x2 = VH[e*3+2][h];
      const float* wr = WT + O_WV0 + h*32 + p;
      #pragma unroll
      for (int j=0;j<2;++j){ float wv = wr[16*j]; v0[j][0]+=x0*wv; v0[j][1]+=x1*wv; v0[j][2]+=x2*wv; }
    }
    #pragma unroll
    for (int j=0;j<2;++j){
      float nn = sqrtf(fmaxf(v0[j][0]*v0[j][0]+v0[j][1]*v0[j][1]+v0[j][2]*v0[j][2], 1e-8f));
      float sg = 1.f/(1.f + __expf(-nn));
      VB[e*3+0][p+16*j] = v0[j][0]*sg;
      VB[e*3+1][p+16*j] = v0[j][1]*sg;
      VB[e*3+2][p+16*j] = v0[j][2]*sg;
    }
  }
  __syncthreads();

  // ---- phase 3: C0 -> A (relu+bias); VALU vh1 (reads VB), vn1 -> A[128..159] ----
  {
    float ba = WT[O_B0 + n_a], bb = WT[O_B0 + n_b];
    #pragma unroll
    for (int j=0;j<4;++j){
      int r = (l>>4)*4 + j;
      A[r][n_a] = f2b(fmaxf(ca[j] + ba, 0.f));
      A[r][n_b] = f2b(fmaxf(cb[j] + bb, 0.f));
    }
  }
  float bh[2][3];
  #pragma unroll
  for (int j=0;j<2;++j){ bh[j][0]=0.f; bh[j][1]=0.f; bh[j][2]=0.f; }
  for (int k=0;k<32;++k){
    float x0 = VB[e*3+0][k], x1 = VB[e*3+1][k], x2 = VB[e*3+2][k];
    const float* wr = WT + O_WH1 + k*32 + p;
    #pragma unroll
    for (int j=0;j<2;++j){ float wv = wr[16*j]; bh[j][0]+=x0*wv; bh[j][1]+=x1*wv; bh[j][2]+=x2*wv; }
  }
  #pragma unroll
  for (int j=0;j<2;++j)
    A[e][128+p+16*j] = f2b(sqrtf(fmaxf(bh[j][0]*bh[j][0]+bh[j][1]*bh[j][1]+bh[j][2]*bh[j][2], 1e-8f)));
  __syncthreads();
  #pragma unroll
  for (int j=0;j<2;++j){ VH[e*3+0][p+16*j]=bh[j][0]; VH[e*3+1][p+16*j]=bh[j][1]; VH[e*3+2][p+16*j]=bh[j][2]; }
  __syncthreads();

  // ---- phase 4: MFMA s1 (K=160) + VALU v1 ----
  ca = (f32x4){0.f,0.f,0.f,0.f}; cb = (f32x4){0.f,0.f,0.f,0.f};
  for (int kk=0; kk<160; kk+=32){
    bf16x8 af = *(const bf16x8*)&A[m_a][kk + kq];
    bf16x8 b1 = *(const bf16x8*)&WB[WB1 + (size_t)n_a*160 + kk + kq];
    bf16x8 b2 = *(const bf16x8*)&WB[WB1 + (size_t)n_b*160 + kk + kq];
    ca = __builtin_amdgcn_mfma_f32_16x16x32_bf16(af, b1, ca, 0, 0, 0);
    cb = __builtin_amdgcn_mfma_f32_16x16x32_bf16(af, b2, cb, 0, 0, 0);
  }
  {
    float v0[2][3];
    #pragma unroll
    for (int j=0;j<2;++j){ v0[j][0]=0.f; v0[j][1]=0.f; v0[j][2]=0.f; }
    for (int h=0;h<32;++h){
      float x0 = VH[e*3+0][h], x1 = VH[e*3+1][h], x2 = VH[e*3+2][h];
      const float* wr = WT + O_WV1 + h*32 + p;
      #pragma unroll
      for (int j=0;j<2;++j){ float wv = wr[16*j]; v0[j][0]+=x0*wv; v0[j][1]+=x1*wv; v0[j][2]+=x2*wv; }
    }
    #pragma unroll
    for (int j=0;j<2;++j){
      float nn = sqrtf(fmaxf(v0[j][0]*v0[j][0]+v0[j][1]*v0[j][1]+v0[j][2]*v0[j][2], 1e-8f));
      float sg = 1.f/(1.f + __expf(-nn));
      VB[e*3+0][p+16*j] = v0[j][0]*sg;
      VB[e*3+1][p+16*j] = v0[j][1]*sg;
      VB[e*3+2][p+16*j] = v0[j][2]*sg;
    }
  }
  __syncthreads();

  // ---- phase 5: C1 -> A; VALU vh2, vn2 -> A[128..159] ----
  {
    float ba = WT[O_B1 + n_a], bb = WT[O_B1 + n_b];
    #pragma unroll
    for (int j=0;j<4;++j){
      int r = (l>>4)*4 + j;
      A[r][n_a] = f2b(fmaxf(ca[j] + ba, 0.f));
      A[r][n_b] = f2b(fmaxf(cb[j] + bb, 0.f));
    }
  }
  #pragma unroll
  for (int j=0;j<2;++j){ bh[j][0]=0.f; bh[j][1]=0.f; bh[j][2]=0.f; }
  for (int k=0;k<32;++k){
    float x0 = VB[e*3+0][k], x1 = VB[e*3+1][k], x2 = VB[e*3+2][k];
    const float* wr = WT + O_WH2 + k*32 + p;
    #pragma unroll
    for (int j=0;j<2;++j){ float wv = wr[16*j]; bh[j][0]+=x0*wv; bh[j][1]+=x1*wv; bh[j][2]+=x2*wv; }
  }
  #pragma unroll
  for (int j=0;j<2;++j)
    A[e][128+p+16*j] = f2b(sqrtf(fmaxf(bh[j][0]*bh[j][0]+bh[j][1]*bh[j][1]+bh[j][2]*bh[j][2], 1e-8f)));
  __syncthreads();
  #pragma unroll
  for (int j=0;j<2;++j){ VH[e*3+0][p+16*j]=bh[j][0]; VH[e*3+1][p+16*j]=bh[j][1]; VH[e*3+2][p+16*j]=bh[j][2]; }
  __syncthreads();

  // ---- phase 6: MFMA s2 (K=160) + VALU v2; atomic aggregation ----
  ca = (f32x4){0.f,0.f,0.f,0.f}; cb = (f32x4){0.f,0.f,0.f,0.f};
  for (int kk=0; kk<160; kk+=32){
    bf16x8 af = *(const bf16x8*)&A[m_a][kk + kq];
    bf16x8 b1 = *(const bf16x8*)&WB[WB2 + (size_t)n_a*160 + kk + kq];
    bf16x8 b2 = *(const bf16x8*)&WB[WB2 + (size_t)n_b*160 + kk + kq];
    ca = __builtin_amdgcn_mfma_f32_16x16x32_bf16(af, b1, ca, 0, 0, 0);
    cb = __builtin_amdgcn_mfma_f32_16x16x32_bf16(af, b2, cb, 0, 0, 0);
  }
  {
    float v2[2][3];
    #pragma unroll
    for (int j=0;j<2;++j){ v2[j][0]=0.f; v2[j][1]=0.f; v2[j][2]=0.f; }
    for (int h=0;h<32;++h){
      float x0 = VH[e*3+0][h], x1 = VH[e*3+1][h], x2 = VH[e*3+2][h];
      const float* wr = WT + O_WV2 + h*32 + p;
      #pragma unroll
      for (int j=0;j<2;++j){ float wv = wr[16*j]; v2[j][0]+=x0*wv; v2[j][1]+=x1*wv; v2[j][2]+=x2*wv; }
    }
    if (live){
      #pragma unroll
      for (int j=0;j<2;++j){
        int vo = p + 16*j;
        atomicAdd(&agg_v[(size_t)dste*96 + vo*3 + 0], v2[j][0]);
        atomicAdd(&agg_v[(size_t)dste*96 + vo*3 + 1], v2[j][1]);
        atomicAdd(&agg_v[(size_t)dste*96 + vo*3 + 2], v2[j][2]);
      }
      if (p == 0) atomicAdd(&cnt[dste], 1.f);
    }
  }
  {
    float ba = WT[O_B2 + n_a], bb = WT[O_B2 + n_b];
    #pragma unroll
    for (int j=0;j<4;++j){
      int r = (l>>4)*4 + j;
      if (ge0 + r < E){
        int dn = SD[r][1];
        atomicAdd(&agg_s[(size_t)dn*128 + n_a], ca[j] + ba);
        atomicAdd(&agg_s[(size_t)dn*128 + n_b], cb[j] + bb);
      }
    }
  }
}

// ---------- residual + tuple LayerNorm after aggregation ----------
__global__ __launch_bounds__(256) void k_ln0(
    const float* __restrict__ node_s, const float* __restrict__ node_v,
    const float* __restrict__ agg_s, const float* __restrict__ agg_v,
    const float* __restrict__ cnt, const float* __restrict__ WT,
    float* __restrict__ s_mid, float* __restrict__ v_mid, int N)
{
  int n = blockIdx.x*256 + threadIdx.x;
  if (n>=N) return;
  const float inv = 1.f/fmaxf(cnt[n], 1.f);
  float sum=0.f, ss=0.f;
  for (int i=0;i<128;++i){
    float x = node_s[(size_t)n*128+i] + agg_s[(size_t)n*128+i]*inv;
    sum += x; ss += x*x;
  }
  const float mu = sum*(1.f/128.f);
  const float var = fmaxf(ss*(1.f/128.f) - mu*mu, 0.f);
  const float rstd = rsqrtf(var + 1e-5f);
  for (int i=0;i<128;++i){
    float x = node_s[(size_t)n*128+i] + agg_s[(size_t)n*128+i]*inv;
    s_mid[(size_t)n*128+i] = (x-mu)*rstd*WT[O_LN0G+i] + WT[O_LN0B+i];
  }
  float vs=0.f;
  for (int vo=0;vo<32;++vo){
    float y0 = node_v[(size_t)n*96+vo*3+0] + agg_v[(size_t)n*96+vo*3+0]*inv;
    float y1 = node_v[(size_t)n*96+vo*3+1] + agg_v[(size_t)n*96+vo*3+1]*inv;
    float y2 = node_v[(size_t)n*96+vo*3+2] + agg_v[(size_t)n*96+vo*3+2]*inv;
    vs += fmaxf(y0*y0+y1*y1+y2*y2, 1e-8f);
  }
  const float scale = rsqrtf(vs*(1.f/32.f));
  for (int vo=0;vo<32;++vo){
    float y0 = node_v[(size_t)n*96+vo*3+0] + agg_v[(size_t)n*96+vo*3+0]*inv;
    float y1 = node_v[(size_t)n*96+vo*3+1] + agg_v[(size_t)n*96+vo*3+1]*inv;
    float y2 = node_v[(size_t)n*96+vo*3+2] + agg_v[(size_t)n*96+vo*3+2]*inv;
    v_mid[(size_t)n*96+vo]      = y0*scale;   // d-major [n][3][32]
    v_mid[(size_t)n*96+32+vo]   = y1*scale;
    v_mid[(size_t)n*96+64+vo]   = y2*scale;
  }
}

// ---------- fused node feed-forward (2 GVPs) + final LN -> d_out ----------
#define NPB 8
__global__ __launch_bounds__(256) void k_node_fused(
    const float* __restrict__ s_mid, const float* __restrict__ v_mid,
    const float* __restrict__ WT, float* __restrict__ out, int N)
{
  __shared__ float ASn[NPB][770];
  __shared__ float VHn[NPB*3][66];
  __shared__ float Vin[NPB*3][33];
  __shared__ float Vff[NPB*3][66];
  const int tid = threadIdx.x;
  const int nd = tid>>5, p = tid&31;
  const int n0 = blockIdx.x*NPB;
  const int n = n0 + nd;
  const bool live = n < N;

  for (int u=tid; u<NPB*128; u+=256){
    int d2 = u>>7, i = u&127;
    ASn[d2][i] = (n0+d2 < N) ? s_mid[(size_t)(n0+d2)*128 + i] : 0.f;
  }
  for (int u=tid; u<NPB*96; u+=256){
    int d2 = u/96, r = u - d2*96;
    Vin[d2*3 + (r>>5)][r&31] = (n0+d2 < N) ? v_mid[(size_t)(n0+d2)*96 + r] : 0.f;
  }
  __syncthreads();

  {
    float a[2][3];
    #pragma unroll
    for (int j=0;j<2;++j){ a[j][0]=0.f; a[j][1]=0.f; a[j][2]=0.f; }
    for (int k=0;k<32;++k){
      float x0 = Vin[nd*3+0][k], x1 = Vin[nd*3+1][k], x2 = Vin[nd*3+2][k];
      const float* wr = WT + O_FF0H + k*64 + p;
      #pragma unroll
      for (int j=0;j<2;++j){ float wv = wr[32*j]; a[j][0]+=x0*wv; a[j][1]+=x1*wv; a[j][2]+=x2*wv; }
    }
    #pragma unroll
    for (int j=0;j<2;++j)
      ASn[nd][128+p+32*j] = sqrtf(fmaxf(a[j][0]*a[j][0]+a[j][1]*a[j][1]+a[j][2]*a[j][2], 1e-8f));
    __syncthreads();
    #pragma unroll
    for (int j=0;j<2;++j){ VHn[nd*3+0][p+32*j]=a[j][0]; VHn[nd*3+1][p+32*j]=a[j][1]; VHn[nd*3+2][p+32*j]=a[j][2]; }
    __syncthreads();
  }
  {
    float s[16];
    #pragma unroll
    for (int j=0;j<16;++j) s[j] = WT[O_FB0 + p + 32*j];
    for (int k=0;k<192;++k){
      float av = ASn[nd][k];
      const float* wr = WT + O_FF0S + k*512 + p;
      #pragma unroll
      for (int j=0;j<16;++j) s[j] += av * wr[32*j];
    }
    float a[2][3];
    #pragma unroll
    for (int j=0;j<2;++j){ a[j][0]=0.f; a[j][1]=0.f; a[j][2]=0.f; }
    for (int h=0;h<64;++h){
      float x0 = VHn[nd*3+0][h], x1 = VHn[nd*3+1][h], x2 = VHn[nd*3+2][h];
      const float* wr = WT + O_FF0V + h*64 + p;
      #pragma unroll
      for (int j=0;j<2;++j){ float wv = wr[32*j]; a[j][0]+=x0*wv; a[j][1]+=x1*wv; a[j][2]+=x2*wv; }
    }
    #pragma unroll
    for (int j=0;j<2;++j){
      float nn = sqrtf(fmaxf(a[j][0]*a[j][0]+a[j][1]*a[j][1]+a[j][2]*a[j][2], 1e-8f));
      float sg = 1.f/(1.f + __expf(-nn));
      Vff[nd*3+0][p+32*j] = a[j][0]*sg;
      Vff[nd*3+1][p+32*j] = a[j][1]*sg;
      Vff[nd*3+2][p+32*j] = a[j][2]*sg;
    }
    __syncthreads();
    #pragma unroll
    for (int j=0;j<16;++j) ASn[nd][192 + p + 32*j] = fmaxf(s[j], 0.f);
    __syncthreads();
  }
  {
    float a[2][3];
    #pragma unroll
    for (int j=0;j<2;++j){ a[j][0]=0.f; a[j][1]=0.f; a[j][2]=0.f; }
    for (int k=0;k<64;++k){
      float x0 = Vff[nd*3+0][k], x1 = Vff[nd*3+1][k], x2 = Vff[nd*3+2][k];
      const float* wr = WT + O_FF1H + k*64 + p;
      #pragma unroll
      for (int j=0;j<2;++j){ float wv = wr[32*j]; a[j][0]+=x0*wv; a[j][1]+=x1*wv; a[j][2]+=x2*wv; }
    }
    #pragma unroll
    for (int j=0;j<2;++j)
      ASn[nd][704+p+32*j] = sqrtf(fmaxf(a[j][0]*a[j][0]+a[j][1]*a[j][1]+a[j][2]*a[j][2], 1e-8f));
    __syncthreads();
    #pragma unroll
    for (int j=0;j<2;++j){ VHn[nd*3+0][p+32*j]=a[j][0]; VHn[nd*3+1][p+32*j]=a[j][1]; VHn[nd*3+2][p+32*j]=a[j][2]; }
    __syncthreads();
  }
  float f[4];
  #pragma unroll
  for (int j=0;j<4;++j) f[j] = WT[O_FB1 + p + 32*j];
  for (int k=0;k<576;++k){
    float av = ASn[nd][192+k];
    const float* wr = WT + O_FF1S + k*128 + p;
    #pragma unroll
    for (int j=0;j<4;++j) f[j] += av * wr[32*j];
  }
  float y0=0.f, y1=0.f, y2=0.f;
  for (int h=0;h<64;++h){
    float wv = WT[O_FF1V + h*32 + p];
    y0 += VHn[nd*3+0][h]*wv;
    y1 += VHn[nd*3+1][h]*wv;
    y2 += VHn[nd*3+2][h]*wv;
  }
  float xs[4], sum=0.f, ss=0.f;
  #pragma unroll
  for (int j=0;j<4;++j){
    xs[j] = ASn[nd][p+32*j] + f[j];
    sum += xs[j]; ss += xs[j]*xs[j];
  }
  #pragma unroll
  for (int m=1; m<32; m<<=1){ sum += __shfl_xor(sum, m); ss += __shfl_xor(ss, m); }
  const float mu = sum*(1.f/128.f);
  const float var = fmaxf(ss*(1.f/128.f) - mu*mu, 0.f);
  const float rstd = rsqrtf(var + 1e-5f);
  if (live){
    #pragma unroll
    for (int j=0;j<4;++j){
      int o = p + 32*j;
      out[(size_t)n*128 + o] = (xs[j]-mu)*rstd*WT[O_LN1G+o] + WT[O_LN1B+o];
    }
  }
  float z0 = Vin[nd*3+0][p] + y0;
  float z1 = Vin[nd*3+1][p] + y1;
  float z2 = Vin[nd*3+2][p] + y2;
  float vs = fmaxf(z0*z0+z1*z1+z2*z2, 1e-8f);
  #pragma unroll
  for (int m=1; m<32; m<<=1) vs += __shfl_xor(vs, m);
  const float scale = rsqrtf(vs*(1.f/32.f));
  if (live){
    size_t base = (size_t)N*128 + (size_t)n*96 + (size_t)p*3;
    out[base+0] = z0*scale;
    out[base+1] = z1*scale;
    out[base+2] = z2*scale;
  }
}

extern "C" void kernel_launch(void* const* d_in, const int* in_sizes, int n_in,
                              void* d_out, int out_size, void* d_ws, size_t ws_size,
                              hipStream_t stream)
{
  (void)n_in; (void)out_size; (void)ws_size;
  const int N = in_sizes[0]/128;
  const int E = in_sizes[4]/2;
  const int* ei = (const int*)d_in[4];

  size_t off = 0;
  auto alloc = [&](size_t bytes)->char*{
    size_t o = (off + 255) & ~(size_t)255;
    off = o + bytes;
    return (char*)d_ws + o;
  };
  float* WT    = (float*)alloc((size_t)WT_TOTAL*4);
  u16*   WB    = (u16*)alloc((size_t)WB_TOTAL*2);
  float* agg_s = (float*)alloc((size_t)N*128*4);
  float* agg_v = (float*)alloc((size_t)N*96*4);
  float* cnt   = (float*)alloc((size_t)N*4);
  size_t aggBytes = (size_t)((char*)(cnt+N) - (char*)agg_s);
  float* s_mid = (float*)alloc((size_t)N*128*4);
  float* v_mid = (float*)alloc((size_t)N*96*4);

  // transpose jobs (v-path weights + biases + LN params)
  TJobs J; int np=0, pos=0;
  auto addj = [&](const void* src, int o_, int O, int K, int P){
    J.j[np].src=(const float*)src; J.j[np].off=o_; J.j[np].O=O; J.j[np].K=K; J.j[np].P=P;
    J.prefix[np]=pos; pos += K*P; ++np;
  };
  addj(d_in[5],  O_WH0,  65, 65, 66);
  addj(d_in[8],  O_WV0,  32, 65, 32);
  addj(d_in[9],  O_WH1,  32, 32, 32);
  addj(d_in[12], O_WV1,  32, 32, 32);
  addj(d_in[13], O_WH2,  32, 32, 32);
  addj(d_in[16], O_WV2,  32, 32, 32);
  addj(d_in[19], O_FF0H, 64, 32, 64);
  addj(d_in[20], O_FF0S, 512, 192, 512);
  addj(d_in[22], O_FF0V, 64, 64, 64);
  addj(d_in[23], O_FF1H, 64, 64, 64);
  addj(d_in[24], O_FF1S, 128, 576, 128);
  addj(d_in[26], O_FF1V, 32, 64, 32);
  addj(d_in[7],  O_B0,   128, 1, 128);
  addj(d_in[11], O_B1,   128, 1, 128);
  addj(d_in[15], O_B2,   128, 1, 128);
  addj(d_in[21], O_FB0,  512, 1, 512);
  addj(d_in[25], O_FB1,  128, 1, 128);
  addj(d_in[17], O_LN0G, 128, 1, 128);
  addj(d_in[18], O_LN0B, 128, 1, 128);
  addj(d_in[27], O_LN1G, 128, 1, 128);
  addj(d_in[28], O_LN1B, 128, 1, 128);
  for (int i=np; i<24; ++i){ J.j[i]=J.j[np-1]; J.prefix[i]=pos; }
  J.prefix[24] = pos;

  hipMemsetAsync(agg_s, 0, aggBytes, stream);
  k_transpose<<<dim3((pos+255)/256), dim3(256), 0, stream>>>(J, WT);
  k_wb<<<dim3((128*384 + 2*128*160 + 255)/256), dim3(256), 0, stream>>>(
      (const float*)d_in[6], (const float*)d_in[10], (const float*)d_in[14], WB);

  k_edge_mfma<<<dim3((E+EPB-1)/EPB), dim3(256), 0, stream>>>(
      (const float*)d_in[0], (const float*)d_in[1], (const float*)d_in[2], (const float*)d_in[3],
      ei, E, WT, WB, agg_s, agg_v, cnt);

  k_ln0<<<dim3((N+255)/256), dim3(256), 0, stream>>>(
      (const float*)d_in[0], (const float*)d_in[1], agg_s, agg_v, cnt, WT, s_mid, v_mid, N);

  k_node_fused<<<dim3((N+NPB-1)/NPB), dim3(256), 0, stream>>>(s_mid, v_mid, WT, (float*)d_out, N);
}

// Round 9
// 1055.391 us; speedup vs baseline: 39.0746x; 1.5782x over previous
//
#include <hip/hip_runtime.h>

typedef unsigned short u16;
typedef __attribute__((ext_vector_type(8))) short bf16x8;
typedef __attribute__((ext_vector_type(4))) float f32x4;

__device__ __forceinline__ u16 f2b(float f){
  unsigned u = __float_as_uint(f);
  unsigned r = ((u>>16)&1u) + 0x7fffu;
  return (u16)((u+r)>>16);
}

// WT arena offsets (f32 elements) -- v-path weights (transposed), biases, LN params
#define O_WH0   0        // [65][66]  wh0_t[k*66+h]
#define O_WV0   49474    // [65][32]
#define O_WH1   51554    // [32][32]
#define O_WV1   73058    // [32][32]
#define O_WH2   74082    // [32][32]
#define O_WV2   95586    // [32][32]
#define O_FF0H  96610    // [32][64]
#define O_FF0S  98658    // [192][512]
#define O_FF0V  196962   // [64][64]
#define O_FF1H  201058   // [64][64]
#define O_FF1S  205154   // [576][128]
#define O_FF1V  278882   // [64][32]
#define O_B0    280930
#define O_B1    281058
#define O_B2    281186
#define O_FB0   281314
#define O_FB1   281826
#define O_LN0G  281954
#define O_LN0B  282082
#define O_LN1G  282210
#define O_LN1B  282338
#define WT_TOTAL 282466

// WB bf16 arena: s-path weights, original [O][K] layout, K padded
#define WB0 0        // [128][384] (wsw0, K=353 zero-padded)
#define WB1 49152    // [128][160]
#define WB2 69632    // [128][160]
#define WB_TOTAL 90112

// ---------- weight transpose into WT arena ----------
struct TJob { const float* src; int off, O, K, P; };
struct TJobs { TJob j[24]; int prefix[25]; };

__global__ __launch_bounds__(256) void k_transpose(TJobs J, float* __restrict__ WT){
  int t = blockIdx.x*256 + threadIdx.x;
  if (t >= J.prefix[24]) return;
  for (int i=0;i<24;i++){
    if (t < J.prefix[i+1]){
      TJob jb = J.j[i];
      int local = t - J.prefix[i];
      int k = local / jb.P, o = local - k*jb.P;
      WT[jb.off + local] = (o < jb.O) ? jb.src[(size_t)o*jb.K + k] : 0.f;
      return;
    }
  }
}

__global__ __launch_bounds__(256) void k_wb(const float* __restrict__ w0,
                                            const float* __restrict__ w1,
                                            const float* __restrict__ w2,
                                            u16* __restrict__ WB){
  int t = blockIdx.x*256 + threadIdx.x;
  if (t < 128*384){
    int o = t/384, k = t - o*384;
    WB[WB0 + t] = f2b(k < 353 ? w0[(size_t)o*353 + k] : 0.f);
    return;
  }
  t -= 128*384;
  if (t < 128*160){ WB[WB1 + t] = f2b(w1[t]); return; }
  t -= 128*160;
  if (t < 128*160){ WB[WB2 + t] = f2b(w2[t]); return; }
}

// ---------- kernel V: edge vector path (3 stages) + vn writes + agg_v ----------
#define EPB 16
__global__ __launch_bounds__(256) void k_edge_v(
    const float* __restrict__ node_v, const float* __restrict__ edge_v,
    const int* __restrict__ ei, int E,
    const float* __restrict__ WT, u16* __restrict__ vnbuf,
    float* __restrict__ agg_v, float* __restrict__ cnt, int eb, int ec)
{
  __shared__ float VH[EPB*3][66];
  __shared__ float VB[EPB*3][33];
  __shared__ int   SD[EPB][2];
  const int tid = threadIdx.x;
  const int e = tid>>4, p = tid&15;
  const int le0 = blockIdx.x*EPB;

  if (tid < EPB*2){
    int ee = tid>>1, which = tid&1;
    int le = le0+ee;
    SD[ee][which] = (le<ec) ? ei[(size_t)which*E + eb + le] : 0;
  }
  __syncthreads();
  for (int u=tid; u<EPB*198; u+=256){
    int ee = u/198, r = u - ee*198, d = r/66, k = r - d*66;
    int le = le0+ee; float v = 0.f;
    if (le<ec && k<65){
      int g = eb+le;
      if (k<32)       v = node_v[(size_t)SD[ee][0]*96 + k*3 + d];
      else if (k==32) v = edge_v[(size_t)g*3 + d];
      else            v = node_v[(size_t)SD[ee][1]*96 + (k-33)*3 + d];
    }
    VH[ee*3+d][k] = v;
  }
  __syncthreads();

  const int le = le0 + e;
  const bool live = le < ec;
  const int dste = SD[e][1];

  // vh0 = mv @ wh0^T (65->65), vn0
  float a0[5], a1[5], a2[5];
  #pragma unroll
  for (int j=0;j<5;++j){ a0[j]=0.f; a1[j]=0.f; a2[j]=0.f; }
  for (int k=0;k<65;++k){
    float x0 = VH[e*3+0][k], x1 = VH[e*3+1][k], x2 = VH[e*3+2][k];
    const float* wr = WT + O_WH0 + k*66;
    #pragma unroll
    for (int j=0;j<5;++j){
      int h = p + 16*j;
      if (h < 65){ float wv = wr[h]; a0[j]+=x0*wv; a1[j]+=x1*wv; a2[j]+=x2*wv; }
    }
  }
  if (live){
    #pragma unroll
    for (int j=0;j<5;++j){
      int h = p + 16*j;
      if (h < 65) vnbuf[(size_t)le*132 + h] = f2b(sqrtf(fmaxf(a0[j]*a0[j]+a1[j]*a1[j]+a2[j]*a2[j], 1e-8f)));
    }
  }
  __syncthreads();
  #pragma unroll
  for (int j=0;j<5;++j){
    int h = p + 16*j;
    if (h < 65){ VH[e*3+0][h]=a0[j]; VH[e*3+1][h]=a1[j]; VH[e*3+2][h]=a2[j]; }
  }
  __syncthreads();

  // v0 = gate(vh0 @ wv0^T) -> VB
  {
    float v0[2][3];
    #pragma unroll
    for (int j=0;j<2;++j){ v0[j][0]=0.f; v0[j][1]=0.f; v0[j][2]=0.f; }
    for (int h=0;h<65;++h){
      float x0 = VH[e*3+0][h], x1 = VH[e*3+1][h], x2 = VH[e*3+2][h];
      const float* wr = WT + O_WV0 + h*32 + p;
      #pragma unroll
      for (int j=0;j<2;++j){ float wv = wr[16*j]; v0[j][0]+=x0*wv; v0[j][1]+=x1*wv; v0[j][2]+=x2*wv; }
    }
    #pragma unroll
    for (int j=0;j<2;++j){
      float nn = sqrtf(fmaxf(v0[j][0]*v0[j][0]+v0[j][1]*v0[j][1]+v0[j][2]*v0[j][2], 1e-8f));
      float sg = 1.f/(1.f + __expf(-nn));
      VB[e*3+0][p+16*j] = v0[j][0]*sg;
      VB[e*3+1][p+16*j] = v0[j][1]*sg;
      VB[e*3+2][p+16*j] = v0[j][2]*sg;
    }
  }
  __syncthreads();

  // vh1 = v0 @ wh1^T, vn1; overwrite VH
  float bh[2][3];
  #pragma unroll
  for (int j=0;j<2;++j){ bh[j][0]=0.f; bh[j][1]=0.f; bh[j][2]=0.f; }
  for (int k=0;k<32;++k){
    float x0 = VB[e*3+0][k], x1 = VB[e*3+1][k], x2 = VB[e*3+2][k];
    const float* wr = WT + O_WH1 + k*32 + p;
    #pragma unroll
    for (int j=0;j<2;++j){ float wv = wr[16*j]; bh[j][0]+=x0*wv; bh[j][1]+=x1*wv; bh[j][2]+=x2*wv; }
  }
  if (live){
    #pragma unroll
    for (int j=0;j<2;++j)
      vnbuf[(size_t)le*132 + 65 + p+16*j] = f2b(sqrtf(fmaxf(bh[j][0]*bh[j][0]+bh[j][1]*bh[j][1]+bh[j][2]*bh[j][2], 1e-8f)));
  }
  #pragma unroll
  for (int j=0;j<2;++j){ VH[e*3+0][p+16*j]=bh[j][0]; VH[e*3+1][p+16*j]=bh[j][1]; VH[e*3+2][p+16*j]=bh[j][2]; }
  __syncthreads();

  // v1 = gate(vh1 @ wv1^T) -> VB
  {
    float v0[2][3];
    #pragma unroll
    for (int j=0;j<2;++j){ v0[j][0]=0.f; v0[j][1]=0.f; v0[j][2]=0.f; }
    for (int h=0;h<32;++h){
      float x0 = VH[e*3+0][h], x1 = VH[e*3+1][h], x2 = VH[e*3+2][h];
      const float* wr = WT + O_WV1 + h*32 + p;
      #pragma unroll
      for (int j=0;j<2;++j){ float wv = wr[16*j]; v0[j][0]+=x0*wv; v0[j][1]+=x1*wv; v0[j][2]+=x2*wv; }
    }
    #pragma unroll
    for (int j=0;j<2;++j){
      float nn = sqrtf(fmaxf(v0[j][0]*v0[j][0]+v0[j][1]*v0[j][1]+v0[j][2]*v0[j][2], 1e-8f));
      float sg = 1.f/(1.f + __expf(-nn));
      VB[e*3+0][p+16*j] = v0[j][0]*sg;
      VB[e*3+1][p+16*j] = v0[j][1]*sg;
      VB[e*3+2][p+16*j] = v0[j][2]*sg;
    }
  }
  __syncthreads();

  // vh2 = v1 @ wh2^T, vn2; overwrite VH
  #pragma unroll
  for (int j=0;j<2;++j){ bh[j][0]=0.f; bh[j][1]=0.f; bh[j][2]=0.f; }
  for (int k=0;k<32;++k){
    float x0 = VB[e*3+0][k], x1 = VB[e*3+1][k], x2 = VB[e*3+2][k];
    const float* wr = WT + O_WH2 + k*32 + p;
    #pragma unroll
    for (int j=0;j<2;++j){ float wv = wr[16*j]; bh[j][0]+=x0*wv; bh[j][1]+=x1*wv; bh[j][2]+=x2*wv; }
  }
  if (live){
    #pragma unroll
    for (int j=0;j<2;++j)
      vnbuf[(size_t)le*132 + 97 + p+16*j] = f2b(sqrtf(fmaxf(bh[j][0]*bh[j][0]+bh[j][1]*bh[j][1]+bh[j][2]*bh[j][2], 1e-8f)));
  }
  #pragma unroll
  for (int j=0;j<2;++j){ VH[e*3+0][p+16*j]=bh[j][0]; VH[e*3+1][p+16*j]=bh[j][1]; VH[e*3+2][p+16*j]=bh[j][2]; }
  __syncthreads();

  // v2 = vh2 @ wv2^T (no gate) -> atomic agg
  {
    float v2[2][3];
    #pragma unroll
    for (int j=0;j<2;++j){ v2[j][0]=0.f; v2[j][1]=0.f; v2[j][2]=0.f; }
    for (int h=0;h<32;++h){
      float x0 = VH[e*3+0][h], x1 = VH[e*3+1][h], x2 = VH[e*3+2][h];
      const float* wr = WT + O_WV2 + h*32 + p;
      #pragma unroll
      for (int j=0;j<2;++j){ float wv = wr[16*j]; v2[j][0]+=x0*wv; v2[j][1]+=x1*wv; v2[j][2]+=x2*wv; }
    }
    if (live){
      #pragma unroll
      for (int j=0;j<2;++j){
        int vo = p + 16*j;
        atomicAdd(&agg_v[(size_t)dste*96 + vo*3 + 0], v2[j][0]);
        atomicAdd(&agg_v[(size_t)dste*96 + vo*3 + 1], v2[j][1]);
        atomicAdd(&agg_v[(size_t)dste*96 + vo*3 + 2], v2[j][2]);
      }
      if (p == 0) atomicAdd(&cnt[dste], 1.f);
    }
  }
}

// ---------- kernel S: gathered 3-stage MFMA GEMM chain + agg_s ----------
#define SPB 32
__global__ __launch_bounds__(512) void k_edge_s(
    const float* __restrict__ node_s, const float* __restrict__ edge_s,
    const int* __restrict__ ei, int E,
    const float* __restrict__ WT, const u16* __restrict__ WB,
    const u16* __restrict__ vnbuf,
    float* __restrict__ agg_s, int eb, int ec)
{
  __shared__ __align__(16) u16 A[SPB][392];
  __shared__ u16 VN1[SPB][32], VN2[SPB][32];
  __shared__ int SD[SPB][2];
  const int tid = threadIdx.x;
  const int le0 = blockIdx.x*SPB;

  if (tid < SPB*2){
    int ee = tid>>1, which = tid&1;
    int le = le0+ee;
    SD[ee][which] = (le<ec) ? ei[(size_t)which*E + eb + le] : 0;
  }
  __syncthreads();
  for (int u=tid; u<SPB*392; u+=512){
    int ee = u/392, i = u - ee*392;
    int le = le0+ee; u16 val = 0;
    if (le<ec){
      int g = eb+le;
      if (i<128)      val = f2b(node_s[(size_t)SD[ee][0]*128 + i]);
      else if (i<160) val = f2b(edge_s[(size_t)g*32 + (i-128)]);
      else if (i<288) val = f2b(node_s[(size_t)SD[ee][1]*128 + (i-160)]);
      else if (i<353) val = vnbuf[(size_t)le*132 + (i-288)];
    }
    A[ee][i] = val;
  }
  for (int u=tid; u<SPB*64; u+=512){
    int ee = u>>6, t = u&63;
    int le = le0+ee;
    u16 val = (le<ec) ? vnbuf[(size_t)le*132 + 65 + t] : 0;
    if (t<32) VN1[ee][t] = val; else VN2[ee][t-32] = val;
  }
  __syncthreads();

  const int w = tid>>6, l = tid&63;
  const int mt = w>>2, nt = w&3;
  const int n_a = nt*32 + (l&15), n_b = n_a + 16;
  const int kq = (l>>4)*8;
  const int ma = mt*16 + (l&15);
  f32x4 ca = {0.f,0.f,0.f,0.f}, cb = {0.f,0.f,0.f,0.f};

  // stage 0: K=384
  for (int kk=0; kk<384; kk+=32){
    bf16x8 af = *(const bf16x8*)&A[ma][kk + kq];
    bf16x8 b1 = *(const bf16x8*)&WB[WB0 + (size_t)n_a*384 + kk + kq];
    bf16x8 b2 = *(const bf16x8*)&WB[WB0 + (size_t)n_b*384 + kk + kq];
    ca = __builtin_amdgcn_mfma_f32_16x16x32_bf16(af, b1, ca, 0, 0, 0);
    cb = __builtin_amdgcn_mfma_f32_16x16x32_bf16(af, b2, cb, 0, 0, 0);
  }
  __syncthreads();
  {
    float ba = WT[O_B0 + n_a], bb = WT[O_B0 + n_b];
    #pragma unroll
    for (int j=0;j<4;++j){
      int r = mt*16 + (l>>4)*4 + j;
      A[r][n_a] = f2b(fmaxf(ca[j] + ba, 0.f));
      A[r][n_b] = f2b(fmaxf(cb[j] + bb, 0.f));
    }
  }
  for (int u=tid; u<SPB*32; u+=512) A[u>>5][128 + (u&31)] = VN1[u>>5][u&31];
  __syncthreads();

  // stage 1: K=160
  ca = (f32x4){0.f,0.f,0.f,0.f}; cb = (f32x4){0.f,0.f,0.f,0.f};
  for (int kk=0; kk<160; kk+=32){
    bf16x8 af = *(const bf16x8*)&A[ma][kk + kq];
    bf16x8 b1 = *(const bf16x8*)&WB[WB1 + (size_t)n_a*160 + kk + kq];
    bf16x8 b2 = *(const bf16x8*)&WB[WB1 + (size_t)n_b*160 + kk + kq];
    ca = __builtin_amdgcn_mfma_f32_16x16x32_bf16(af, b1, ca, 0, 0, 0);
    cb = __builtin_amdgcn_mfma_f32_16x16x32_bf16(af, b2, cb, 0, 0, 0);
  }
  __syncthreads();
  {
    float ba = WT[O_B1 + n_a], bb = WT[O_B1 + n_b];
    #pragma unroll
    for (int j=0;j<4;++j){
      int r = mt*16 + (l>>4)*4 + j;
      A[r][n_a] = f2b(fmaxf(ca[j] + ba, 0.f));
      A[r][n_b] = f2b(fmaxf(cb[j] + bb, 0.f));
    }
  }
  for (int u=tid; u<SPB*32; u+=512) A[u>>5][128 + (u&31)] = VN2[u>>5][u&31];
  __syncthreads();

  // stage 2: K=160, no relu, atomic aggregation
  ca = (f32x4){0.f,0.f,0.f,0.f}; cb = (f32x4){0.f,0.f,0.f,0.f};
  for (int kk=0; kk<160; kk+=32){
    bf16x8 af = *(const bf16x8*)&A[ma][kk + kq];
    bf16x8 b1 = *(const bf16x8*)&WB[WB2 + (size_t)n_a*160 + kk + kq];
    bf16x8 b2 = *(const bf16x8*)&WB[WB2 + (size_t)n_b*160 + kk + kq];
    ca = __builtin_amdgcn_mfma_f32_16x16x32_bf16(af, b1, ca, 0, 0, 0);
    cb = __builtin_amdgcn_mfma_f32_16x16x32_bf16(af, b2, cb, 0, 0, 0);
  }
  {
    float ba = WT[O_B2 + n_a], bb = WT[O_B2 + n_b];
    #pragma unroll
    for (int j=0;j<4;++j){
      int r = mt*16 + (l>>4)*4 + j;
      int le = le0 + r;
      if (le < ec){
        int dn = SD[r][1];
        atomicAdd(&agg_s[(size_t)dn*128 + n_a], ca[j] + ba);
        atomicAdd(&agg_s[(size_t)dn*128 + n_b], cb[j] + bb);
      }
    }
  }
}

// ---------- residual + tuple LayerNorm after aggregation ----------
__global__ __launch_bounds__(256) void k_ln0(
    const float* __restrict__ node_s, const float* __restrict__ node_v,
    const float* __restrict__ agg_s, const float* __restrict__ agg_v,
    const float* __restrict__ cnt, const float* __restrict__ WT,
    float* __restrict__ s_mid, float* __restrict__ v_mid, int N)
{
  int n = blockIdx.x*256 + threadIdx.x;
  if (n>=N) return;
  const float inv = 1.f/fmaxf(cnt[n], 1.f);
  float sum=0.f, ss=0.f;
  for (int i=0;i<128;++i){
    float x = node_s[(size_t)n*128+i] + agg_s[(size_t)n*128+i]*inv;
    sum += x; ss += x*x;
  }
  const float mu = sum*(1.f/128.f);
  const float var = fmaxf(ss*(1.f/128.f) - mu*mu, 0.f);
  const float rstd = rsqrtf(var + 1e-5f);
  for (int i=0;i<128;++i){
    float x = node_s[(size_t)n*128+i] + agg_s[(size_t)n*128+i]*inv;
    s_mid[(size_t)n*128+i] = (x-mu)*rstd*WT[O_LN0G+i] + WT[O_LN0B+i];
  }
  float vs=0.f;
  for (int vo=0;vo<32;++vo){
    float y0 = node_v[(size_t)n*96+vo*3+0] + agg_v[(size_t)n*96+vo*3+0]*inv;
    float y1 = node_v[(size_t)n*96+vo*3+1] + agg_v[(size_t)n*96+vo*3+1]*inv;
    float y2 = node_v[(size_t)n*96+vo*3+2] + agg_v[(size_t)n*96+vo*3+2]*inv;
    vs += fmaxf(y0*y0+y1*y1+y2*y2, 1e-8f);
  }
  const float scale = rsqrtf(vs*(1.f/32.f));
  for (int vo=0;vo<32;++vo){
    float y0 = node_v[(size_t)n*96+vo*3+0] + agg_v[(size_t)n*96+vo*3+0]*inv;
    float y1 = node_v[(size_t)n*96+vo*3+1] + agg_v[(size_t)n*96+vo*3+1]*inv;
    float y2 = node_v[(size_t)n*96+vo*3+2] + agg_v[(size_t)n*96+vo*3+2]*inv;
    v_mid[(size_t)n*96+vo]      = y0*scale;   // d-major [n][3][32]
    v_mid[(size_t)n*96+32+vo]   = y1*scale;
    v_mid[(size_t)n*96+64+vo]   = y2*scale;
  }
}

// ---------- fused node feed-forward (2 GVPs) + final LN -> d_out ----------
#define NPB 8
__global__ __launch_bounds__(256) void k_node_fused(
    const float* __restrict__ s_mid, const float* __restrict__ v_mid,
    const float* __restrict__ WT, float* __restrict__ out, int N)
{
  __shared__ float ASn[NPB][770];
  __shared__ float VHn[NPB*3][66];
  __shared__ float Vin[NPB*3][33];
  __shared__ float Vff[NPB*3][66];
  const int tid = threadIdx.x;
  const int nd = tid>>5, p = tid&31;
  const int n0 = blockIdx.x*NPB;
  const int n = n0 + nd;
  const bool live = n < N;

  for (int u=tid; u<NPB*128; u+=256){
    int d2 = u>>7, i = u&127;
    ASn[d2][i] = (n0+d2 < N) ? s_mid[(size_t)(n0+d2)*128 + i] : 0.f;
  }
  for (int u=tid; u<NPB*96; u+=256){
    int d2 = u/96, r = u - d2*96;
    Vin[d2*3 + (r>>5)][r&31] = (n0+d2 < N) ? v_mid[(size_t)(n0+d2)*96 + r] : 0.f;
  }
  __syncthreads();

  {
    float a[2][3];
    #pragma unroll
    for (int j=0;j<2;++j){ a[j][0]=0.f; a[j][1]=0.f; a[j][2]=0.f; }
    for (int k=0;k<32;++k){
      float x0 = Vin[nd*3+0][k], x1 = Vin[nd*3+1][k], x2 = Vin[nd*3+2][k];
      const float* wr = WT + O_FF0H + k*64 + p;
      #pragma unroll
      for (int j=0;j<2;++j){ float wv = wr[32*j]; a[j][0]+=x0*wv; a[j][1]+=x1*wv; a[j][2]+=x2*wv; }
    }
    #pragma unroll
    for (int j=0;j<2;++j)
      ASn[nd][128+p+32*j] = sqrtf(fmaxf(a[j][0]*a[j][0]+a[j][1]*a[j][1]+a[j][2]*a[j][2], 1e-8f));
    __syncthreads();
    #pragma unroll
    for (int j=0;j<2;++j){ VHn[nd*3+0][p+32*j]=a[j][0]; VHn[nd*3+1][p+32*j]=a[j][1]; VHn[nd*3+2][p+32*j]=a[j][2]; }
    __syncthreads();
  }
  {
    float s[16];
    #pragma unroll
    for (int j=0;j<16;++j) s[j] = WT[O_FB0 + p + 32*j];
    for (int k=0;k<192;++k){
      float av = ASn[nd][k];
      const float* wr = WT + O_FF0S + k*512 + p;
      #pragma unroll
      for (int j=0;j<16;++j) s[j] += av * wr[32*j];
    }
    float a[2][3];
    #pragma unroll
    for (int j=0;j<2;++j){ a[j][0]=0.f; a[j][1]=0.f; a[j][2]=0.f; }
    for (int h=0;h<64;++h){
      float x0 = VHn[nd*3+0][h], x1 = VHn[nd*3+1][h], x2 = VHn[nd*3+2][h];
      const float* wr = WT + O_FF0V + h*64 + p;
      #pragma unroll
      for (int j=0;j<2;++j){ float wv = wr[32*j]; a[j][0]+=x0*wv; a[j][1]+=x1*wv; a[j][2]+=x2*wv; }
    }
    #pragma unroll
    for (int j=0;j<2;++j){
      float nn = sqrtf(fmaxf(a[j][0]*a[j][0]+a[j][1]*a[j][1]+a[j][2]*a[j][2], 1e-8f));
      float sg = 1.f/(1.f + __expf(-nn));
      Vff[nd*3+0][p+32*j] = a[j][0]*sg;
      Vff[nd*3+1][p+32*j] = a[j][1]*sg;
      Vff[nd*3+2][p+32*j] = a[j][2]*sg;
    }
    __syncthreads();
    #pragma unroll
    for (int j=0;j<16;++j) ASn[nd][192 + p + 32*j] = fmaxf(s[j], 0.f);
    __syncthreads();
  }
  {
    float a[2][3];
    #pragma unroll
    for (int j=0;j<2;++j){ a[j][0]=0.f; a[j][1]=0.f; a[j][2]=0.f; }
    for (int k=0;k<64;++k){
      float x0 = Vff[nd*3+0][k], x1 = Vff[nd*3+1][k], x2 = Vff[nd*3+2][k];
      const float* wr = WT + O_FF1H + k*64 + p;
      #pragma unroll
      for (int j=0;j<2;++j){ float wv = wr[32*j]; a[j][0]+=x0*wv; a[j][1]+=x1*wv; a[j][2]+=x2*wv; }
    }
    #pragma unroll
    for (int j=0;j<2;++j)
      ASn[nd][704+p+32*j] = sqrtf(fmaxf(a[j][0]*a[j][0]+a[j][1]*a[j][1]+a[j][2]*a[j][2], 1e-8f));
    __syncthreads();
    #pragma unroll
    for (int j=0;j<2;++j){ VHn[nd*3+0][p+32*j]=a[j][0]; VHn[nd*3+1][p+32*j]=a[j][1]; VHn[nd*3+2][p+32*j]=a[j][2]; }
    __syncthreads();
  }
  float f[4];
  #pragma unroll
  for (int j=0;j<4;++j) f[j] = WT[O_FB1 + p + 32*j];
  for (int k=0;k<576;++k){
    float av = ASn[nd][192+k];
    const float* wr = WT + O_FF1S + k*128 + p;
    #pragma unroll
    for (int j=0;j<4;++j) f[j] += av * wr[32*j];
  }
  float y0=0.f, y1=0.f, y2=0.f;
  for (int h=0;h<64;++h){
    float wv = WT[O_FF1V + h*32 + p];
    y0 += VHn[nd*3+0][h]*wv;
    y1 += VHn[nd*3+1][h]*wv;
    y2 += VHn[nd*3+2][h]*wv;
  }
  float xs[4], sum=0.f, ss=0.f;
  #pragma unroll
  for (int j=0;j<4;++j){
    xs[j] = ASn[nd][p+32*j] + f[j];
    sum += xs[j]; ss += xs[j]*xs[j];
  }
  #pragma unroll
  for (int m=1; m<32; m<<=1){ sum += __shfl_xor(sum, m); ss += __shfl_xor(ss, m); }
  const float mu = sum*(1.f/128.f);
  const float var = fmaxf(ss*(1.f/128.f) - mu*mu, 0.f);
  const float rstd = rsqrtf(var + 1e-5f);
  if (live){
    #pragma unroll
    for (int j=0;j<4;++j){
      int o = p + 32*j;
      out[(size_t)n*128 + o] = (xs[j]-mu)*rstd*WT[O_LN1G+o] + WT[O_LN1B+o];
    }
  }
  float z0 = Vin[nd*3+0][p] + y0;
  float z1 = Vin[nd*3+1][p] + y1;
  float z2 = Vin[nd*3+2][p] + y2;
  float vs = fmaxf(z0*z0+z1*z1+z2*z2, 1e-8f);
  #pragma unroll
  for (int m=1; m<32; m<<=1) vs += __shfl_xor(vs, m);
  const float scale = rsqrtf(vs*(1.f/32.f));
  if (live){
    size_t base = (size_t)N*128 + (size_t)n*96 + (size_t)p*3;
    out[base+0] = z0*scale;
    out[base+1] = z1*scale;
    out[base+2] = z2*scale;
  }
}

extern "C" void kernel_launch(void* const* d_in, const int* in_sizes, int n_in,
                              void* d_out, int out_size, void* d_ws, size_t ws_size,
                              hipStream_t stream)
{
  (void)n_in; (void)out_size;
  const int N = in_sizes[0]/128;
  const int E = in_sizes[4]/2;
  const int* ei = (const int*)d_in[4];

  size_t off = 0;
  auto alloc = [&](size_t bytes)->char*{
    size_t o = (off + 255) & ~(size_t)255;
    off = o + bytes;
    return (char*)d_ws + o;
  };
  float* WT    = (float*)alloc((size_t)WT_TOTAL*4);
  u16*   WB    = (u16*)alloc((size_t)WB_TOTAL*2);
  float* agg_s = (float*)alloc((size_t)N*128*4);
  float* agg_v = (float*)alloc((size_t)N*96*4);
  float* cnt   = (float*)alloc((size_t)N*4);
  size_t aggBytes = (size_t)((char*)(cnt+N) - (char*)agg_s);
  float* s_mid = (float*)alloc((size_t)N*128*4);
  float* v_mid = (float*)alloc((size_t)N*96*4);
  const size_t persist_end = off;

  // vn chunk buffer within remaining ws
  size_t avail = (ws_size > persist_end + (1u<<20)) ? (ws_size - persist_end - (1u<<20)) : 0;
  long EC = (long)(avail / 264);
  if (EC < 8192) EC = 8192;
  if (EC > E) EC = E;
  u16* vnbuf = (u16*)alloc((size_t)EC*132*2);

  TJobs J; int np=0, pos=0;
  auto addj = [&](const void* src, int o_, int O, int K, int P){
    J.j[np].src=(const float*)src; J.j[np].off=o_; J.j[np].O=O; J.j[np].K=K; J.j[np].P=P;
    J.prefix[np]=pos; pos += K*P; ++np;
  };
  addj(d_in[5],  O_WH0,  65, 65, 66);
  addj(d_in[8],  O_WV0,  32, 65, 32);
  addj(d_in[9],  O_WH1,  32, 32, 32);
  addj(d_in[12], O_WV1,  32, 32, 32);
  addj(d_in[13], O_WH2,  32, 32, 32);
  addj(d_in[16], O_WV2,  32, 32, 32);
  addj(d_in[19], O_FF0H, 64, 32, 64);
  addj(d_in[20], O_FF0S, 512, 192, 512);
  addj(d_in[22], O_FF0V, 64, 64, 64);
  addj(d_in[23], O_FF1H, 64, 64, 64);
  addj(d_in[24], O_FF1S, 128, 576, 128);
  addj(d_in[26], O_FF1V, 32, 64, 32);
  addj(d_in[7],  O_B0,   128, 1, 128);
  addj(d_in[11], O_B1,   128, 1, 128);
  addj(d_in[15], O_B2,   128, 1, 128);
  addj(d_in[21], O_FB0,  512, 1, 512);
  addj(d_in[25], O_FB1,  128, 1, 128);
  addj(d_in[17], O_LN0G, 128, 1, 128);
  addj(d_in[18], O_LN0B, 128, 1, 128);
  addj(d_in[27], O_LN1G, 128, 1, 128);
  addj(d_in[28], O_LN1B, 128, 1, 128);
  for (int i=np; i<24; ++i){ J.j[i]=J.j[np-1]; J.prefix[i]=pos; }
  J.prefix[24] = pos;

  hipMemsetAsync(agg_s, 0, aggBytes, stream);
  k_transpose<<<dim3((pos+255)/256), dim3(256), 0, stream>>>(J, WT);
  k_wb<<<dim3((128*384 + 2*128*160 + 255)/256), dim3(256), 0, stream>>>(
      (const float*)d_in[6], (const float*)d_in[10], (const float*)d_in[14], WB);

  const int nch = (int)((E + EC - 1)/EC);
  for (int c=0; c<nch; ++c){
    const int eb = c*(int)EC;
    int ec = E - eb; if (ec > (int)EC) ec = (int)EC;
    if (ec <= 0) break;
    k_edge_v<<<dim3((ec+EPB-1)/EPB), dim3(256), 0, stream>>>(
        (const float*)d_in[1], (const float*)d_in[3], ei, E, WT, vnbuf, agg_v, cnt, eb, ec);
    k_edge_s<<<dim3((ec+SPB-1)/SPB), dim3(512), 0, stream>>>(
        (const float*)d_in[0], (const float*)d_in[2], ei, E, WT, WB, vnbuf, agg_s, eb, ec);
  }

  k_ln0<<<dim3((N+255)/256), dim3(256), 0, stream>>>(
      (const float*)d_in[0], (const float*)d_in[1], agg_s, agg_v, cnt, WT, s_mid, v_mid, N);

  k_node_fused<<<dim3((N+NPB-1)/NPB), dim3(256), 0, stream>>>(s_mid, v_mid, WT, (float*)d_out, N);
}

// Round 10
// 926.240 us; speedup vs baseline: 44.5230x; 1.1394x over previous
//
#include <hip/hip_runtime.h>

typedef unsigned short u16;
typedef __attribute__((ext_vector_type(8))) short bf16x8;
typedef __attribute__((ext_vector_type(4))) float f32x4;

__device__ __forceinline__ float b2f(u16 h){ return __uint_as_float(((unsigned)h)<<16); }
__device__ __forceinline__ u16 f2b(float f){
  unsigned u = __float_as_uint(f);
  unsigned r = ((u>>16)&1u) + 0x7fffu;
  return (u16)((u+r)>>16);
}

// WT arena offsets (f32) -- ff weights (transposed), biases, LN params
#define O_FF0H  96610    // [32][64]
#define O_FF0S  98658    // [192][512]
#define O_FF0V  196962   // [64][64]
#define O_FF1H  201058   // [64][64]
#define O_FF1S  205154   // [576][128]
#define O_FF1V  278882   // [64][32]
#define O_B0    280930
#define O_B1    281058
#define O_B2    281186
#define O_FB0   281314
#define O_FB1   281826
#define O_LN0G  281954
#define O_LN0B  282082
#define O_LN1G  282210
#define O_LN1B  282338
#define WT_TOTAL 282466

// WB bf16 arena: s-path weights, [O][K] layout, K padded
#define WB0 0        // [128][384]
#define WB1 49152    // [128][160]
#define WB2 69632    // [128][160]
#define WB_TOTAL 90112

// WVb bf16 arena: v-path weights, [N_pad][K_pad] layout
#define V_WH0 0      // [80][96]  (65x65 real)
#define V_WV0 7680   // [32][96]  (32x65 real)
#define V_WH1 10752  // [32][32]
#define V_WV1 11776
#define V_WH2 12800
#define V_WV2 13824
#define WV_TOTAL 14848

// ---------- weight transpose into WT arena ----------
struct TJob { const float* src; int off, O, K, P; };
struct TJobs { TJob j[24]; int prefix[25]; };

__global__ __launch_bounds__(256) void k_transpose(TJobs J, float* __restrict__ WT){
  int t = blockIdx.x*256 + threadIdx.x;
  if (t >= J.prefix[24]) return;
  for (int i=0;i<24;i++){
    if (t < J.prefix[i+1]){
      TJob jb = J.j[i];
      int local = t - J.prefix[i];
      int k = local / jb.P, o = local - k*jb.P;
      WT[jb.off + local] = (o < jb.O) ? jb.src[(size_t)o*jb.K + k] : 0.f;
      return;
    }
  }
}

__global__ __launch_bounds__(256) void k_wb(const float* __restrict__ w0,
                                            const float* __restrict__ w1,
                                            const float* __restrict__ w2,
                                            u16* __restrict__ WB){
  int t = blockIdx.x*256 + threadIdx.x;
  if (t < 128*384){
    int o = t/384, k = t - o*384;
    WB[WB0 + t] = f2b(k < 353 ? w0[(size_t)o*353 + k] : 0.f);
    return;
  }
  t -= 128*384;
  if (t < 128*160){ WB[WB1 + t] = f2b(w1[t]); return; }
  t -= 128*160;
  if (t < 128*160){ WB[WB2 + t] = f2b(w2[t]); return; }
}

__global__ __launch_bounds__(256) void k_wv(const float* __restrict__ wh0, const float* __restrict__ wv0,
    const float* __restrict__ wh1, const float* __restrict__ wv1,
    const float* __restrict__ wh2, const float* __restrict__ wv2,
    u16* __restrict__ WVb){
  int t = blockIdx.x*256 + threadIdx.x;
  if (t < 80*96){
    int n=t/96, k=t-n*96;
    WVb[V_WH0+t] = f2b((n<65 && k<65) ? wh0[(size_t)n*65+k] : 0.f);
    return;
  }
  t -= 80*96;
  if (t < 32*96){
    int n=t/96, k=t-n*96;
    WVb[V_WV0+t] = f2b((k<65) ? wv0[(size_t)n*65+k] : 0.f);
    return;
  }
  t -= 32*96;
  if (t < 1024){ WVb[V_WH1+t]=f2b(wh1[t]); return; }
  t -= 1024;
  if (t < 1024){ WVb[V_WV1+t]=f2b(wv1[t]); return; }
  t -= 1024;
  if (t < 1024){ WVb[V_WH2+t]=f2b(wh2[t]); return; }
  t -= 1024;
  if (t < 1024){ WVb[V_WV2+t]=f2b(wv2[t]); return; }
}

// ---------- kernel V: batched-MFMA edge vector path + vn writes + agg_v ----------
// 32 edges/block -> M=96 rows (edge x d). Ping-pong bf16 LDS buffers.
#define VEPB 32
__global__ __launch_bounds__(256) void k_edge_v(
    const float* __restrict__ node_v, const float* __restrict__ edge_v,
    const int* __restrict__ ei, int E,
    const u16* __restrict__ WVb, u16* __restrict__ vnbuf,
    float* __restrict__ agg_v, float* __restrict__ cnt, int eb, int ec)
{
  __shared__ __align__(16) u16 B0[96][104];
  __shared__ __align__(16) u16 B1[96][104];
  __shared__ int SD[VEPB][2];
  const int tid = threadIdx.x;
  const int w = tid>>6, l = tid&63;
  const int le0 = blockIdx.x*VEPB;

  { // zero both buffers (pad-safety: stale bf16 bits could be NaN; 0*NaN=NaN)
    unsigned* z0 = (unsigned*)&B0[0][0];
    unsigned* z1 = (unsigned*)&B1[0][0];
    for (int u=tid; u<96*52; u+=256){ z0[u]=0u; z1[u]=0u; }
  }
  if (tid < VEPB*2){
    int ee=tid>>1, which=tid&1;
    int le = le0+ee;
    SD[ee][which] = (le<ec) ? ei[(size_t)which*E + eb + le] : 0;
  }
  __syncthreads();
  // stage mv into B0: row 3e+d, cols 0..64 (65..95 stay zero)
  for (int u=tid; u<VEPB*195; u+=256){
    int ee=u/195, r=u-ee*195, d=r/65, k=r-d*65;
    int le=le0+ee; float v=0.f;
    if (le<ec){
      int g = eb+le;
      if (k<32)       v = node_v[(size_t)SD[ee][0]*96 + k*3 + d];
      else if (k==32) v = edge_v[(size_t)g*3 + d];
      else            v = node_v[(size_t)SD[ee][1]*96 + (k-33)*3 + d];
    }
    B0[ee*3+d][k] = f2b(v);
  }
  if (tid < VEPB){
    int le=le0+tid;
    if (le<ec) atomicAdd(&cnt[SD[tid][1]], 1.f);
  }
  __syncthreads();

  // batched GEMM helper: C[96][NT*16] = A[96][Kp] @ W^T, W = WVb[woff] as [NT*16][Kp]
  auto mm = [&](const u16 (*A)[104], int woff, int Kp, int NT, u16 (*C)[104]){
    const int nks = Kp>>5;
    for (int t=w; t<6*NT; t+=4){
      int mt = t % 6, nt = t / 6;
      f32x4 acc = {0.f,0.f,0.f,0.f};
      for (int ks=0; ks<nks; ++ks){
        bf16x8 af = *(const bf16x8*)&A[mt*16 + (l&15)][ks*32 + (l>>4)*8];
        bf16x8 bf = *(const bf16x8*)&WVb[woff + (size_t)(nt*16 + (l&15))*Kp + ks*32 + (l>>4)*8];
        acc = __builtin_amdgcn_mfma_f32_16x16x32_bf16(af, bf, acc, 0, 0, 0);
      }
      const int col = nt*16 + (l&15);
      const int r0 = mt*16 + (l>>4)*4;
      C[r0+0][col]=f2b(acc[0]); C[r0+1][col]=f2b(acc[1]);
      C[r0+2][col]=f2b(acc[2]); C[r0+3][col]=f2b(acc[3]);
    }
  };

  // vh0 = mv @ wh0^T  (K=96pad, N=80pad)
  mm(B0, V_WH0, 96, 5, B1);
  __syncthreads();
  // vn0 (reads B1) || wv0: v0 = vh0 @ wv0^T -> B0 cols 0..31
  for (int u=tid; u<VEPB*65; u+=256){
    int ee=u/65, h=u-ee*65;
    int le=le0+ee;
    if (le<ec){
      float x0=b2f(B1[ee*3+0][h]), x1=b2f(B1[ee*3+1][h]), x2=b2f(B1[ee*3+2][h]);
      vnbuf[(size_t)le*132 + h] = f2b(sqrtf(fmaxf(x0*x0+x1*x1+x2*x2, 1e-8f)));
    }
  }
  mm(B1, V_WV0, 96, 2, B0);
  __syncthreads();
  // gate0 on B0
  for (int u=tid; u<VEPB*32; u+=256){
    int ee=u>>5, vo=u&31;
    float x0=b2f(B0[ee*3+0][vo]), x1=b2f(B0[ee*3+1][vo]), x2=b2f(B0[ee*3+2][vo]);
    float nn=sqrtf(fmaxf(x0*x0+x1*x1+x2*x2, 1e-8f));
    float sg=1.f/(1.f+__expf(-nn));
    B0[ee*3+0][vo]=f2b(x0*sg); B0[ee*3+1][vo]=f2b(x1*sg); B0[ee*3+2][vo]=f2b(x2*sg);
  }
  __syncthreads();
  // vh1 = v0 @ wh1^T
  mm(B0, V_WH1, 32, 2, B1);
  __syncthreads();
  // vn1 || wv1
  for (int u=tid; u<VEPB*32; u+=256){
    int ee=u>>5, h=u&31;
    int le=le0+ee;
    if (le<ec){
      float x0=b2f(B1[ee*3+0][h]), x1=b2f(B1[ee*3+1][h]), x2=b2f(B1[ee*3+2][h]);
      vnbuf[(size_t)le*132 + 65 + h] = f2b(sqrtf(fmaxf(x0*x0+x1*x1+x2*x2, 1e-8f)));
    }
  }
  mm(B1, V_WV1, 32, 2, B0);
  __syncthreads();
  // gate1 on B0
  for (int u=tid; u<VEPB*32; u+=256){
    int ee=u>>5, vo=u&31;
    float x0=b2f(B0[ee*3+0][vo]), x1=b2f(B0[ee*3+1][vo]), x2=b2f(B0[ee*3+2][vo]);
    float nn=sqrtf(fmaxf(x0*x0+x1*x1+x2*x2, 1e-8f));
    float sg=1.f/(1.f+__expf(-nn));
    B0[ee*3+0][vo]=f2b(x0*sg); B0[ee*3+1][vo]=f2b(x1*sg); B0[ee*3+2][vo]=f2b(x2*sg);
  }
  __syncthreads();
  // vh2 = v1 @ wh2^T
  mm(B0, V_WH2, 32, 2, B1);
  __syncthreads();
  // vn2 (B1) || wv2 from fragments -> atomic agg_v
  for (int u=tid; u<VEPB*32; u+=256){
    int ee=u>>5, h=u&31;
    int le=le0+ee;
    if (le<ec){
      float x0=b2f(B1[ee*3+0][h]), x1=b2f(B1[ee*3+1][h]), x2=b2f(B1[ee*3+2][h]);
      vnbuf[(size_t)le*132 + 97 + h] = f2b(sqrtf(fmaxf(x0*x0+x1*x1+x2*x2, 1e-8f)));
    }
  }
  for (int t=w; t<12; t+=4){
    int mt = t % 6, nt = t / 6;
    f32x4 acc = {0.f,0.f,0.f,0.f};
    bf16x8 af = *(const bf16x8*)&B1[mt*16 + (l&15)][(l>>4)*8];
    bf16x8 bf = *(const bf16x8*)&WVb[V_WV2 + (size_t)(nt*16 + (l&15))*32 + (l>>4)*8];
    acc = __builtin_amdgcn_mfma_f32_16x16x32_bf16(af, bf, acc, 0, 0, 0);
    const int vo = nt*16 + (l&15);
    const int r0 = mt*16 + (l>>4)*4;
    #pragma unroll
    for (int j=0;j<4;++j){
      int r = r0 + j;
      int ee = r/3, d = r - ee*3;
      int le = le0 + ee;
      if (le < ec)
        atomicAdd(&agg_v[(size_t)SD[ee][1]*96 + vo*3 + d], acc[j]);
    }
  }
}

// ---------- kernel S: gathered 3-stage MFMA GEMM chain + agg_s ----------
#define SPB 32
__global__ __launch_bounds__(512) void k_edge_s(
    const float* __restrict__ node_s, const float* __restrict__ edge_s,
    const int* __restrict__ ei, int E,
    const float* __restrict__ WT, const u16* __restrict__ WB,
    const u16* __restrict__ vnbuf,
    float* __restrict__ agg_s, int eb, int ec)
{
  __shared__ __align__(16) u16 A[SPB][392];
  __shared__ u16 VN1[SPB][32], VN2[SPB][32];
  __shared__ int SD[SPB][2];
  const int tid = threadIdx.x;
  const int le0 = blockIdx.x*SPB;

  if (tid < SPB*2){
    int ee = tid>>1, which = tid&1;
    int le = le0+ee;
    SD[ee][which] = (le<ec) ? ei[(size_t)which*E + eb + le] : 0;
  }
  __syncthreads();
  for (int u=tid; u<SPB*392; u+=512){
    int ee = u/392, i = u - ee*392;
    int le = le0+ee; u16 val = 0;
    if (le<ec){
      int g = eb+le;
      if (i<128)      val = f2b(node_s[(size_t)SD[ee][0]*128 + i]);
      else if (i<160) val = f2b(edge_s[(size_t)g*32 + (i-128)]);
      else if (i<288) val = f2b(node_s[(size_t)SD[ee][1]*128 + (i-160)]);
      else if (i<353) val = vnbuf[(size_t)le*132 + (i-288)];
    }
    A[ee][i] = val;
  }
  for (int u=tid; u<SPB*64; u+=512){
    int ee = u>>6, t = u&63;
    int le = le0+ee;
    u16 val = (le<ec) ? vnbuf[(size_t)le*132 + 65 + t] : 0;
    if (t<32) VN1[ee][t] = val; else VN2[ee][t-32] = val;
  }
  __syncthreads();

  const int w = tid>>6, l = tid&63;
  const int mt = w>>2, nt = w&3;
  const int n_a = nt*32 + (l&15), n_b = n_a + 16;
  const int kq = (l>>4)*8;
  const int ma = mt*16 + (l&15);
  f32x4 ca = {0.f,0.f,0.f,0.f}, cb = {0.f,0.f,0.f,0.f};

  for (int kk=0; kk<384; kk+=32){
    bf16x8 af = *(const bf16x8*)&A[ma][kk + kq];
    bf16x8 b1 = *(const bf16x8*)&WB[WB0 + (size_t)n_a*384 + kk + kq];
    bf16x8 b2 = *(const bf16x8*)&WB[WB0 + (size_t)n_b*384 + kk + kq];
    ca = __builtin_amdgcn_mfma_f32_16x16x32_bf16(af, b1, ca, 0, 0, 0);
    cb = __builtin_amdgcn_mfma_f32_16x16x32_bf16(af, b2, cb, 0, 0, 0);
  }
  __syncthreads();
  {
    float ba = WT[O_B0 + n_a], bb = WT[O_B0 + n_b];
    #pragma unroll
    for (int j=0;j<4;++j){
      int r = mt*16 + (l>>4)*4 + j;
      A[r][n_a] = f2b(fmaxf(ca[j] + ba, 0.f));
      A[r][n_b] = f2b(fmaxf(cb[j] + bb, 0.f));
    }
  }
  for (int u=tid; u<SPB*32; u+=512) A[u>>5][128 + (u&31)] = VN1[u>>5][u&31];
  __syncthreads();

  ca = (f32x4){0.f,0.f,0.f,0.f}; cb = (f32x4){0.f,0.f,0.f,0.f};
  for (int kk=0; kk<160; kk+=32){
    bf16x8 af = *(const bf16x8*)&A[ma][kk + kq];
    bf16x8 b1 = *(const bf16x8*)&WB[WB1 + (size_t)n_a*160 + kk + kq];
    bf16x8 b2 = *(const bf16x8*)&WB[WB1 + (size_t)n_b*160 + kk + kq];
    ca = __builtin_amdgcn_mfma_f32_16x16x32_bf16(af, b1, ca, 0, 0, 0);
    cb = __builtin_amdgcn_mfma_f32_16x16x32_bf16(af, b2, cb, 0, 0, 0);
  }
  __syncthreads();
  {
    float ba = WT[O_B1 + n_a], bb = WT[O_B1 + n_b];
    #pragma unroll
    for (int j=0;j<4;++j){
      int r = mt*16 + (l>>4)*4 + j;
      A[r][n_a] = f2b(fmaxf(ca[j] + ba, 0.f));
      A[r][n_b] = f2b(fmaxf(cb[j] + bb, 0.f));
    }
  }
  for (int u=tid; u<SPB*32; u+=512) A[u>>5][128 + (u&31)] = VN2[u>>5][u&31];
  __syncthreads();

  ca = (f32x4){0.f,0.f,0.f,0.f}; cb = (f32x4){0.f,0.f,0.f,0.f};
  for (int kk=0; kk<160; kk+=32){
    bf16x8 af = *(const bf16x8*)&A[ma][kk + kq];
    bf16x8 b1 = *(const bf16x8*)&WB[WB2 + (size_t)n_a*160 + kk + kq];
    bf16x8 b2 = *(const bf16x8*)&WB[WB2 + (size_t)n_b*160 + kk + kq];
    ca = __builtin_amdgcn_mfma_f32_16x16x32_bf16(af, b1, ca, 0, 0, 0);
    cb = __builtin_amdgcn_mfma_f32_16x16x32_bf16(af, b2, cb, 0, 0, 0);
  }
  {
    float ba = WT[O_B2 + n_a], bb = WT[O_B2 + n_b];
    #pragma unroll
    for (int j=0;j<4;++j){
      int r = mt*16 + (l>>4)*4 + j;
      int le = le0 + r;
      if (le < ec){
        int dn = SD[r][1];
        atomicAdd(&agg_s[(size_t)dn*128 + n_a], ca[j] + ba);
        atomicAdd(&agg_s[(size_t)dn*128 + n_b], cb[j] + bb);
      }
    }
  }
}

// ---------- residual + tuple LayerNorm after aggregation ----------
__global__ __launch_bounds__(256) void k_ln0(
    const float* __restrict__ node_s, const float* __restrict__ node_v,
    const float* __restrict__ agg_s, const float* __restrict__ agg_v,
    const float* __restrict__ cnt, const float* __restrict__ WT,
    float* __restrict__ s_mid, float* __restrict__ v_mid, int N)
{
  int n = blockIdx.x*256 + threadIdx.x;
  if (n>=N) return;
  const float inv = 1.f/fmaxf(cnt[n], 1.f);
  float sum=0.f, ss=0.f;
  for (int i=0;i<128;++i){
    float x = node_s[(size_t)n*128+i] + agg_s[(size_t)n*128+i]*inv;
    sum += x; ss += x*x;
  }
  const float mu = sum*(1.f/128.f);
  const float var = fmaxf(ss*(1.f/128.f) - mu*mu, 0.f);
  const float rstd = rsqrtf(var + 1e-5f);
  for (int i=0;i<128;++i){
    float x = node_s[(size_t)n*128+i] + agg_s[(size_t)n*128+i]*inv;
    s_mid[(size_t)n*128+i] = (x-mu)*rstd*WT[O_LN0G+i] + WT[O_LN0B+i];
  }
  float vs=0.f;
  for (int vo=0;vo<32;++vo){
    float y0 = node_v[(size_t)n*96+vo*3+0] + agg_v[(size_t)n*96+vo*3+0]*inv;
    float y1 = node_v[(size_t)n*96+vo*3+1] + agg_v[(size_t)n*96+vo*3+1]*inv;
    float y2 = node_v[(size_t)n*96+vo*3+2] + agg_v[(size_t)n*96+vo*3+2]*inv;
    vs += fmaxf(y0*y0+y1*y1+y2*y2, 1e-8f);
  }
  const float scale = rsqrtf(vs*(1.f/32.f));
  for (int vo=0;vo<32;++vo){
    float y0 = node_v[(size_t)n*96+vo*3+0] + agg_v[(size_t)n*96+vo*3+0]*inv;
    float y1 = node_v[(size_t)n*96+vo*3+1] + agg_v[(size_t)n*96+vo*3+1]*inv;
    float y2 = node_v[(size_t)n*96+vo*3+2] + agg_v[(size_t)n*96+vo*3+2]*inv;
    v_mid[(size_t)n*96+vo]      = y0*scale;   // d-major [n][3][32]
    v_mid[(size_t)n*96+32+vo]   = y1*scale;
    v_mid[(size_t)n*96+64+vo]   = y2*scale;
  }
}

// ---------- fused node feed-forward (2 GVPs) + final LN -> d_out ----------
#define NPB 8
__global__ __launch_bounds__(256) void k_node_fused(
    const float* __restrict__ s_mid, const float* __restrict__ v_mid,
    const float* __restrict__ WT, float* __restrict__ out, int N)
{
  __shared__ float ASn[NPB][770];
  __shared__ float VHn[NPB*3][66];
  __shared__ float Vin[NPB*3][33];
  __shared__ float Vff[NPB*3][66];
  const int tid = threadIdx.x;
  const int nd = tid>>5, p = tid&31;
  const int n0 = blockIdx.x*NPB;
  const int n = n0 + nd;
  const bool live = n < N;

  for (int u=tid; u<NPB*128; u+=256){
    int d2 = u>>7, i = u&127;
    ASn[d2][i] = (n0+d2 < N) ? s_mid[(size_t)(n0+d2)*128 + i] : 0.f;
  }
  for (int u=tid; u<NPB*96; u+=256){
    int d2 = u/96, r = u - d2*96;
    Vin[d2*3 + (r>>5)][r&31] = (n0+d2 < N) ? v_mid[(size_t)(n0+d2)*96 + r] : 0.f;
  }
  __syncthreads();

  {
    float a[2][3];
    #pragma unroll
    for (int j=0;j<2;++j){ a[j][0]=0.f; a[j][1]=0.f; a[j][2]=0.f; }
    for (int k=0;k<32;++k){
      float x0 = Vin[nd*3+0][k], x1 = Vin[nd*3+1][k], x2 = Vin[nd*3+2][k];
      const float* wr = WT + O_FF0H + k*64 + p;
      #pragma unroll
      for (int j=0;j<2;++j){ float wv = wr[32*j]; a[j][0]+=x0*wv; a[j][1]+=x1*wv; a[j][2]+=x2*wv; }
    }
    #pragma unroll
    for (int j=0;j<2;++j)
      ASn[nd][128+p+32*j] = sqrtf(fmaxf(a[j][0]*a[j][0]+a[j][1]*a[j][1]+a[j][2]*a[j][2], 1e-8f));
    __syncthreads();
    #pragma unroll
    for (int j=0;j<2;++j){ VHn[nd*3+0][p+32*j]=a[j][0]; VHn[nd*3+1][p+32*j]=a[j][1]; VHn[nd*3+2][p+32*j]=a[j][2]; }
    __syncthreads();
  }
  {
    float s[16];
    #pragma unroll
    for (int j=0;j<16;++j) s[j] = WT[O_FB0 + p + 32*j];
    for (int k=0;k<192;++k){
      float av = ASn[nd][k];
      const float* wr = WT + O_FF0S + k*512 + p;
      #pragma unroll
      for (int j=0;j<16;++j) s[j] += av * wr[32*j];
    }
    float a[2][3];
    #pragma unroll
    for (int j=0;j<2;++j){ a[j][0]=0.f; a[j][1]=0.f; a[j][2]=0.f; }
    for (int h=0;h<64;++h){
      float x0 = VHn[nd*3+0][h], x1 = VHn[nd*3+1][h], x2 = VHn[nd*3+2][h];
      const float* wr = WT + O_FF0V + h*64 + p;
      #pragma unroll
      for (int j=0;j<2;++j){ float wv = wr[32*j]; a[j][0]+=x0*wv; a[j][1]+=x1*wv; a[j][2]+=x2*wv; }
    }
    #pragma unroll
    for (int j=0;j<2;++j){
      float nn = sqrtf(fmaxf(a[j][0]*a[j][0]+a[j][1]*a[j][1]+a[j][2]*a[j][2], 1e-8f));
      float sg = 1.f/(1.f + __expf(-nn));
      Vff[nd*3+0][p+32*j] = a[j][0]*sg;
      Vff[nd*3+1][p+32*j] = a[j][1]*sg;
      Vff[nd*3+2][p+32*j] = a[j][2]*sg;
    }
    __syncthreads();
    #pragma unroll
    for (int j=0;j<16;++j) ASn[nd][192 + p + 32*j] = fmaxf(s[j], 0.f);
    __syncthreads();
  }
  {
    float a[2][3];
    #pragma unroll
    for (int j=0;j<2;++j){ a[j][0]=0.f; a[j][1]=0.f; a[j][2]=0.f; }
    for (int k=0;k<64;++k){
      float x0 = Vff[nd*3+0][k], x1 = Vff[nd*3+1][k], x2 = Vff[nd*3+2][k];
      const float* wr = WT + O_FF1H + k*64 + p;
      #pragma unroll
      for (int j=0;j<2;++j){ float wv = wr[32*j]; a[j][0]+=x0*wv; a[j][1]+=x1*wv; a[j][2]+=x2*wv; }
    }
    #pragma unroll
    for (int j=0;j<2;++j)
      ASn[nd][704+p+32*j] = sqrtf(fmaxf(a[j][0]*a[j][0]+a[j][1]*a[j][1]+a[j][2]*a[j][2], 1e-8f));
    __syncthreads();
    #pragma unroll
    for (int j=0;j<2;++j){ VHn[nd*3+0][p+32*j]=a[j][0]; VHn[nd*3+1][p+32*j]=a[j][1]; VHn[nd*3+2][p+32*j]=a[j][2]; }
    __syncthreads();
  }
  float f[4];
  #pragma unroll
  for (int j=0;j<4;++j) f[j] = WT[O_FB1 + p + 32*j];
  for (int k=0;k<576;++k){
    float av = ASn[nd][192+k];
    const float* wr = WT + O_FF1S + k*128 + p;
    #pragma unroll
    for (int j=0;j<4;++j) f[j] += av * wr[32*j];
  }
  float y0=0.f, y1=0.f, y2=0.f;
  for (int h=0;h<64;++h){
    float wv = WT[O_FF1V + h*32 + p];
    y0 += VHn[nd*3+0][h]*wv;
    y1 += VHn[nd*3+1][h]*wv;
    y2 += VHn[nd*3+2][h]*wv;
  }
  float xs[4], sum=0.f, ss=0.f;
  #pragma unroll
  for (int j=0;j<4;++j){
    xs[j] = ASn[nd][p+32*j] + f[j];
    sum += xs[j]; ss += xs[j]*xs[j];
  }
  #pragma unroll
  for (int m=1; m<32; m<<=1){ sum += __shfl_xor(sum, m); ss += __shfl_xor(ss, m); }
  const float mu = sum*(1.f/128.f);
  const float var = fmaxf(ss*(1.f/128.f) - mu*mu, 0.f);
  const float rstd = rsqrtf(var + 1e-5f);
  if (live){
    #pragma unroll
    for (int j=0;j<4;++j){
      int o = p + 32*j;
      out[(size_t)n*128 + o] = (xs[j]-mu)*rstd*WT[O_LN1G+o] + WT[O_LN1B+o];
    }
  }
  float z0 = Vin[nd*3+0][p] + y0;
  float z1 = Vin[nd*3+1][p] + y1;
  float z2 = Vin[nd*3+2][p] + y2;
  float vs = fmaxf(z0*z0+z1*z1+z2*z2, 1e-8f);
  #pragma unroll
  for (int m=1; m<32; m<<=1) vs += __shfl_xor(vs, m);
  const float scale = rsqrtf(vs*(1.f/32.f));
  if (live){
    size_t base = (size_t)N*128 + (size_t)n*96 + (size_t)p*3;
    out[base+0] = z0*scale;
    out[base+1] = z1*scale;
    out[base+2] = z2*scale;
  }
}

extern "C" void kernel_launch(void* const* d_in, const int* in_sizes, int n_in,
                              void* d_out, int out_size, void* d_ws, size_t ws_size,
                              hipStream_t stream)
{
  (void)n_in; (void)out_size;
  const int N = in_sizes[0]/128;
  const int E = in_sizes[4]/2;
  const int* ei = (const int*)d_in[4];

  size_t off = 0;
  auto alloc = [&](size_t bytes)->char*{
    size_t o = (off + 255) & ~(size_t)255;
    off = o + bytes;
    return (char*)d_ws + o;
  };
  float* WT    = (float*)alloc((size_t)WT_TOTAL*4);
  u16*   WB    = (u16*)alloc((size_t)WB_TOTAL*2);
  u16*   WVb   = (u16*)alloc((size_t)WV_TOTAL*2);
  float* agg_s = (float*)alloc((size_t)N*128*4);
  float* agg_v = (float*)alloc((size_t)N*96*4);
  float* cnt   = (float*)alloc((size_t)N*4);
  size_t aggBytes = (size_t)((char*)(cnt+N) - (char*)agg_s);
  float* s_mid = (float*)alloc((size_t)N*128*4);
  float* v_mid = (float*)alloc((size_t)N*96*4);
  const size_t persist_end = off;

  size_t avail = (ws_size > persist_end + (1u<<20)) ? (ws_size - persist_end - (1u<<20)) : 0;
  long EC = (long)(avail / 264);
  if (EC < 8192) EC = 8192;
  if (EC > E) EC = E;
  u16* vnbuf = (u16*)alloc((size_t)EC*132*2);

  TJobs J; int np=0, pos=0;
  auto addj = [&](const void* src, int o_, int O, int K, int P){
    J.j[np].src=(const float*)src; J.j[np].off=o_; J.j[np].O=O; J.j[np].K=K; J.j[np].P=P;
    J.prefix[np]=pos; pos += K*P; ++np;
  };
  addj(d_in[19], O_FF0H, 64, 32, 64);
  addj(d_in[20], O_FF0S, 512, 192, 512);
  addj(d_in[22], O_FF0V, 64, 64, 64);
  addj(d_in[23], O_FF1H, 64, 64, 64);
  addj(d_in[24], O_FF1S, 128, 576, 128);
  addj(d_in[26], O_FF1V, 32, 64, 32);
  addj(d_in[7],  O_B0,   128, 1, 128);
  addj(d_in[11], O_B1,   128, 1, 128);
  addj(d_in[15], O_B2,   128, 1, 128);
  addj(d_in[21], O_FB0,  512, 1, 512);
  addj(d_in[25], O_FB1,  128, 1, 128);
  addj(d_in[17], O_LN0G, 128, 1, 128);
  addj(d_in[18], O_LN0B, 128, 1, 128);
  addj(d_in[27], O_LN1G, 128, 1, 128);
  addj(d_in[28], O_LN1B, 128, 1, 128);
  for (int i=np; i<24; ++i){ J.j[i]=J.j[np-1]; J.prefix[i]=pos; }
  J.prefix[24] = pos;

  hipMemsetAsync(agg_s, 0, aggBytes, stream);
  k_transpose<<<dim3((pos+255)/256), dim3(256), 0, stream>>>(J, WT);
  k_wb<<<dim3((128*384 + 2*128*160 + 255)/256), dim3(256), 0, stream>>>(
      (const float*)d_in[6], (const float*)d_in[10], (const float*)d_in[14], WB);
  k_wv<<<dim3((WV_TOTAL+255)/256), dim3(256), 0, stream>>>(
      (const float*)d_in[5], (const float*)d_in[8], (const float*)d_in[9],
      (const float*)d_in[12], (const float*)d_in[13], (const float*)d_in[16], WVb);

  const int nch = (int)((E + EC - 1)/EC);
  for (int c=0; c<nch; ++c){
    const int eb = c*(int)EC;
    int ec = E - eb; if (ec > (int)EC) ec = (int)EC;
    if (ec <= 0) break;
    k_edge_v<<<dim3((ec+VEPB-1)/VEPB), dim3(256), 0, stream>>>(
        (const float*)d_in[1], (const float*)d_in[3], ei, E, WVb, vnbuf, agg_v, cnt, eb, ec);
    k_edge_s<<<dim3((ec+SPB-1)/SPB), dim3(512), 0, stream>>>(
        (const float*)d_in[0], (const float*)d_in[2], ei, E, WT, WB, vnbuf, agg_s, eb, ec);
  }

  k_ln0<<<dim3((N+255)/256), dim3(256), 0, stream>>>(
      (const float*)d_in[0], (const float*)d_in[1], agg_s, agg_v, cnt, WT, s_mid, v_mid, N);

  k_node_fused<<<dim3((N+NPB-1)/NPB), dim3(256), 0, stream>>>(s_mid, v_mid, WT, (float*)d_out, N);
}

// Round 11
// 644.533 us; speedup vs baseline: 63.9828x; 1.4371x over previous
//
#include <hip/hip_runtime.h>

typedef unsigned short u16;
typedef __attribute__((ext_vector_type(8))) short bf16x8;
typedef __attribute__((ext_vector_type(4))) float f32x4;

__device__ __forceinline__ float b2f(u16 h){ return __uint_as_float(((unsigned)h)<<16); }
__device__ __forceinline__ u16 f2b(float f){
  unsigned u = __float_as_uint(f);
  unsigned r = ((u>>16)&1u) + 0x7fffu;
  return (u16)((u+r)>>16);
}
__device__ __forceinline__ short4 pack4(float4 f){
  short4 s; s.x=(short)f2b(f.x); s.y=(short)f2b(f.y); s.z=(short)f2b(f.z); s.w=(short)f2b(f.w);
  return s;
}

// WB bf16 arena: s-path weights, [O][K] layout
#define WB0   0        // [128][384] (wsw0, K=353 zero-padded)
#define WB1   49152    // [128][160]
#define WB2   69632    // [128][160]
#define WBF0  90112    // [512][192] ff0s
#define WBF1  188416   // [128][576] ff1s
#define WB_TOTAL 262144

// WVb bf16 arena: v-path weights, [N_pad][K_pad]
#define V_WH0   0      // [80][96]  (65x65 real, K permuted: src|dst|edge)
#define V_WV0   7680   // [32][96]  (32x65 real)
#define V_WH1   10752  // [32][32]
#define V_WV1   11776
#define V_WH2   12800
#define V_WV2   13824
#define NV_FF0H 14848  // [64][32]
#define NV_FF0V 16896  // [64][64]
#define NV_FF1H 20992  // [64][64]
#define NV_FF1V 25088  // [32][64]
#define WV_TOTAL 27136

// ---------- s-path weights -> bf16 ----------
__global__ __launch_bounds__(256) void k_wb(const float* __restrict__ w0,
    const float* __restrict__ w1, const float* __restrict__ w2,
    const float* __restrict__ f0, const float* __restrict__ f1,
    u16* __restrict__ WB){
  int t = blockIdx.x*256 + threadIdx.x;
  if (t < 49152){
    int o = t/384, k = t - o*384;
    WB[WB0 + t] = f2b(k < 353 ? w0[(size_t)o*353 + k] : 0.f);
    return;
  }
  t -= 49152;
  if (t < 20480){ WB[WB1 + t] = f2b(w1[t]); return; }
  t -= 20480;
  if (t < 20480){ WB[WB2 + t] = f2b(w2[t]); return; }
  t -= 20480;
  if (t < 98304){ WB[WBF0 + t] = f2b(f0[t]); return; }
  t -= 98304;
  if (t < 73728){ WB[WBF1 + t] = f2b(f1[t]); return; }
}

// ---------- v-path weights -> bf16 ----------
__global__ __launch_bounds__(256) void k_wv(const float* __restrict__ wh0, const float* __restrict__ wv0,
    const float* __restrict__ wh1, const float* __restrict__ wv1,
    const float* __restrict__ wh2, const float* __restrict__ wv2,
    const float* __restrict__ nf0h, const float* __restrict__ nf0v,
    const float* __restrict__ nf1h, const float* __restrict__ nf1v,
    u16* __restrict__ WVb){
  int t = blockIdx.x*256 + threadIdx.x;
  if (t < 7680){
    int n=t/96, k=t-n*96;
    float v = 0.f;
    if (n < 65){
      if (k < 32)       v = wh0[(size_t)n*65 + k];
      else if (k < 64)  v = wh0[(size_t)n*65 + 33 + (k-32)];
      else if (k == 64) v = wh0[(size_t)n*65 + 32];
    }
    WVb[V_WH0+t] = f2b(v);
    return;
  }
  t -= 7680;
  if (t < 3072){
    int n=t/96, k=t-n*96;
    WVb[V_WV0+t] = f2b((k<65) ? wv0[(size_t)n*65+k] : 0.f);
    return;
  }
  t -= 3072;
  if (t < 1024){ WVb[V_WH1+t]=f2b(wh1[t]); return; }
  t -= 1024;
  if (t < 1024){ WVb[V_WV1+t]=f2b(wv1[t]); return; }
  t -= 1024;
  if (t < 1024){ WVb[V_WH2+t]=f2b(wh2[t]); return; }
  t -= 1024;
  if (t < 1024){ WVb[V_WV2+t]=f2b(wv2[t]); return; }
  t -= 1024;
  if (t < 2048){ WVb[NV_FF0H+t]=f2b(nf0h[t]); return; }
  t -= 2048;
  if (t < 4096){ WVb[NV_FF0V+t]=f2b(nf0v[t]); return; }
  t -= 4096;
  if (t < 4096){ WVb[NV_FF1H+t]=f2b(nf1h[t]); return; }
  t -= 4096;
  if (t < 2048){ WVb[NV_FF1V+t]=f2b(nf1v[t]); return; }
}

// ---------- input prep: node_s -> bf16; node_v -> bf16 d-major [N][3][32] ----------
__global__ __launch_bounds__(256) void k_prep(const float* __restrict__ node_s,
    const float* __restrict__ node_v, u16* __restrict__ node_sb,
    u16* __restrict__ node_vb, int N){
  int t = blockIdx.x*256 + threadIdx.x;
  if (t < N*128){ node_sb[t] = f2b(node_s[t]); return; }
  t -= N*128;
  if (t < N*96){
    int n=t/96, r=t-n*96, d=r>>5, vo=r&31;
    node_vb[(size_t)n*96 + d*32 + vo] = f2b(node_v[(size_t)n*96 + vo*3 + d]);
  }
}

// ---------- kernel V: batched-MFMA edge vector path ----------
#define VEPB 32
__global__ __launch_bounds__(256) void k_edge_v(
    const u16* __restrict__ node_vb, const float* __restrict__ edge_v,
    const int* __restrict__ ei, int E,
    const u16* __restrict__ WVb, u16* __restrict__ vnbuf,
    float* __restrict__ agg_v, float* __restrict__ cnt, int eb, int ec)
{
  __shared__ __align__(16) u16 B0[96][104];
  __shared__ __align__(16) u16 B1[96][104];
  __shared__ int SD[VEPB][2];
  const int tid = threadIdx.x;
  const int w = tid>>6, l = tid&63;
  const int le0 = blockIdx.x*VEPB;

  if (tid < VEPB*2){
    int ee=tid>>1, which=tid&1;
    int le = le0+ee;
    SD[ee][which] = (le<ec) ? ei[(size_t)which*E + eb + le] : 0;
  }
  __syncthreads();
  // stage cols 0..63 (src|dst) as short4
  for (int u=tid; u<96*16; u+=256){
    int r=u>>4, g=u&15, ee=r/3, d=r-ee*3;
    int le=le0+ee;
    short4 v = {0,0,0,0};
    if (le<ec){
      int node = (g<8) ? SD[ee][0] : SD[ee][1];
      v = *(const short4*)&node_vb[(size_t)node*96 + d*32 + 4*(g&7)];
    }
    *(short4*)&B0[r][4*g] = v;
  }
  // cols 64..95: edge_v at 64, zeros elsewhere
  for (int u=tid; u<96*8; u+=256){
    int r=u>>3, g=u&7, ee=r/3, d=r-ee*3;
    int le=le0+ee;
    short4 v = {0,0,0,0};
    if (g==0 && le<ec) v.x = (short)f2b(edge_v[(size_t)(eb+le)*3 + d]);
    *(short4*)&B0[r][64+4*g] = v;
  }
  // B1 cols 80..95 zero (wv0 K=96 pad)
  for (int u=tid; u<96*4; u+=256){
    int r=u>>2, g=u&3;
    *(short4*)&B1[r][80+4*g] = (short4){0,0,0,0};
  }
  if (tid < VEPB){
    int le=le0+tid;
    if (le<ec) atomicAdd(&cnt[SD[tid][1]], 1.f);
  }
  __syncthreads();

  auto mm = [&](const u16 (*A)[104], int woff, int Kp, int NT, u16 (*C)[104]){
    const int nks = Kp>>5;
    for (int t=w; t<6*NT; t+=4){
      int mt = t % 6, nt = t / 6;
      f32x4 acc = {0.f,0.f,0.f,0.f};
      for (int ks=0; ks<nks; ++ks){
        bf16x8 af = *(const bf16x8*)&A[mt*16 + (l&15)][ks*32 + (l>>4)*8];
        bf16x8 bf = *(const bf16x8*)&WVb[woff + (size_t)(nt*16 + (l&15))*Kp + ks*32 + (l>>4)*8];
        acc = __builtin_amdgcn_mfma_f32_16x16x32_bf16(af, bf, acc, 0, 0, 0);
      }
      const int col = nt*16 + (l&15);
      const int r0 = mt*16 + (l>>4)*4;
      C[r0+0][col]=f2b(acc[0]); C[r0+1][col]=f2b(acc[1]);
      C[r0+2][col]=f2b(acc[2]); C[r0+3][col]=f2b(acc[3]);
    }
  };

  // vh0 = mv @ wh0^T
  mm(B0, V_WH0, 96, 5, B1);
  __syncthreads();
  // vn0 (pad to 80 with zeros) || v0 = vh0 @ wv0^T
  for (int u=tid; u<VEPB*80; u+=256){
    int ee=u/80, h=u-ee*80;
    int le=le0+ee;
    if (le<ec){
      u16 val = 0;
      if (h<65){
        float x0=b2f(B1[ee*3+0][h]), x1=b2f(B1[ee*3+1][h]), x2=b2f(B1[ee*3+2][h]);
        val = f2b(sqrtf(fmaxf(x0*x0+x1*x1+x2*x2, 1e-8f)));
      }
      vnbuf[(size_t)le*144 + h] = val;
    }
  }
  mm(B1, V_WV0, 96, 2, B0);
  __syncthreads();
  for (int u=tid; u<VEPB*32; u+=256){
    int ee=u>>5, vo=u&31;
    float x0=b2f(B0[ee*3+0][vo]), x1=b2f(B0[ee*3+1][vo]), x2=b2f(B0[ee*3+2][vo]);
    float nn=sqrtf(fmaxf(x0*x0+x1*x1+x2*x2, 1e-8f));
    float sg=1.f/(1.f+__expf(-nn));
    B0[ee*3+0][vo]=f2b(x0*sg); B0[ee*3+1][vo]=f2b(x1*sg); B0[ee*3+2][vo]=f2b(x2*sg);
  }
  __syncthreads();
  mm(B0, V_WH1, 32, 2, B1);
  __syncthreads();
  for (int u=tid; u<VEPB*32; u+=256){
    int ee=u>>5, h=u&31;
    int le=le0+ee;
    if (le<ec){
      float x0=b2f(B1[ee*3+0][h]), x1=b2f(B1[ee*3+1][h]), x2=b2f(B1[ee*3+2][h]);
      vnbuf[(size_t)le*144 + 80 + h] = f2b(sqrtf(fmaxf(x0*x0+x1*x1+x2*x2, 1e-8f)));
    }
  }
  mm(B1, V_WV1, 32, 2, B0);
  __syncthreads();
  for (int u=tid; u<VEPB*32; u+=256){
    int ee=u>>5, vo=u&31;
    float x0=b2f(B0[ee*3+0][vo]), x1=b2f(B0[ee*3+1][vo]), x2=b2f(B0[ee*3+2][vo]);
    float nn=sqrtf(fmaxf(x0*x0+x1*x1+x2*x2, 1e-8f));
    float sg=1.f/(1.f+__expf(-nn));
    B0[ee*3+0][vo]=f2b(x0*sg); B0[ee*3+1][vo]=f2b(x1*sg); B0[ee*3+2][vo]=f2b(x2*sg);
  }
  __syncthreads();
  mm(B0, V_WH2, 32, 2, B1);
  __syncthreads();
  for (int u=tid; u<VEPB*32; u+=256){
    int ee=u>>5, h=u&31;
    int le=le0+ee;
    if (le<ec){
      float x0=b2f(B1[ee*3+0][h]), x1=b2f(B1[ee*3+1][h]), x2=b2f(B1[ee*3+2][h]);
      vnbuf[(size_t)le*144 + 112 + h] = f2b(sqrtf(fmaxf(x0*x0+x1*x1+x2*x2, 1e-8f)));
    }
  }
  // v2 = vh2 @ wv2^T -> atomic agg
  for (int t=w; t<12; t+=4){
    int mt = t % 6, nt = t / 6;
    f32x4 acc = {0.f,0.f,0.f,0.f};
    bf16x8 af = *(const bf16x8*)&B1[mt*16 + (l&15)][(l>>4)*8];
    bf16x8 bf = *(const bf16x8*)&WVb[V_WV2 + (size_t)(nt*16 + (l&15))*32 + (l>>4)*8];
    acc = __builtin_amdgcn_mfma_f32_16x16x32_bf16(af, bf, acc, 0, 0, 0);
    const int vo = nt*16 + (l&15);
    const int r0 = mt*16 + (l>>4)*4;
    #pragma unroll
    for (int j=0;j<4;++j){
      int r = r0 + j;
      int ee = r/3, d = r - ee*3;
      int le = le0 + ee;
      if (le < ec)
        atomicAdd(&agg_v[(size_t)SD[ee][1]*96 + vo*3 + d], acc[j]);
    }
  }
}

// ---------- kernel S: gathered 3-stage MFMA GEMM chain + agg_s ----------
#define SPB 32
__global__ __launch_bounds__(512) void k_edge_s(
    const u16* __restrict__ node_sb, const float* __restrict__ edge_s,
    const int* __restrict__ ei, int E,
    const u16* __restrict__ WB, const u16* __restrict__ vnbuf,
    const float* __restrict__ b0p, const float* __restrict__ b1p, const float* __restrict__ b2p,
    float* __restrict__ agg_s, int eb, int ec)
{
  __shared__ __align__(16) u16 A[SPB][392];
  __shared__ int SD[SPB][2];
  const int tid = threadIdx.x;
  const int le0 = blockIdx.x*SPB;

  if (tid < SPB*2){
    int ee = tid>>1, which = tid&1;
    int le = le0+ee;
    SD[ee][which] = (le<ec) ? ei[(size_t)which*E + eb + le] : 0;
  }
  __syncthreads();
  for (int u=tid; u<SPB*98; u+=512){
    int ee = u/98, g = u - ee*98;
    int le = le0+ee;
    short4 v = {0,0,0,0};
    if (le<ec){
      if (g < 32)      v = *(const short4*)&node_sb[(size_t)SD[ee][0]*128 + 4*g];
      else if (g < 40) v = pack4(*(const float4*)&edge_s[(size_t)(eb+le)*32 + 4*(g-32)]);
      else if (g < 72) v = *(const short4*)&node_sb[(size_t)SD[ee][1]*128 + 4*(g-40)];
      else if (g < 92) v = *(const short4*)&vnbuf[(size_t)le*144 + 4*(g-72)];
    }
    *(short4*)&A[ee][4*g] = v;
  }
  __syncthreads();

  const int w = tid>>6, l = tid&63;
  const int mt = w>>2, nt = w&3;
  const int n_a = nt*32 + (l&15), n_b = n_a + 16;
  const int kq = (l>>4)*8;
  const int ma = mt*16 + (l&15);
  f32x4 ca = {0.f,0.f,0.f,0.f}, cb = {0.f,0.f,0.f,0.f};

  for (int kk=0; kk<384; kk+=32){
    bf16x8 af = *(const bf16x8*)&A[ma][kk + kq];
    bf16x8 b1 = *(const bf16x8*)&WB[WB0 + (size_t)n_a*384 + kk + kq];
    bf16x8 b2 = *(const bf16x8*)&WB[WB0 + (size_t)n_b*384 + kk + kq];
    ca = __builtin_amdgcn_mfma_f32_16x16x32_bf16(af, b1, ca, 0, 0, 0);
    cb = __builtin_amdgcn_mfma_f32_16x16x32_bf16(af, b2, cb, 0, 0, 0);
  }
  __syncthreads();
  {
    float ba = b0p[n_a], bb = b0p[n_b];
    #pragma unroll
    for (int j=0;j<4;++j){
      int r = mt*16 + (l>>4)*4 + j;
      A[r][n_a] = f2b(fmaxf(ca[j] + ba, 0.f));
      A[r][n_b] = f2b(fmaxf(cb[j] + bb, 0.f));
    }
  }
  for (int u=tid; u<SPB*8; u+=512){
    int ee=u>>3, q=u&7;
    int le=le0+ee;
    short4 v = {0,0,0,0};
    if (le<ec) v = *(const short4*)&vnbuf[(size_t)le*144 + 80 + 4*q];
    *(short4*)&A[ee][128+4*q] = v;
  }
  __syncthreads();

  ca = (f32x4){0.f,0.f,0.f,0.f}; cb = (f32x4){0.f,0.f,0.f,0.f};
  for (int kk=0; kk<160; kk+=32){
    bf16x8 af = *(const bf16x8*)&A[ma][kk + kq];
    bf16x8 b1 = *(const bf16x8*)&WB[WB1 + (size_t)n_a*160 + kk + kq];
    bf16x8 b2 = *(const bf16x8*)&WB[WB1 + (size_t)n_b*160 + kk + kq];
    ca = __builtin_amdgcn_mfma_f32_16x16x32_bf16(af, b1, ca, 0, 0, 0);
    cb = __builtin_amdgcn_mfma_f32_16x16x32_bf16(af, b2, cb, 0, 0, 0);
  }
  __syncthreads();
  {
    float ba = b1p[n_a], bb = b1p[n_b];
    #pragma unroll
    for (int j=0;j<4;++j){
      int r = mt*16 + (l>>4)*4 + j;
      A[r][n_a] = f2b(fmaxf(ca[j] + ba, 0.f));
      A[r][n_b] = f2b(fmaxf(cb[j] + bb, 0.f));
    }
  }
  for (int u=tid; u<SPB*8; u+=512){
    int ee=u>>3, q=u&7;
    int le=le0+ee;
    short4 v = {0,0,0,0};
    if (le<ec) v = *(const short4*)&vnbuf[(size_t)le*144 + 112 + 4*q];
    *(short4*)&A[ee][128+4*q] = v;
  }
  __syncthreads();

  ca = (f32x4){0.f,0.f,0.f,0.f}; cb = (f32x4){0.f,0.f,0.f,0.f};
  for (int kk=0; kk<160; kk+=32){
    bf16x8 af = *(const bf16x8*)&A[ma][kk + kq];
    bf16x8 b1 = *(const bf16x8*)&WB[WB2 + (size_t)n_a*160 + kk + kq];
    bf16x8 b2 = *(const bf16x8*)&WB[WB2 + (size_t)n_b*160 + kk + kq];
    ca = __builtin_amdgcn_mfma_f32_16x16x32_bf16(af, b1, ca, 0, 0, 0);
    cb = __builtin_amdgcn_mfma_f32_16x16x32_bf16(af, b2, cb, 0, 0, 0);
  }
  {
    float ba = b2p[n_a], bb = b2p[n_b];
    #pragma unroll
    for (int j=0;j<4;++j){
      int r = mt*16 + (l>>4)*4 + j;
      int le = le0 + r;
      if (le < ec){
        int dn = SD[r][1];
        atomicAdd(&agg_s[(size_t)dn*128 + n_a], ca[j] + ba);
        atomicAdd(&agg_s[(size_t)dn*128 + n_b], cb[j] + bb);
      }
    }
  }
}

// ---------- residual + tuple LayerNorm after aggregation ----------
__global__ __launch_bounds__(256) void k_ln0(
    const float* __restrict__ node_s, const float* __restrict__ node_v,
    const float* __restrict__ agg_s, const float* __restrict__ agg_v,
    const float* __restrict__ cnt,
    const float* __restrict__ g, const float* __restrict__ b,
    float* __restrict__ s_mid, float* __restrict__ v_mid, int N)
{
  int n = blockIdx.x*256 + threadIdx.x;
  if (n>=N) return;
  const float inv = 1.f/fmaxf(cnt[n], 1.f);
  float sum=0.f, ss=0.f;
  for (int i=0;i<128;++i){
    float x = node_s[(size_t)n*128+i] + agg_s[(size_t)n*128+i]*inv;
    sum += x; ss += x*x;
  }
  const float mu = sum*(1.f/128.f);
  const float var = fmaxf(ss*(1.f/128.f) - mu*mu, 0.f);
  const float rstd = rsqrtf(var + 1e-5f);
  for (int i=0;i<128;++i){
    float x = node_s[(size_t)n*128+i] + agg_s[(size_t)n*128+i]*inv;
    s_mid[(size_t)n*128+i] = (x-mu)*rstd*g[i] + b[i];
  }
  float vs=0.f;
  for (int vo=0;vo<32;++vo){
    float y0 = node_v[(size_t)n*96+vo*3+0] + agg_v[(size_t)n*96+vo*3+0]*inv;
    float y1 = node_v[(size_t)n*96+vo*3+1] + agg_v[(size_t)n*96+vo*3+1]*inv;
    float y2 = node_v[(size_t)n*96+vo*3+2] + agg_v[(size_t)n*96+vo*3+2]*inv;
    vs += fmaxf(y0*y0+y1*y1+y2*y2, 1e-8f);
  }
  const float scale = rsqrtf(vs*(1.f/32.f));
  for (int vo=0;vo<32;++vo){
    float y0 = node_v[(size_t)n*96+vo*3+0] + agg_v[(size_t)n*96+vo*3+0]*inv;
    float y1 = node_v[(size_t)n*96+vo*3+1] + agg_v[(size_t)n*96+vo*3+1]*inv;
    float y2 = node_v[(size_t)n*96+vo*3+2] + agg_v[(size_t)n*96+vo*3+2]*inv;
    v_mid[(size_t)n*96+vo]      = y0*scale;   // d-major [n][3][32]
    v_mid[(size_t)n*96+32+vo]   = y1*scale;
    v_mid[(size_t)n*96+64+vo]   = y2*scale;
  }
}

// ---------- node vector FF (batched MFMA): vn0f, vn1f, fv1 ----------
__global__ __launch_bounds__(256) void k_node_v(
    const float* __restrict__ v_mid, const u16* __restrict__ WVb,
    u16* __restrict__ vn0f, u16* __restrict__ vn1f, float* __restrict__ fv1, int N)
{
  __shared__ __align__(16) u16 B0[96][104];
  __shared__ __align__(16) u16 B1[96][104];
  const int tid = threadIdx.x;
  const int w = tid>>6, l = tid&63;
  const int n0 = blockIdx.x*32;

  for (int u=tid; u<96*8; u+=256){
    int r=u>>3, g=u&7, nd=r/3, d=r-nd*3;
    int n=n0+nd;
    short4 v = {0,0,0,0};
    if (n<N) v = pack4(*(const float4*)&v_mid[(size_t)n*96 + d*32 + 4*g]);
    *(short4*)&B0[r][4*g] = v;
  }
  __syncthreads();

  auto mm = [&](const u16 (*A)[104], int woff, int Kp, int NT, u16 (*C)[104]){
    const int nks = Kp>>5;
    for (int t=w; t<6*NT; t+=4){
      int mt = t % 6, nt = t / 6;
      f32x4 acc = {0.f,0.f,0.f,0.f};
      for (int ks=0; ks<nks; ++ks){
        bf16x8 af = *(const bf16x8*)&A[mt*16 + (l&15)][ks*32 + (l>>4)*8];
        bf16x8 bf = *(const bf16x8*)&WVb[woff + (size_t)(nt*16 + (l&15))*Kp + ks*32 + (l>>4)*8];
        acc = __builtin_amdgcn_mfma_f32_16x16x32_bf16(af, bf, acc, 0, 0, 0);
      }
      const int col = nt*16 + (l&15);
      const int r0 = mt*16 + (l>>4)*4;
      C[r0+0][col]=f2b(acc[0]); C[r0+1][col]=f2b(acc[1]);
      C[r0+2][col]=f2b(acc[2]); C[r0+3][col]=f2b(acc[3]);
    }
  };

  mm(B0, NV_FF0H, 32, 4, B1);   // vh0 (64)
  __syncthreads();
  for (int u=tid; u<32*64; u+=256){
    int nd=u>>6, h=u&63;
    int n=n0+nd;
    if (n<N){
      float x0=b2f(B1[nd*3+0][h]), x1=b2f(B1[nd*3+1][h]), x2=b2f(B1[nd*3+2][h]);
      vn0f[(size_t)n*64+h] = f2b(sqrtf(fmaxf(x0*x0+x1*x1+x2*x2, 1e-8f)));
    }
  }
  mm(B1, NV_FF0V, 64, 4, B0);   // fv0 raw (64)
  __syncthreads();
  for (int u=tid; u<32*64; u+=256){
    int nd=u>>6, vo=u&63;
    float x0=b2f(B0[nd*3+0][vo]), x1=b2f(B0[nd*3+1][vo]), x2=b2f(B0[nd*3+2][vo]);
    float nn=sqrtf(fmaxf(x0*x0+x1*x1+x2*x2, 1e-8f));
    float sg=1.f/(1.f+__expf(-nn));
    B0[nd*3+0][vo]=f2b(x0*sg); B0[nd*3+1][vo]=f2b(x1*sg); B0[nd*3+2][vo]=f2b(x2*sg);
  }
  __syncthreads();
  mm(B0, NV_FF1H, 64, 4, B1);   // vh1 (64)
  __syncthreads();
  for (int u=tid; u<32*64; u+=256){
    int nd=u>>6, h=u&63;
    int n=n0+nd;
    if (n<N){
      float x0=b2f(B1[nd*3+0][h]), x1=b2f(B1[nd*3+1][h]), x2=b2f(B1[nd*3+2][h]);
      vn1f[(size_t)n*64+h] = f2b(sqrtf(fmaxf(x0*x0+x1*x1+x2*x2, 1e-8f)));
    }
  }
  // fv1 = vh1 @ ff1v^T (64->32), no gate -> global f32 d-major
  for (int t=w; t<12; t+=4){
    int mt = t % 6, nt = t / 6;
    f32x4 acc = {0.f,0.f,0.f,0.f};
    for (int ks=0; ks<2; ++ks){
      bf16x8 af = *(const bf16x8*)&B1[mt*16 + (l&15)][ks*32 + (l>>4)*8];
      bf16x8 bf = *(const bf16x8*)&WVb[NV_FF1V + (size_t)(nt*16 + (l&15))*64 + ks*32 + (l>>4)*8];
      acc = __builtin_amdgcn_mfma_f32_16x16x32_bf16(af, bf, acc, 0, 0, 0);
    }
    const int vo = nt*16 + (l&15);
    const int r0 = mt*16 + (l>>4)*4;
    #pragma unroll
    for (int j=0;j<4;++j){
      int r = r0 + j;
      int nd = r/3, d = r - nd*3;
      int n = n0 + nd;
      if (n < N) fv1[(size_t)n*96 + d*32 + vo] = acc[j];
    }
  }
}

// ---------- node scalar FF (2 MFMA GEMMs) + fused final LN -> d_out ----------
__global__ __launch_bounds__(512) void k_node_s(
    const float* __restrict__ s_mid, const u16* __restrict__ vn0f, const u16* __restrict__ vn1f,
    const float* __restrict__ v_mid, const float* __restrict__ fv1,
    const u16* __restrict__ WB,
    const float* __restrict__ fb0, const float* __restrict__ fb1,
    const float* __restrict__ ln1g, const float* __restrict__ ln1b,
    float* __restrict__ out, int N)
{
  __shared__ __align__(16) char U1[16896];           // A1 [32][200] u16, later FS [32][132] f32
  __shared__ __align__(16) u16 A2[32][584];
  u16 (*A1)[200] = (u16(*)[200])U1;
  float (*FS)[132] = (float(*)[132])U1;
  const int tid = threadIdx.x;
  const int n0 = blockIdx.x*32;

  // stage A1 = [s_mid(128), vn0f(64)]
  for (int u=tid; u<32*48; u+=512){
    int nd = u/48, g = u - nd*48;
    int n = n0+nd;
    short4 v = {0,0,0,0};
    if (n<N){
      if (g < 32) v = pack4(*(const float4*)&s_mid[(size_t)n*128 + 4*g]);
      else        v = *(const short4*)&vn0f[(size_t)n*64 + 4*(g-32)];
    }
    *(short4*)&A1[nd][4*g] = v;
  }
  __syncthreads();

  const int w = tid>>6, l = tid&63;
  const int mt = w>>2, ng = w&3;
  const int kq = (l>>4)*8;
  const int ma = mt*16 + (l&15);
  const int r0 = mt*16 + (l>>4)*4;

  // GEMM0: [32][192] @ ff0s[512][192]^T -> relu -> A2 cols 0..511
  for (int nt2=0; nt2<8; ++nt2){
    const int nt = ng*8 + nt2;
    const int col = nt*16 + (l&15);
    f32x4 acc = {0.f,0.f,0.f,0.f};
    for (int ks=0; ks<6; ++ks){
      bf16x8 af = *(const bf16x8*)&A1[ma][ks*32 + kq];
      bf16x8 bf = *(const bf16x8*)&WB[WBF0 + (size_t)col*192 + ks*32 + kq];
      acc = __builtin_amdgcn_mfma_f32_16x16x32_bf16(af, bf, acc, 0, 0, 0);
    }
    float bias = fb0[col];
    #pragma unroll
    for (int j=0;j<4;++j) A2[r0+j][col] = f2b(fmaxf(acc[j] + bias, 0.f));
  }
  __syncthreads();
  // A2 cols 512..575 <- vn1f
  for (int u=tid; u<32*16; u+=512){
    int nd=u>>4, q=u&15;
    int n=n0+nd;
    short4 v = {0,0,0,0};
    if (n<N) v = *(const short4*)&vn1f[(size_t)n*64 + 4*q];
    *(short4*)&A2[nd][512+4*q] = v;
  }
  __syncthreads();

  // GEMM1: [32][576] @ ff1s[128][576]^T -> FS (f32, overlays A1 -- A1 dead)
  for (int nt2=0; nt2<2; ++nt2){
    const int nt = ng*2 + nt2;
    const int col = nt*16 + (l&15);
    f32x4 acc = {0.f,0.f,0.f,0.f};
    for (int ks=0; ks<18; ++ks){
      bf16x8 af = *(const bf16x8*)&A2[ma][ks*32 + kq];
      bf16x8 bf = *(const bf16x8*)&WB[WBF1 + (size_t)col*576 + ks*32 + kq];
      acc = __builtin_amdgcn_mfma_f32_16x16x32_bf16(af, bf, acc, 0, 0, 0);
    }
    float bias = fb1[col];
    #pragma unroll
    for (int j=0;j<4;++j) FS[r0+j][col] = acc[j] + bias;
  }
  __syncthreads();

  // fused LN1: 16 threads per node
  {
    const int nd = tid>>4, q = tid&15;
    const int n = n0 + nd;
    const bool live = n < N;
    float xs[8], sum=0.f, ss=0.f;
    #pragma unroll
    for (int j=0;j<8;++j){
      int c = q*8 + j;
      float x = 0.f;
      if (live) x = s_mid[(size_t)n*128 + c] + FS[nd][c];
      xs[j] = x; sum += x; ss += x*x;
    }
    #pragma unroll
    for (int m=1; m<16; m<<=1){ sum += __shfl_xor(sum, m); ss += __shfl_xor(ss, m); }
    const float mu = sum*(1.f/128.f);
    const float var = fmaxf(ss*(1.f/128.f) - mu*mu, 0.f);
    const float rstd = rsqrtf(var + 1e-5f);
    if (live){
      #pragma unroll
      for (int j=0;j<8;++j){
        int c = q*8 + j;
        out[(size_t)n*128 + c] = (xs[j]-mu)*rstd*ln1g[c] + ln1b[c];
      }
    }
    // v-part: 2 vectors per thread
    float z[2][3]; float vs = 0.f;
    #pragma unroll
    for (int j=0;j<2;++j){
      int vo = q + 16*j;
      #pragma unroll
      for (int d=0;d<3;++d){
        float y = live ? (v_mid[(size_t)n*96 + d*32 + vo] + fv1[(size_t)n*96 + d*32 + vo]) : 0.f;
        z[j][d] = y;
      }
      vs += fmaxf(z[j][0]*z[j][0]+z[j][1]*z[j][1]+z[j][2]*z[j][2], 1e-8f);
    }
    #pragma unroll
    for (int m=1; m<16; m<<=1) vs += __shfl_xor(vs, m);
    const float scale = rsqrtf(vs*(1.f/32.f));
    if (live){
      size_t base = (size_t)N*128 + (size_t)n*96;
      #pragma unroll
      for (int j=0;j<2;++j){
        int vo = q + 16*j;
        out[base + vo*3 + 0] = z[j][0]*scale;
        out[base + vo*3 + 1] = z[j][1]*scale;
        out[base + vo*3 + 2] = z[j][2]*scale;
      }
    }
  }
}

extern "C" void kernel_launch(void* const* d_in, const int* in_sizes, int n_in,
                              void* d_out, int out_size, void* d_ws, size_t ws_size,
                              hipStream_t stream)
{
  (void)n_in; (void)out_size;
  const int N = in_sizes[0]/128;
  const int E = in_sizes[4]/2;
  const int* ei = (const int*)d_in[4];

  size_t off = 0;
  auto alloc = [&](size_t bytes)->char*{
    size_t o = (off + 255) & ~(size_t)255;
    off = o + bytes;
    return (char*)d_ws + o;
  };
  u16*   WB      = (u16*)alloc((size_t)WB_TOTAL*2);
  u16*   WVb     = (u16*)alloc((size_t)WV_TOTAL*2);
  float* agg_s   = (float*)alloc((size_t)N*128*4);
  float* agg_v   = (float*)alloc((size_t)N*96*4);
  float* cnt     = (float*)alloc((size_t)N*4);
  size_t aggBytes = (size_t)((char*)(cnt+N) - (char*)agg_s);
  float* s_mid   = (float*)alloc((size_t)N*128*4);
  float* v_mid   = (float*)alloc((size_t)N*96*4);
  u16*   node_sb = (u16*)alloc((size_t)N*128*2);
  u16*   node_vb = (u16*)alloc((size_t)N*96*2);
  u16*   vn0f    = (u16*)alloc((size_t)N*64*2);
  u16*   vn1f    = (u16*)alloc((size_t)N*64*2);
  float* fv1     = (float*)alloc((size_t)N*96*4);
  const size_t persist_end = off;

  size_t avail = (ws_size > persist_end + (1u<<20)) ? (ws_size - persist_end - (1u<<20)) : 0;
  long EC = (long)(avail / 288);
  if (EC < 8192) EC = 8192;
  if (EC > E) EC = E;
  u16* vnbuf = (u16*)alloc((size_t)EC*144*2);

  hipMemsetAsync(agg_s, 0, aggBytes, stream);
  k_wb<<<dim3((WB_TOTAL+255)/256), dim3(256), 0, stream>>>(
      (const float*)d_in[6], (const float*)d_in[10], (const float*)d_in[14],
      (const float*)d_in[20], (const float*)d_in[24], WB);
  k_wv<<<dim3((WV_TOTAL+255)/256), dim3(256), 0, stream>>>(
      (const float*)d_in[5], (const float*)d_in[8], (const float*)d_in[9],
      (const float*)d_in[12], (const float*)d_in[13], (const float*)d_in[16],
      (const float*)d_in[19], (const float*)d_in[22], (const float*)d_in[23],
      (const float*)d_in[26], WVb);
  k_prep<<<dim3((N*224+255)/256), dim3(256), 0, stream>>>(
      (const float*)d_in[0], (const float*)d_in[1], node_sb, node_vb, N);

  const int nch = (int)((E + EC - 1)/EC);
  for (int c=0; c<nch; ++c){
    const int eb = c*(int)EC;
    int ec = E - eb; if (ec > (int)EC) ec = (int)EC;
    if (ec <= 0) break;
    k_edge_v<<<dim3((ec+VEPB-1)/VEPB), dim3(256), 0, stream>>>(
        node_vb, (const float*)d_in[3], ei, E, WVb, vnbuf, agg_v, cnt, eb, ec);
    k_edge_s<<<dim3((ec+SPB-1)/SPB), dim3(512), 0, stream>>>(
        node_sb, (const float*)d_in[2], ei, E, WB, vnbuf,
        (const float*)d_in[7], (const float*)d_in[11], (const float*)d_in[15],
        agg_s, eb, ec);
  }

  k_ln0<<<dim3((N+255)/256), dim3(256), 0, stream>>>(
      (const float*)d_in[0], (const float*)d_in[1], agg_s, agg_v, cnt,
      (const float*)d_in[17], (const float*)d_in[18], s_mid, v_mid, N);

  k_node_v<<<dim3((N+31)/32), dim3(256), 0, stream>>>(v_mid, WVb, vn0f, vn1f, fv1, N);
  k_node_s<<<dim3((N+31)/32), dim3(512), 0, stream>>>(
      s_mid, vn0f, vn1f, v_mid, fv1, WB,
      (const float*)d_in[21], (const float*)d_in[25],
      (const float*)d_in[27], (const float*)d_in[28],
      (float*)d_out, N);
}

// Round 12
// 587.438 us; speedup vs baseline: 70.2014x; 1.0972x over previous
//
#include <hip/hip_runtime.h>

typedef unsigned short u16;
typedef __attribute__((ext_vector_type(8))) short bf16x8;
typedef __attribute__((ext_vector_type(4))) float f32x4;

__device__ __forceinline__ float b2f(u16 h){ return __uint_as_float(((unsigned)h)<<16); }
__device__ __forceinline__ u16 f2b(float f){
  unsigned u = __float_as_uint(f);
  unsigned r = ((u>>16)&1u) + 0x7fffu;
  return (u16)((u+r)>>16);
}
__device__ __forceinline__ short4 pack4(float4 f){
  short4 s; s.x=(short)f2b(f.x); s.y=(short)f2b(f.y); s.z=(short)f2b(f.z); s.w=(short)f2b(f.w);
  return s;
}

// WB bf16 arena: s-path weights, [O][K] layout
#define WB0   0        // [128][384]
#define WB1   49152    // [128][160]
#define WB2   69632    // [128][160]
#define WBF0  90112    // [512][192]
#define WBF1  188416   // [128][576]
#define WB_TOTAL 262144

// WVb bf16 arena: v-path weights, [N_pad][K_pad]
#define V_WH0   0
#define V_WV0   7680
#define V_WH1   10752
#define V_WV1   11776
#define V_WH2   12800
#define V_WV2   13824
#define NV_FF0H 14848
#define NV_FF0V 16896
#define NV_FF1H 20992
#define NV_FF1V 25088
#define WV_TOTAL 27136

__global__ __launch_bounds__(256) void k_wb(const float* __restrict__ w0,
    const float* __restrict__ w1, const float* __restrict__ w2,
    const float* __restrict__ f0, const float* __restrict__ f1,
    u16* __restrict__ WB){
  int t = blockIdx.x*256 + threadIdx.x;
  if (t < 49152){
    int o = t/384, k = t - o*384;
    WB[WB0 + t] = f2b(k < 353 ? w0[(size_t)o*353 + k] : 0.f);
    return;
  }
  t -= 49152;
  if (t < 20480){ WB[WB1 + t] = f2b(w1[t]); return; }
  t -= 20480;
  if (t < 20480){ WB[WB2 + t] = f2b(w2[t]); return; }
  t -= 20480;
  if (t < 98304){ WB[WBF0 + t] = f2b(f0[t]); return; }
  t -= 98304;
  if (t < 73728){ WB[WBF1 + t] = f2b(f1[t]); return; }
}

__global__ __launch_bounds__(256) void k_wv(const float* __restrict__ wh0, const float* __restrict__ wv0,
    const float* __restrict__ wh1, const float* __restrict__ wv1,
    const float* __restrict__ wh2, const float* __restrict__ wv2,
    const float* __restrict__ nf0h, const float* __restrict__ nf0v,
    const float* __restrict__ nf1h, const float* __restrict__ nf1v,
    u16* __restrict__ WVb){
  int t = blockIdx.x*256 + threadIdx.x;
  if (t < 7680){
    int n=t/96, k=t-n*96;
    float v = 0.f;
    if (n < 65){
      if (k < 32)       v = wh0[(size_t)n*65 + k];
      else if (k < 64)  v = wh0[(size_t)n*65 + 33 + (k-32)];
      else if (k == 64) v = wh0[(size_t)n*65 + 32];
    }
    WVb[V_WH0+t] = f2b(v);
    return;
  }
  t -= 7680;
  if (t < 3072){
    int n=t/96, k=t-n*96;
    WVb[V_WV0+t] = f2b((k<65) ? wv0[(size_t)n*65+k] : 0.f);
    return;
  }
  t -= 3072;
  if (t < 1024){ WVb[V_WH1+t]=f2b(wh1[t]); return; }
  t -= 1024;
  if (t < 1024){ WVb[V_WV1+t]=f2b(wv1[t]); return; }
  t -= 1024;
  if (t < 1024){ WVb[V_WH2+t]=f2b(wh2[t]); return; }
  t -= 1024;
  if (t < 1024){ WVb[V_WV2+t]=f2b(wv2[t]); return; }
  t -= 1024;
  if (t < 2048){ WVb[NV_FF0H+t]=f2b(nf0h[t]); return; }
  t -= 2048;
  if (t < 4096){ WVb[NV_FF0V+t]=f2b(nf0v[t]); return; }
  t -= 4096;
  if (t < 4096){ WVb[NV_FF1H+t]=f2b(nf1h[t]); return; }
  t -= 4096;
  if (t < 2048){ WVb[NV_FF1V+t]=f2b(nf1v[t]); return; }
}

__global__ __launch_bounds__(256) void k_prep(const float* __restrict__ node_s,
    const float* __restrict__ node_v, u16* __restrict__ node_sb,
    u16* __restrict__ node_vb, int N){
  int t = blockIdx.x*256 + threadIdx.x;
  if (t < N*128){ node_sb[t] = f2b(node_s[t]); return; }
  t -= N*128;
  if (t < N*96){
    int n=t/96, r=t-n*96, d=r>>5, vo=r&31;
    node_vb[(size_t)n*96 + d*32 + vo] = f2b(node_v[(size_t)n*96 + vo*3 + d]);
  }
}

// ---------- dst histogram (also = mean-agg count) ----------
__global__ __launch_bounds__(256) void k_hist(const int* __restrict__ ei, int E,
                                              float* __restrict__ cnt){
  int e = blockIdx.x*256 + threadIdx.x;
  if (e < E) atomicAdd(&cnt[ei[(size_t)E + e]], 1.f);
}

// ---------- single-block exclusive scan of cnt -> wpos ----------
__global__ __launch_bounds__(256) void k_scan(const float* __restrict__ cnt,
                                              int* __restrict__ wpos, int N){
  __shared__ int part[256];
  const int tid = threadIdx.x;
  const int per = (N + 255)/256;
  const int base = tid*per;
  int s = 0;
  for (int i=0;i<per;++i){ int n=base+i; if (n<N) s += (int)cnt[n]; }
  part[tid] = s; __syncthreads();
  for (int st=1; st<256; st<<=1){
    int v = (tid>=st) ? part[tid-st] : 0;
    __syncthreads();
    part[tid] += v;
    __syncthreads();
  }
  int run = part[tid] - s;
  for (int i=0;i<per;++i){ int n=base+i; if (n<N){ wpos[n]=run; run += (int)cnt[n]; } }
}

// ---------- scatter edge ids into dst-sorted perm ----------
__global__ __launch_bounds__(256) void k_scatter(const int* __restrict__ ei, int E,
                                                 int* __restrict__ wpos, int* __restrict__ perm){
  int e = blockIdx.x*256 + threadIdx.x;
  if (e >= E) return;
  int d = ei[(size_t)E + e];
  int pos = atomicAdd(&wpos[d], 1);
  perm[pos] = e;
}

// ---------- kernel V: batched-MFMA edge vector path (dst-sorted, segmented agg) ----------
#define VEPB 32
__global__ __launch_bounds__(256) void k_edge_v(
    const u16* __restrict__ node_vb, const float* __restrict__ edge_v,
    const int* __restrict__ ei, int E, const int* __restrict__ perm,
    const u16* __restrict__ WVb, u16* __restrict__ vnbuf,
    float* __restrict__ agg_v, int eb, int ec)
{
  __shared__ __align__(16) char UB0[96*104*2];
  __shared__ __align__(16) u16 B1[96][104];
  __shared__ int SD[VEPB][2];
  __shared__ int GE[VEPB];
  u16 (*B0)[104] = (u16(*)[104])UB0;
  float (*SCv)[33] = (float(*)[33])UB0;   // 96*33*4 = 12672 <= 19968
  const int tid = threadIdx.x;
  const int w = tid>>6, l = tid&63;
  const int le0 = blockIdx.x*VEPB;

  if (tid < VEPB){
    int le = le0 + tid;
    int ge = (le<ec) ? perm[eb+le] : 0;
    GE[tid] = ge;
    SD[tid][0] = ei[ge];
    SD[tid][1] = ei[(size_t)E + ge];
  }
  __syncthreads();
  for (int u=tid; u<96*16; u+=256){
    int r=u>>4, g=u&15, ee=r/3, d=r-ee*3;
    int le=le0+ee;
    short4 v = {0,0,0,0};
    if (le<ec){
      int node = (g<8) ? SD[ee][0] : SD[ee][1];
      v = *(const short4*)&node_vb[(size_t)node*96 + d*32 + 4*(g&7)];
    }
    *(short4*)&B0[r][4*g] = v;
  }
  for (int u=tid; u<96*8; u+=256){
    int r=u>>3, g=u&7, ee=r/3, d=r-ee*3;
    int le=le0+ee;
    short4 v = {0,0,0,0};
    if (g==0 && le<ec) v.x = (short)f2b(edge_v[(size_t)GE[ee]*3 + d]);
    *(short4*)&B0[r][64+4*g] = v;
  }
  for (int u=tid; u<96*4; u+=256){
    int r=u>>2, g=u&3;
    *(short4*)&B1[r][80+4*g] = (short4){0,0,0,0};
  }
  __syncthreads();

  auto mm = [&](const u16 (*A)[104], int woff, int Kp, int NT, u16 (*C)[104]){
    const int nks = Kp>>5;
    for (int t=w; t<6*NT; t+=4){
      int mt = t % 6, nt = t / 6;
      f32x4 acc = {0.f,0.f,0.f,0.f};
      for (int ks=0; ks<nks; ++ks){
        bf16x8 af = *(const bf16x8*)&A[mt*16 + (l&15)][ks*32 + (l>>4)*8];
        bf16x8 bf = *(const bf16x8*)&WVb[woff + (size_t)(nt*16 + (l&15))*Kp + ks*32 + (l>>4)*8];
        acc = __builtin_amdgcn_mfma_f32_16x16x32_bf16(af, bf, acc, 0, 0, 0);
      }
      const int col = nt*16 + (l&15);
      const int r0 = mt*16 + (l>>4)*4;
      C[r0+0][col]=f2b(acc[0]); C[r0+1][col]=f2b(acc[1]);
      C[r0+2][col]=f2b(acc[2]); C[r0+3][col]=f2b(acc[3]);
    }
  };

  mm(B0, V_WH0, 96, 5, B1);
  __syncthreads();
  for (int u=tid; u<VEPB*80; u+=256){
    int ee=u/80, h=u-ee*80;
    int le=le0+ee;
    if (le<ec){
      u16 val = 0;
      if (h<65){
        float x0=b2f(B1[ee*3+0][h]), x1=b2f(B1[ee*3+1][h]), x2=b2f(B1[ee*3+2][h]);
        val = f2b(sqrtf(fmaxf(x0*x0+x1*x1+x2*x2, 1e-8f)));
      }
      vnbuf[(size_t)le*144 + h] = val;
    }
  }
  mm(B1, V_WV0, 96, 2, B0);
  __syncthreads();
  for (int u=tid; u<VEPB*32; u+=256){
    int ee=u>>5, vo=u&31;
    float x0=b2f(B0[ee*3+0][vo]), x1=b2f(B0[ee*3+1][vo]), x2=b2f(B0[ee*3+2][vo]);
    float nn=sqrtf(fmaxf(x0*x0+x1*x1+x2*x2, 1e-8f));
    float sg=1.f/(1.f+__expf(-nn));
    B0[ee*3+0][vo]=f2b(x0*sg); B0[ee*3+1][vo]=f2b(x1*sg); B0[ee*3+2][vo]=f2b(x2*sg);
  }
  __syncthreads();
  mm(B0, V_WH1, 32, 2, B1);
  __syncthreads();
  for (int u=tid; u<VEPB*32; u+=256){
    int ee=u>>5, h=u&31;
    int le=le0+ee;
    if (le<ec){
      float x0=b2f(B1[ee*3+0][h]), x1=b2f(B1[ee*3+1][h]), x2=b2f(B1[ee*3+2][h]);
      vnbuf[(size_t)le*144 + 80 + h] = f2b(sqrtf(fmaxf(x0*x0+x1*x1+x2*x2, 1e-8f)));
    }
  }
  mm(B1, V_WV1, 32, 2, B0);
  __syncthreads();
  for (int u=tid; u<VEPB*32; u+=256){
    int ee=u>>5, vo=u&31;
    float x0=b2f(B0[ee*3+0][vo]), x1=b2f(B0[ee*3+1][vo]), x2=b2f(B0[ee*3+2][vo]);
    float nn=sqrtf(fmaxf(x0*x0+x1*x1+x2*x2, 1e-8f));
    float sg=1.f/(1.f+__expf(-nn));
    B0[ee*3+0][vo]=f2b(x0*sg); B0[ee*3+1][vo]=f2b(x1*sg); B0[ee*3+2][vo]=f2b(x2*sg);
  }
  __syncthreads();
  mm(B0, V_WH2, 32, 2, B1);
  __syncthreads();           // B0 dead from here; SCv may overlay it
  for (int u=tid; u<VEPB*32; u+=256){
    int ee=u>>5, h=u&31;
    int le=le0+ee;
    if (le<ec){
      float x0=b2f(B1[ee*3+0][h]), x1=b2f(B1[ee*3+1][h]), x2=b2f(B1[ee*3+2][h]);
      vnbuf[(size_t)le*144 + 112 + h] = f2b(sqrtf(fmaxf(x0*x0+x1*x1+x2*x2, 1e-8f)));
    }
  }
  // v2 = vh2 @ wv2^T -> SCv
  for (int t=w; t<12; t+=4){
    int mt = t % 6, nt = t / 6;
    f32x4 acc = {0.f,0.f,0.f,0.f};
    bf16x8 af = *(const bf16x8*)&B1[mt*16 + (l&15)][(l>>4)*8];
    bf16x8 bf = *(const bf16x8*)&WVb[V_WV2 + (size_t)(nt*16 + (l&15))*32 + (l>>4)*8];
    acc = __builtin_amdgcn_mfma_f32_16x16x32_bf16(af, bf, acc, 0, 0, 0);
    const int vo = nt*16 + (l&15);
    const int r0 = mt*16 + (l>>4)*4;
    #pragma unroll
    for (int j=0;j<4;++j){
      int r = r0 + j;
      int le = le0 + r/3;
      SCv[r][vo] = (le < ec) ? acc[j] : 0.f;
    }
  }
  __syncthreads();
  // segmented reduction over dst-sorted runs: one atomic per (run, vo, d)
  if (tid < 96){
    const int vo = tid & 31, d = tid >> 5;
    float run = 0.f; int prev = -1;
    for (int ee=0; ee<VEPB; ++ee){
      int le = le0 + ee;
      int dn = (le<ec) ? SD[ee][1] : -1;
      if (dn != prev){
        if (prev >= 0) atomicAdd(&agg_v[(size_t)prev*96 + vo*3 + d], run);
        run = 0.f; prev = dn;
      }
      run += SCv[ee*3+d][vo];
    }
    if (prev >= 0) atomicAdd(&agg_v[(size_t)prev*96 + vo*3 + d], run);
  }
}

// ---------- kernel S: gathered 3-stage MFMA GEMM chain (dst-sorted, segmented agg) ----------
#define SPB 32
__global__ __launch_bounds__(512) void k_edge_s(
    const u16* __restrict__ node_sb, const float* __restrict__ edge_s,
    const int* __restrict__ ei, int E, const int* __restrict__ perm,
    const u16* __restrict__ WB, const u16* __restrict__ vnbuf,
    const float* __restrict__ b0p, const float* __restrict__ b1p, const float* __restrict__ b2p,
    float* __restrict__ agg_s, int eb, int ec)
{
  __shared__ __align__(16) char UA[SPB*392*2];
  __shared__ int SD[SPB][2];
  __shared__ int GE[SPB];
  u16 (*A)[392] = (u16(*)[392])UA;
  float (*SC)[132] = (float(*)[132])UA;   // 32*132*4 = 16896 <= 25088
  const int tid = threadIdx.x;
  const int le0 = blockIdx.x*SPB;

  if (tid < SPB){
    int le = le0 + tid;
    int ge = (le<ec) ? perm[eb+le] : 0;
    GE[tid] = ge;
    SD[tid][0] = ei[ge];
    SD[tid][1] = ei[(size_t)E + ge];
  }
  __syncthreads();
  for (int u=tid; u<SPB*98; u+=512){
    int ee = u/98, g = u - ee*98;
    int le = le0+ee;
    short4 v = {0,0,0,0};
    if (le<ec){
      if (g < 32)      v = *(const short4*)&node_sb[(size_t)SD[ee][0]*128 + 4*g];
      else if (g < 40) v = pack4(*(const float4*)&edge_s[(size_t)GE[ee]*32 + 4*(g-32)]);
      else if (g < 72) v = *(const short4*)&node_sb[(size_t)SD[ee][1]*128 + 4*(g-40)];
      else if (g < 92) v = *(const short4*)&vnbuf[(size_t)le*144 + 4*(g-72)];
    }
    *(short4*)&A[ee][4*g] = v;
  }
  __syncthreads();

  const int w = tid>>6, l = tid&63;
  const int mt = w>>2, nt = w&3;
  const int n_a = nt*32 + (l&15), n_b = n_a + 16;
  const int kq = (l>>4)*8;
  const int ma = mt*16 + (l&15);
  f32x4 ca = {0.f,0.f,0.f,0.f}, cb = {0.f,0.f,0.f,0.f};

  for (int kk=0; kk<384; kk+=32){
    bf16x8 af = *(const bf16x8*)&A[ma][kk + kq];
    bf16x8 b1 = *(const bf16x8*)&WB[WB0 + (size_t)n_a*384 + kk + kq];
    bf16x8 b2 = *(const bf16x8*)&WB[WB0 + (size_t)n_b*384 + kk + kq];
    ca = __builtin_amdgcn_mfma_f32_16x16x32_bf16(af, b1, ca, 0, 0, 0);
    cb = __builtin_amdgcn_mfma_f32_16x16x32_bf16(af, b2, cb, 0, 0, 0);
  }
  __syncthreads();
  {
    float ba = b0p[n_a], bb = b0p[n_b];
    #pragma unroll
    for (int j=0;j<4;++j){
      int r = mt*16 + (l>>4)*4 + j;
      A[r][n_a] = f2b(fmaxf(ca[j] + ba, 0.f));
      A[r][n_b] = f2b(fmaxf(cb[j] + bb, 0.f));
    }
  }
  for (int u=tid; u<SPB*8; u+=512){
    int ee=u>>3, q=u&7;
    int le=le0+ee;
    short4 v = {0,0,0,0};
    if (le<ec) v = *(const short4*)&vnbuf[(size_t)le*144 + 80 + 4*q];
    *(short4*)&A[ee][128+4*q] = v;
  }
  __syncthreads();

  ca = (f32x4){0.f,0.f,0.f,0.f}; cb = (f32x4){0.f,0.f,0.f,0.f};
  for (int kk=0; kk<160; kk+=32){
    bf16x8 af = *(const bf16x8*)&A[ma][kk + kq];
    bf16x8 b1 = *(const bf16x8*)&WB[WB1 + (size_t)n_a*160 + kk + kq];
    bf16x8 b2 = *(const bf16x8*)&WB[WB1 + (size_t)n_b*160 + kk + kq];
    ca = __builtin_amdgcn_mfma_f32_16x16x32_bf16(af, b1, ca, 0, 0, 0);
    cb = __builtin_amdgcn_mfma_f32_16x16x32_bf16(af, b2, cb, 0, 0, 0);
  }
  __syncthreads();
  {
    float ba = b1p[n_a], bb = b1p[n_b];
    #pragma unroll
    for (int j=0;j<4;++j){
      int r = mt*16 + (l>>4)*4 + j;
      A[r][n_a] = f2b(fmaxf(ca[j] + ba, 0.f));
      A[r][n_b] = f2b(fmaxf(cb[j] + bb, 0.f));
    }
  }
  for (int u=tid; u<SPB*8; u+=512){
    int ee=u>>3, q=u&7;
    int le=le0+ee;
    short4 v = {0,0,0,0};
    if (le<ec) v = *(const short4*)&vnbuf[(size_t)le*144 + 112 + 4*q];
    *(short4*)&A[ee][128+4*q] = v;
  }
  __syncthreads();

  ca = (f32x4){0.f,0.f,0.f,0.f}; cb = (f32x4){0.f,0.f,0.f,0.f};
  for (int kk=0; kk<160; kk+=32){
    bf16x8 af = *(const bf16x8*)&A[ma][kk + kq];
    bf16x8 b1 = *(const bf16x8*)&WB[WB2 + (size_t)n_a*160 + kk + kq];
    bf16x8 b2 = *(const bf16x8*)&WB[WB2 + (size_t)n_b*160 + kk + kq];
    ca = __builtin_amdgcn_mfma_f32_16x16x32_bf16(af, b1, ca, 0, 0, 0);
    cb = __builtin_amdgcn_mfma_f32_16x16x32_bf16(af, b2, cb, 0, 0, 0);
  }
  __syncthreads();           // A dead; SC overlays it
  {
    float ba = b2p[n_a], bb = b2p[n_b];
    #pragma unroll
    for (int j=0;j<4;++j){
      int r = mt*16 + (l>>4)*4 + j;
      int le = le0 + r;
      SC[r][n_a] = (le<ec) ? (ca[j] + ba) : 0.f;
      SC[r][n_b] = (le<ec) ? (cb[j] + bb) : 0.f;
    }
  }
  __syncthreads();
  // segmented reduction: one atomic per (dst-run, col)
  if (tid < 128){
    const int c = tid;
    float run = 0.f; int prev = -1;
    for (int r=0; r<SPB; ++r){
      int le = le0 + r;
      int dn = (le<ec) ? SD[r][1] : -1;
      if (dn != prev){
        if (prev >= 0) atomicAdd(&agg_s[(size_t)prev*128 + c], run);
        run = 0.f; prev = dn;
      }
      run += SC[r][c];
    }
    if (prev >= 0) atomicAdd(&agg_s[(size_t)prev*128 + c], run);
  }
}

// ---------- residual + tuple LayerNorm after aggregation ----------
__global__ __launch_bounds__(256) void k_ln0(
    const float* __restrict__ node_s, const float* __restrict__ node_v,
    const float* __restrict__ agg_s, const float* __restrict__ agg_v,
    const float* __restrict__ cnt,
    const float* __restrict__ g, const float* __restrict__ b,
    float* __restrict__ s_mid, float* __restrict__ v_mid, int N)
{
  int n = blockIdx.x*256 + threadIdx.x;
  if (n>=N) return;
  const float inv = 1.f/fmaxf(cnt[n], 1.f);
  float sum=0.f, ss=0.f;
  for (int i=0;i<128;++i){
    float x = node_s[(size_t)n*128+i] + agg_s[(size_t)n*128+i]*inv;
    sum += x; ss += x*x;
  }
  const float mu = sum*(1.f/128.f);
  const float var = fmaxf(ss*(1.f/128.f) - mu*mu, 0.f);
  const float rstd = rsqrtf(var + 1e-5f);
  for (int i=0;i<128;++i){
    float x = node_s[(size_t)n*128+i] + agg_s[(size_t)n*128+i]*inv;
    s_mid[(size_t)n*128+i] = (x-mu)*rstd*g[i] + b[i];
  }
  float vs=0.f;
  for (int vo=0;vo<32;++vo){
    float y0 = node_v[(size_t)n*96+vo*3+0] + agg_v[(size_t)n*96+vo*3+0]*inv;
    float y1 = node_v[(size_t)n*96+vo*3+1] + agg_v[(size_t)n*96+vo*3+1]*inv;
    float y2 = node_v[(size_t)n*96+vo*3+2] + agg_v[(size_t)n*96+vo*3+2]*inv;
    vs += fmaxf(y0*y0+y1*y1+y2*y2, 1e-8f);
  }
  const float scale = rsqrtf(vs*(1.f/32.f));
  for (int vo=0;vo<32;++vo){
    float y0 = node_v[(size_t)n*96+vo*3+0] + agg_v[(size_t)n*96+vo*3+0]*inv;
    float y1 = node_v[(size_t)n*96+vo*3+1] + agg_v[(size_t)n*96+vo*3+1]*inv;
    float y2 = node_v[(size_t)n*96+vo*3+2] + agg_v[(size_t)n*96+vo*3+2]*inv;
    v_mid[(size_t)n*96+vo]      = y0*scale;
    v_mid[(size_t)n*96+32+vo]   = y1*scale;
    v_mid[(size_t)n*96+64+vo]   = y2*scale;
  }
}

// ---------- node vector FF (batched MFMA) ----------
__global__ __launch_bounds__(256) void k_node_v(
    const float* __restrict__ v_mid, const u16* __restrict__ WVb,
    u16* __restrict__ vn0f, u16* __restrict__ vn1f, float* __restrict__ fv1, int N)
{
  __shared__ __align__(16) u16 B0[96][104];
  __shared__ __align__(16) u16 B1[96][104];
  const int tid = threadIdx.x;
  const int w = tid>>6, l = tid&63;
  const int n0 = blockIdx.x*32;

  for (int u=tid; u<96*8; u+=256){
    int r=u>>3, g=u&7, nd=r/3, d=r-nd*3;
    int n=n0+nd;
    short4 v = {0,0,0,0};
    if (n<N) v = pack4(*(const float4*)&v_mid[(size_t)n*96 + d*32 + 4*g]);
    *(short4*)&B0[r][4*g] = v;
  }
  __syncthreads();

  auto mm = [&](const u16 (*A)[104], int woff, int Kp, int NT, u16 (*C)[104]){
    const int nks = Kp>>5;
    for (int t=w; t<6*NT; t+=4){
      int mt = t % 6, nt = t / 6;
      f32x4 acc = {0.f,0.f,0.f,0.f};
      for (int ks=0; ks<nks; ++ks){
        bf16x8 af = *(const bf16x8*)&A[mt*16 + (l&15)][ks*32 + (l>>4)*8];
        bf16x8 bf = *(const bf16x8*)&WVb[woff + (size_t)(nt*16 + (l&15))*Kp + ks*32 + (l>>4)*8];
        acc = __builtin_amdgcn_mfma_f32_16x16x32_bf16(af, bf, acc, 0, 0, 0);
      }
      const int col = nt*16 + (l&15);
      const int r0 = mt*16 + (l>>4)*4;
      C[r0+0][col]=f2b(acc[0]); C[r0+1][col]=f2b(acc[1]);
      C[r0+2][col]=f2b(acc[2]); C[r0+3][col]=f2b(acc[3]);
    }
  };

  mm(B0, NV_FF0H, 32, 4, B1);
  __syncthreads();
  for (int u=tid; u<32*64; u+=256){
    int nd=u>>6, h=u&63;
    int n=n0+nd;
    if (n<N){
      float x0=b2f(B1[nd*3+0][h]), x1=b2f(B1[nd*3+1][h]), x2=b2f(B1[nd*3+2][h]);
      vn0f[(size_t)n*64+h] = f2b(sqrtf(fmaxf(x0*x0+x1*x1+x2*x2, 1e-8f)));
    }
  }
  mm(B1, NV_FF0V, 64, 4, B0);
  __syncthreads();
  for (int u=tid; u<32*64; u+=256){
    int nd=u>>6, vo=u&63;
    float x0=b2f(B0[nd*3+0][vo]), x1=b2f(B0[nd*3+1][vo]), x2=b2f(B0[nd*3+2][vo]);
    float nn=sqrtf(fmaxf(x0*x0+x1*x1+x2*x2, 1e-8f));
    float sg=1.f/(1.f+__expf(-nn));
    B0[nd*3+0][vo]=f2b(x0*sg); B0[nd*3+1][vo]=f2b(x1*sg); B0[nd*3+2][vo]=f2b(x2*sg);
  }
  __syncthreads();
  mm(B0, NV_FF1H, 64, 4, B1);
  __syncthreads();
  for (int u=tid; u<32*64; u+=256){
    int nd=u>>6, h=u&63;
    int n=n0+nd;
    if (n<N){
      float x0=b2f(B1[nd*3+0][h]), x1=b2f(B1[nd*3+1][h]), x2=b2f(B1[nd*3+2][h]);
      vn1f[(size_t)n*64+h] = f2b(sqrtf(fmaxf(x0*x0+x1*x1+x2*x2, 1e-8f)));
    }
  }
  for (int t=w; t<12; t+=4){
    int mt = t % 6, nt = t / 6;
    f32x4 acc = {0.f,0.f,0.f,0.f};
    for (int ks=0; ks<2; ++ks){
      bf16x8 af = *(const bf16x8*)&B1[mt*16 + (l&15)][ks*32 + (l>>4)*8];
      bf16x8 bf = *(const bf16x8*)&WVb[NV_FF1V + (size_t)(nt*16 + (l&15))*64 + ks*32 + (l>>4)*8];
      acc = __builtin_amdgcn_mfma_f32_16x16x32_bf16(af, bf, acc, 0, 0, 0);
    }
    const int vo = nt*16 + (l&15);
    const int r0 = mt*16 + (l>>4)*4;
    #pragma unroll
    for (int j=0;j<4;++j){
      int r = r0 + j;
      int nd = r/3, d = r - nd*3;
      int n = n0 + nd;
      if (n < N) fv1[(size_t)n*96 + d*32 + vo] = acc[j];
    }
  }
}

// ---------- node scalar FF (2 MFMA GEMMs) + fused final LN -> d_out ----------
__global__ __launch_bounds__(512) void k_node_s(
    const float* __restrict__ s_mid, const u16* __restrict__ vn0f, const u16* __restrict__ vn1f,
    const float* __restrict__ v_mid, const float* __restrict__ fv1,
    const u16* __restrict__ WB,
    const float* __restrict__ fb0, const float* __restrict__ fb1,
    const float* __restrict__ ln1g, const float* __restrict__ ln1b,
    float* __restrict__ out, int N)
{
  __shared__ __align__(16) char U1[16896];
  __shared__ __align__(16) u16 A2[32][584];
  u16 (*A1)[200] = (u16(*)[200])U1;
  float (*FS)[132] = (float(*)[132])U1;
  const int tid = threadIdx.x;
  const int n0 = blockIdx.x*32;

  for (int u=tid; u<32*48; u+=512){
    int nd = u/48, g = u - nd*48;
    int n = n0+nd;
    short4 v = {0,0,0,0};
    if (n<N){
      if (g < 32) v = pack4(*(const float4*)&s_mid[(size_t)n*128 + 4*g]);
      else        v = *(const short4*)&vn0f[(size_t)n*64 + 4*(g-32)];
    }
    *(short4*)&A1[nd][4*g] = v;
  }
  __syncthreads();

  const int w = tid>>6, l = tid&63;
  const int mt = w>>2, ng = w&3;
  const int kq = (l>>4)*8;
  const int ma = mt*16 + (l&15);
  const int r0 = mt*16 + (l>>4)*4;

  for (int nt2=0; nt2<8; ++nt2){
    const int nt = ng*8 + nt2;
    const int col = nt*16 + (l&15);
    f32x4 acc = {0.f,0.f,0.f,0.f};
    for (int ks=0; ks<6; ++ks){
      bf16x8 af = *(const bf16x8*)&A1[ma][ks*32 + kq];
      bf16x8 bf = *(const bf16x8*)&WB[WBF0 + (size_t)col*192 + ks*32 + kq];
      acc = __builtin_amdgcn_mfma_f32_16x16x32_bf16(af, bf, acc, 0, 0, 0);
    }
    float bias = fb0[col];
    #pragma unroll
    for (int j=0;j<4;++j) A2[r0+j][col] = f2b(fmaxf(acc[j] + bias, 0.f));
  }
  __syncthreads();
  for (int u=tid; u<32*16; u+=512){
    int nd=u>>4, q=u&15;
    int n=n0+nd;
    short4 v = {0,0,0,0};
    if (n<N) v = *(const short4*)&vn1f[(size_t)n*64 + 4*q];
    *(short4*)&A2[nd][512+4*q] = v;
  }
  __syncthreads();

  for (int nt2=0; nt2<2; ++nt2){
    const int nt = ng*2 + nt2;
    const int col = nt*16 + (l&15);
    f32x4 acc = {0.f,0.f,0.f,0.f};
    for (int ks=0; ks<18; ++ks){
      bf16x8 af = *(const bf16x8*)&A2[ma][ks*32 + kq];
      bf16x8 bf = *(const bf16x8*)&WB[WBF1 + (size_t)col*576 + ks*32 + kq];
      acc = __builtin_amdgcn_mfma_f32_16x16x32_bf16(af, bf, acc, 0, 0, 0);
    }
    float bias = fb1[col];
    #pragma unroll
    for (int j=0;j<4;++j) FS[r0+j][col] = acc[j] + bias;
  }
  __syncthreads();

  {
    const int nd = tid>>4, q = tid&15;
    const int n = n0 + nd;
    const bool live = n < N;
    float xs[8], sum=0.f, ss=0.f;
    #pragma unroll
    for (int j=0;j<8;++j){
      int c = q*8 + j;
      float x = 0.f;
      if (live) x = s_mid[(size_t)n*128 + c] + FS[nd][c];
      xs[j] = x; sum += x; ss += x*x;
    }
    #pragma unroll
    for (int m=1; m<16; m<<=1){ sum += __shfl_xor(sum, m); ss += __shfl_xor(ss, m); }
    const float mu = sum*(1.f/128.f);
    const float var = fmaxf(ss*(1.f/128.f) - mu*mu, 0.f);
    const float rstd = rsqrtf(var + 1e-5f);
    if (live){
      #pragma unroll
      for (int j=0;j<8;++j){
        int c = q*8 + j;
        out[(size_t)n*128 + c] = (xs[j]-mu)*rstd*ln1g[c] + ln1b[c];
      }
    }
    float z[2][3]; float vs = 0.f;
    #pragma unroll
    for (int j=0;j<2;++j){
      int vo = q + 16*j;
      #pragma unroll
      for (int d=0;d<3;++d){
        float y = live ? (v_mid[(size_t)n*96 + d*32 + vo] + fv1[(size_t)n*96 + d*32 + vo]) : 0.f;
        z[j][d] = y;
      }
      vs += fmaxf(z[j][0]*z[j][0]+z[j][1]*z[j][1]+z[j][2]*z[j][2], 1e-8f);
    }
    #pragma unroll
    for (int m=1; m<16; m<<=1) vs += __shfl_xor(vs, m);
    const float scale = rsqrtf(vs*(1.f/32.f));
    if (live){
      size_t base = (size_t)N*128 + (size_t)n*96;
      #pragma unroll
      for (int j=0;j<2;++j){
        int vo = q + 16*j;
        out[base + vo*3 + 0] = z[j][0]*scale;
        out[base + vo*3 + 1] = z[j][1]*scale;
        out[base + vo*3 + 2] = z[j][2]*scale;
      }
    }
  }
}

extern "C" void kernel_launch(void* const* d_in, const int* in_sizes, int n_in,
                              void* d_out, int out_size, void* d_ws, size_t ws_size,
                              hipStream_t stream)
{
  (void)n_in; (void)out_size;
  const int N = in_sizes[0]/128;
  const int E = in_sizes[4]/2;
  const int* ei = (const int*)d_in[4];

  size_t off = 0;
  auto alloc = [&](size_t bytes)->char*{
    size_t o = (off + 255) & ~(size_t)255;
    off = o + bytes;
    return (char*)d_ws + o;
  };
  u16*   WB      = (u16*)alloc((size_t)WB_TOTAL*2);
  u16*   WVb     = (u16*)alloc((size_t)WV_TOTAL*2);
  float* agg_s   = (float*)alloc((size_t)N*128*4);
  float* agg_v   = (float*)alloc((size_t)N*96*4);
  float* cnt     = (float*)alloc((size_t)N*4);
  size_t aggBytes = (size_t)((char*)(cnt+N) - (char*)agg_s);
  float* s_mid   = (float*)alloc((size_t)N*128*4);
  float* v_mid   = (float*)alloc((size_t)N*96*4);
  u16*   node_sb = (u16*)alloc((size_t)N*128*2);
  u16*   node_vb = (u16*)alloc((size_t)N*96*2);
  u16*   vn0f    = (u16*)alloc((size_t)N*64*2);
  u16*   vn1f    = (u16*)alloc((size_t)N*64*2);
  float* fv1     = (float*)alloc((size_t)N*96*4);
  int*   wpos    = (int*)alloc((size_t)N*4);
  int*   perm    = (int*)alloc((size_t)E*4);
  const size_t persist_end = off;

  size_t avail = (ws_size > persist_end + (1u<<20)) ? (ws_size - persist_end - (1u<<20)) : 0;
  long EC = (long)(avail / 288);
  if (EC < 8192) EC = 8192;
  if (EC > E) EC = E;
  u16* vnbuf = (u16*)alloc((size_t)EC*144*2);

  hipMemsetAsync(agg_s, 0, aggBytes, stream);
  k_wb<<<dim3((WB_TOTAL+255)/256), dim3(256), 0, stream>>>(
      (const float*)d_in[6], (const float*)d_in[10], (const float*)d_in[14],
      (const float*)d_in[20], (const float*)d_in[24], WB);
  k_wv<<<dim3((WV_TOTAL+255)/256), dim3(256), 0, stream>>>(
      (const float*)d_in[5], (const float*)d_in[8], (const float*)d_in[9],
      (const float*)d_in[12], (const float*)d_in[13], (const float*)d_in[16],
      (const float*)d_in[19], (const float*)d_in[22], (const float*)d_in[23],
      (const float*)d_in[26], WVb);
  k_prep<<<dim3((N*224+255)/256), dim3(256), 0, stream>>>(
      (const float*)d_in[0], (const float*)d_in[1], node_sb, node_vb, N);
  k_hist<<<dim3((E+255)/256), dim3(256), 0, stream>>>(ei, E, cnt);
  k_scan<<<dim3(1), dim3(256), 0, stream>>>(cnt, wpos, N);
  k_scatter<<<dim3((E+255)/256), dim3(256), 0, stream>>>(ei, E, wpos, perm);

  const int nch = (int)((E + EC - 1)/EC);
  for (int c=0; c<nch; ++c){
    const int eb = c*(int)EC;
    int ec = E - eb; if (ec > (int)EC) ec = (int)EC;
    if (ec <= 0) break;
    k_edge_v<<<dim3((ec+VEPB-1)/VEPB), dim3(256), 0, stream>>>(
        node_vb, (const float*)d_in[3], ei, E, perm, WVb, vnbuf, agg_v, eb, ec);
    k_edge_s<<<dim3((ec+SPB-1)/SPB), dim3(512), 0, stream>>>(
        node_sb, (const float*)d_in[2], ei, E, perm, WB, vnbuf,
        (const float*)d_in[7], (const float*)d_in[11], (const float*)d_in[15],
        agg_s, eb, ec);
  }

  k_ln0<<<dim3((N+255)/256), dim3(256), 0, stream>>>(
      (const float*)d_in[0], (const float*)d_in[1], agg_s, agg_v, cnt,
      (const float*)d_in[17], (const float*)d_in[18], s_mid, v_mid, N);

  k_node_v<<<dim3((N+31)/32), dim3(256), 0, stream>>>(v_mid, WVb, vn0f, vn1f, fv1, N);
  k_node_s<<<dim3((N+31)/32), dim3(512), 0, stream>>>(
      s_mid, vn0f, vn1f, v_mid, fv1, WB,
      (const float*)d_in[21], (const float*)d_in[25],
      (const float*)d_in[27], (const float*)d_in[28],
      (float*)d_out, N);
}

// Round 13
// 568.585 us; speedup vs baseline: 72.5291x; 1.0332x over previous
//
#include <hip/hip_runtime.h>

typedef unsigned short u16;
typedef __attribute__((ext_vector_type(8))) short bf16x8;
typedef __attribute__((ext_vector_type(4))) float f32x4;

__device__ __forceinline__ float b2f(u16 h){ return __uint_as_float(((unsigned)h)<<16); }
__device__ __forceinline__ u16 f2b(float f){
  unsigned u = __float_as_uint(f);
  unsigned r = ((u>>16)&1u) + 0x7fffu;
  return (u16)((u+r)>>16);
}
__device__ __forceinline__ short4 pack4(float4 f){
  short4 s; s.x=(short)f2b(f.x); s.y=(short)f2b(f.y); s.z=(short)f2b(f.z); s.w=(short)f2b(f.w);
  return s;
}

// WB bf16 arena: s-path weights, [O][K] layout
#define WB0   0        // [128][384]
#define WB1   49152    // [128][160]
#define WB2   69632    // [128][160]
#define WBF0  90112    // [512][192]
#define WBF1  188416   // [128][576]
#define WB_TOTAL 262144

// WVb bf16 arena: v-path weights, [N_pad][K_pad]
#define V_WH0   0
#define V_WV0   7680
#define V_WH1   10752
#define V_WV1   11776
#define V_WH2   12800
#define V_WV2   13824
#define NV_FF0H 14848
#define NV_FF0V 16896
#define NV_FF1H 20992
#define NV_FF1V 25088
#define WV_TOTAL 27136

__global__ __launch_bounds__(256) void k_wb(const float* __restrict__ w0,
    const float* __restrict__ w1, const float* __restrict__ w2,
    const float* __restrict__ f0, const float* __restrict__ f1,
    u16* __restrict__ WB){
  int t = blockIdx.x*256 + threadIdx.x;
  if (t < 49152){
    int o = t/384, k = t - o*384;
    WB[WB0 + t] = f2b(k < 353 ? w0[(size_t)o*353 + k] : 0.f);
    return;
  }
  t -= 49152;
  if (t < 20480){ WB[WB1 + t] = f2b(w1[t]); return; }
  t -= 20480;
  if (t < 20480){ WB[WB2 + t] = f2b(w2[t]); return; }
  t -= 20480;
  if (t < 98304){ WB[WBF0 + t] = f2b(f0[t]); return; }
  t -= 98304;
  if (t < 73728){ WB[WBF1 + t] = f2b(f1[t]); return; }
}

__global__ __launch_bounds__(256) void k_wv(const float* __restrict__ wh0, const float* __restrict__ wv0,
    const float* __restrict__ wh1, const float* __restrict__ wv1,
    const float* __restrict__ wh2, const float* __restrict__ wv2,
    const float* __restrict__ nf0h, const float* __restrict__ nf0v,
    const float* __restrict__ nf1h, const float* __restrict__ nf1v,
    u16* __restrict__ WVb){
  int t = blockIdx.x*256 + threadIdx.x;
  if (t < 7680){
    int n=t/96, k=t-n*96;
    float v = 0.f;
    if (n < 65){
      if (k < 32)       v = wh0[(size_t)n*65 + k];
      else if (k < 64)  v = wh0[(size_t)n*65 + 33 + (k-32)];
      else if (k == 64) v = wh0[(size_t)n*65 + 32];
    }
    WVb[V_WH0+t] = f2b(v);
    return;
  }
  t -= 7680;
  if (t < 3072){
    int n=t/96, k=t-n*96;
    WVb[V_WV0+t] = f2b((k<65) ? wv0[(size_t)n*65+k] : 0.f);
    return;
  }
  t -= 3072;
  if (t < 1024){ WVb[V_WH1+t]=f2b(wh1[t]); return; }
  t -= 1024;
  if (t < 1024){ WVb[V_WV1+t]=f2b(wv1[t]); return; }
  t -= 1024;
  if (t < 1024){ WVb[V_WH2+t]=f2b(wh2[t]); return; }
  t -= 1024;
  if (t < 1024){ WVb[V_WV2+t]=f2b(wv2[t]); return; }
  t -= 1024;
  if (t < 2048){ WVb[NV_FF0H+t]=f2b(nf0h[t]); return; }
  t -= 2048;
  if (t < 4096){ WVb[NV_FF0V+t]=f2b(nf0v[t]); return; }
  t -= 4096;
  if (t < 4096){ WVb[NV_FF1H+t]=f2b(nf1h[t]); return; }
  t -= 4096;
  if (t < 2048){ WVb[NV_FF1V+t]=f2b(nf1v[t]); return; }
}

__global__ __launch_bounds__(256) void k_prep(const float* __restrict__ node_s,
    const float* __restrict__ node_v, u16* __restrict__ node_sb,
    u16* __restrict__ node_vb, int N){
  int t = blockIdx.x*256 + threadIdx.x;
  if (t < N*128){ node_sb[t] = f2b(node_s[t]); return; }
  t -= N*128;
  if (t < N*96){
    int n=t/96, r=t-n*96, d=r>>5, vo=r&31;
    node_vb[(size_t)n*96 + d*32 + vo] = f2b(node_v[(size_t)n*96 + vo*3 + d]);
  }
}

__global__ __launch_bounds__(256) void k_hist(const int* __restrict__ ei, int E,
                                              float* __restrict__ cnt){
  int e = blockIdx.x*256 + threadIdx.x;
  if (e < E) atomicAdd(&cnt[ei[(size_t)E + e]], 1.f);
}

__global__ __launch_bounds__(256) void k_scan(const float* __restrict__ cnt,
                                              int* __restrict__ wpos, int N){
  __shared__ int part[256];
  const int tid = threadIdx.x;
  const int per = (N + 255)/256;
  const int base = tid*per;
  int s = 0;
  for (int i=0;i<per;++i){ int n=base+i; if (n<N) s += (int)cnt[n]; }
  part[tid] = s; __syncthreads();
  for (int st=1; st<256; st<<=1){
    int v = (tid>=st) ? part[tid-st] : 0;
    __syncthreads();
    part[tid] += v;
    __syncthreads();
  }
  int run = part[tid] - s;
  for (int i=0;i<per;++i){ int n=base+i; if (n<N){ wpos[n]=run; run += (int)cnt[n]; } }
}

__global__ __launch_bounds__(256) void k_scatter(const int* __restrict__ ei, int E,
                                                 int* __restrict__ wpos, int* __restrict__ perm){
  int e = blockIdx.x*256 + threadIdx.x;
  if (e >= E) return;
  int d = ei[(size_t)E + e];
  int pos = atomicAdd(&wpos[d], 1);
  perm[pos] = e;
}

// ---------- fused edge kernel: v-path + s-path, dst-sorted, segmented agg ----------
#define EPB 32
__global__ __launch_bounds__(512) void k_edge_fused(
    const u16* __restrict__ node_sb, const u16* __restrict__ node_vb,
    const float* __restrict__ edge_s, const float* __restrict__ edge_v,
    const int* __restrict__ ei, int E, const int* __restrict__ perm,
    const u16* __restrict__ WB, const u16* __restrict__ WVb,
    const float* __restrict__ b0p, const float* __restrict__ b1p, const float* __restrict__ b2p,
    float* __restrict__ agg_s, float* __restrict__ agg_v)
{
  __shared__ __align__(16) char R1[42240];
  __shared__ __align__(16) u16 VN0[EPB][80];
  __shared__ __align__(16) u16 VN1[EPB][32];
  __shared__ __align__(16) u16 VN2[EPB][32];
  __shared__ int SD[EPB][2];
  __shared__ int GE[EPB];
  u16 (*B0)[104]  = (u16(*)[104])R1;            // v-phase
  u16 (*B1)[104]  = (u16(*)[104])(R1 + 20480);
  float (*SCv)[33] = (float(*)[33])R1;           // overlays B0 (dead)
  u16 (*A)[392]   = (u16(*)[392])R1;             // s-phase (overlays B0+B1)
  float (*SC)[132] = (float(*)[132])R1;          // overlays A (dead)

  const int tid = threadIdx.x;
  const int w = tid>>6, l = tid&63;
  const int le0 = blockIdx.x*EPB;

  if (tid < EPB){
    int le = le0 + tid;
    int ge = (le<E) ? perm[le] : 0;
    GE[tid] = ge;
    SD[tid][0] = ei[ge];
    SD[tid][1] = ei[(size_t)E + ge];
  }
  __syncthreads();
  // stage B0 = mv (src|dst cols 0..63, edge col 64, zeros 65..95)
  for (int u=tid; u<96*16; u+=512){
    int r=u>>4, g=u&15, ee=r/3, d=r-ee*3;
    int le=le0+ee;
    short4 v = {0,0,0,0};
    if (le<E){
      int node = (g<8) ? SD[ee][0] : SD[ee][1];
      v = *(const short4*)&node_vb[(size_t)node*96 + d*32 + 4*(g&7)];
    }
    *(short4*)&B0[r][4*g] = v;
  }
  for (int u=tid; u<96*8; u+=512){
    int r=u>>3, g=u&7, ee=r/3, d=r-ee*3;
    int le=le0+ee;
    short4 v = {0,0,0,0};
    if (g==0 && le<E) v.x = (short)f2b(edge_v[(size_t)GE[ee]*3 + d]);
    *(short4*)&B0[r][64+4*g] = v;
  }
  for (int u=tid; u<96*4; u+=512){
    int r=u>>2, g=u&3;
    *(short4*)&B1[r][80+4*g] = (short4){0,0,0,0};
  }
  __syncthreads();

  auto mm = [&](const u16 (*Ai)[104], int woff, int Kp, int NT, u16 (*C)[104]){
    const int nks = Kp>>5;
    for (int t=w; t<6*NT; t+=8){
      int mt = t % 6, nt = t / 6;
      f32x4 acc = {0.f,0.f,0.f,0.f};
      for (int ks=0; ks<nks; ++ks){
        bf16x8 af = *(const bf16x8*)&Ai[mt*16 + (l&15)][ks*32 + (l>>4)*8];
        bf16x8 bf = *(const bf16x8*)&WVb[woff + (size_t)(nt*16 + (l&15))*Kp + ks*32 + (l>>4)*8];
        acc = __builtin_amdgcn_mfma_f32_16x16x32_bf16(af, bf, acc, 0, 0, 0);
      }
      const int col = nt*16 + (l&15);
      const int r0 = mt*16 + (l>>4)*4;
      C[r0+0][col]=f2b(acc[0]); C[r0+1][col]=f2b(acc[1]);
      C[r0+2][col]=f2b(acc[2]); C[r0+3][col]=f2b(acc[3]);
    }
  };

  // ---- v-path ----
  mm(B0, V_WH0, 96, 5, B1);
  __syncthreads();
  for (int u=tid; u<EPB*80; u+=512){
    int ee=u/80, h=u-ee*80;
    u16 val = 0;
    if (h<65){
      float x0=b2f(B1[ee*3+0][h]), x1=b2f(B1[ee*3+1][h]), x2=b2f(B1[ee*3+2][h]);
      val = f2b(sqrtf(fmaxf(x0*x0+x1*x1+x2*x2, 1e-8f)));
    }
    VN0[ee][h] = val;
  }
  mm(B1, V_WV0, 96, 2, B0);
  __syncthreads();
  for (int u=tid; u<EPB*32; u+=512){
    int ee=u>>5, vo=u&31;
    float x0=b2f(B0[ee*3+0][vo]), x1=b2f(B0[ee*3+1][vo]), x2=b2f(B0[ee*3+2][vo]);
    float nn=sqrtf(fmaxf(x0*x0+x1*x1+x2*x2, 1e-8f));
    float sg=1.f/(1.f+__expf(-nn));
    B0[ee*3+0][vo]=f2b(x0*sg); B0[ee*3+1][vo]=f2b(x1*sg); B0[ee*3+2][vo]=f2b(x2*sg);
  }
  __syncthreads();
  mm(B0, V_WH1, 32, 2, B1);
  __syncthreads();
  for (int u=tid; u<EPB*32; u+=512){
    int ee=u>>5, h=u&31;
    float x0=b2f(B1[ee*3+0][h]), x1=b2f(B1[ee*3+1][h]), x2=b2f(B1[ee*3+2][h]);
    VN1[ee][h] = f2b(sqrtf(fmaxf(x0*x0+x1*x1+x2*x2, 1e-8f)));
  }
  mm(B1, V_WV1, 32, 2, B0);
  __syncthreads();
  for (int u=tid; u<EPB*32; u+=512){
    int ee=u>>5, vo=u&31;
    float x0=b2f(B0[ee*3+0][vo]), x1=b2f(B0[ee*3+1][vo]), x2=b2f(B0[ee*3+2][vo]);
    float nn=sqrtf(fmaxf(x0*x0+x1*x1+x2*x2, 1e-8f));
    float sg=1.f/(1.f+__expf(-nn));
    B0[ee*3+0][vo]=f2b(x0*sg); B0[ee*3+1][vo]=f2b(x1*sg); B0[ee*3+2][vo]=f2b(x2*sg);
  }
  __syncthreads();
  mm(B0, V_WH2, 32, 2, B1);
  __syncthreads();           // B0 dead; SCv overlays it
  for (int u=tid; u<EPB*32; u+=512){
    int ee=u>>5, h=u&31;
    float x0=b2f(B1[ee*3+0][h]), x1=b2f(B1[ee*3+1][h]), x2=b2f(B1[ee*3+2][h]);
    VN2[ee][h] = f2b(sqrtf(fmaxf(x0*x0+x1*x1+x2*x2, 1e-8f)));
  }
  for (int t=w; t<12; t+=8){
    int mt = t % 6, nt = t / 6;
    f32x4 acc = {0.f,0.f,0.f,0.f};
    bf16x8 af = *(const bf16x8*)&B1[mt*16 + (l&15)][(l>>4)*8];
    bf16x8 bf = *(const bf16x8*)&WVb[V_WV2 + (size_t)(nt*16 + (l&15))*32 + (l>>4)*8];
    acc = __builtin_amdgcn_mfma_f32_16x16x32_bf16(af, bf, acc, 0, 0, 0);
    const int vo = nt*16 + (l&15);
    const int r0 = mt*16 + (l>>4)*4;
    #pragma unroll
    for (int j=0;j<4;++j){
      int r = r0 + j;
      int le = le0 + r/3;
      SCv[r][vo] = (le < E) ? acc[j] : 0.f;
    }
  }
  __syncthreads();
  if (tid < 96){
    const int vo = tid & 31, d = tid >> 5;
    float run = 0.f; int prev = -1;
    for (int ee=0; ee<EPB; ++ee){
      int le = le0 + ee;
      int dn = (le<E) ? SD[ee][1] : -1;
      if (dn != prev){
        if (prev >= 0) atomicAdd(&agg_v[(size_t)prev*96 + vo*3 + d], run);
        run = 0.f; prev = dn;
      }
      run += SCv[ee*3+d][vo];
    }
    if (prev >= 0) atomicAdd(&agg_v[(size_t)prev*96 + vo*3 + d], run);
  }
  __syncthreads();           // SCv + B1 dead; A overlays R1

  // ---- s-path staging ----
  for (int u=tid; u<EPB*98; u+=512){
    int ee = u/98, g = u - ee*98;
    int le = le0+ee;
    short4 v = {0,0,0,0};
    if (le<E){
      if (g < 32)      v = *(const short4*)&node_sb[(size_t)SD[ee][0]*128 + 4*g];
      else if (g < 40) v = pack4(*(const float4*)&edge_s[(size_t)GE[ee]*32 + 4*(g-32)]);
      else if (g < 72) v = *(const short4*)&node_sb[(size_t)SD[ee][1]*128 + 4*(g-40)];
      else if (g < 92) v = *(const short4*)&VN0[ee][4*(g-72)];
    }
    *(short4*)&A[ee][4*g] = v;
  }
  __syncthreads();

  const int mt = w>>2, nt = w&3;
  const int n_a = nt*32 + (l&15), n_b = n_a + 16;
  const int kq = (l>>4)*8;
  const int ma = mt*16 + (l&15);
  f32x4 ca = {0.f,0.f,0.f,0.f}, cb = {0.f,0.f,0.f,0.f};

  for (int kk=0; kk<384; kk+=32){
    bf16x8 af = *(const bf16x8*)&A[ma][kk + kq];
    bf16x8 b1 = *(const bf16x8*)&WB[WB0 + (size_t)n_a*384 + kk + kq];
    bf16x8 b2 = *(const bf16x8*)&WB[WB0 + (size_t)n_b*384 + kk + kq];
    ca = __builtin_amdgcn_mfma_f32_16x16x32_bf16(af, b1, ca, 0, 0, 0);
    cb = __builtin_amdgcn_mfma_f32_16x16x32_bf16(af, b2, cb, 0, 0, 0);
  }
  __syncthreads();
  {
    float ba = b0p[n_a], bb = b0p[n_b];
    #pragma unroll
    for (int j=0;j<4;++j){
      int r = mt*16 + (l>>4)*4 + j;
      A[r][n_a] = f2b(fmaxf(ca[j] + ba, 0.f));
      A[r][n_b] = f2b(fmaxf(cb[j] + bb, 0.f));
    }
  }
  for (int u=tid; u<EPB*8; u+=512){
    int ee=u>>3, q=u&7;
    *(short4*)&A[ee][128+4*q] = *(const short4*)&VN1[ee][4*q];
  }
  __syncthreads();

  ca = (f32x4){0.f,0.f,0.f,0.f}; cb = (f32x4){0.f,0.f,0.f,0.f};
  for (int kk=0; kk<160; kk+=32){
    bf16x8 af = *(const bf16x8*)&A[ma][kk + kq];
    bf16x8 b1 = *(const bf16x8*)&WB[WB1 + (size_t)n_a*160 + kk + kq];
    bf16x8 b2 = *(const bf16x8*)&WB[WB1 + (size_t)n_b*160 + kk + kq];
    ca = __builtin_amdgcn_mfma_f32_16x16x32_bf16(af, b1, ca, 0, 0, 0);
    cb = __builtin_amdgcn_mfma_f32_16x16x32_bf16(af, b2, cb, 0, 0, 0);
  }
  __syncthreads();
  {
    float ba = b1p[n_a], bb = b1p[n_b];
    #pragma unroll
    for (int j=0;j<4;++j){
      int r = mt*16 + (l>>4)*4 + j;
      A[r][n_a] = f2b(fmaxf(ca[j] + ba, 0.f));
      A[r][n_b] = f2b(fmaxf(cb[j] + bb, 0.f));
    }
  }
  for (int u=tid; u<EPB*8; u+=512){
    int ee=u>>3, q=u&7;
    *(short4*)&A[ee][128+4*q] = *(const short4*)&VN2[ee][4*q];
  }
  __syncthreads();

  ca = (f32x4){0.f,0.f,0.f,0.f}; cb = (f32x4){0.f,0.f,0.f,0.f};
  for (int kk=0; kk<160; kk+=32){
    bf16x8 af = *(const bf16x8*)&A[ma][kk + kq];
    bf16x8 b1 = *(const bf16x8*)&WB[WB2 + (size_t)n_a*160 + kk + kq];
    bf16x8 b2 = *(const bf16x8*)&WB[WB2 + (size_t)n_b*160 + kk + kq];
    ca = __builtin_amdgcn_mfma_f32_16x16x32_bf16(af, b1, ca, 0, 0, 0);
    cb = __builtin_amdgcn_mfma_f32_16x16x32_bf16(af, b2, cb, 0, 0, 0);
  }
  __syncthreads();           // A dead; SC overlays it
  {
    float ba = b2p[n_a], bb = b2p[n_b];
    #pragma unroll
    for (int j=0;j<4;++j){
      int r = mt*16 + (l>>4)*4 + j;
      int le = le0 + r;
      SC[r][n_a] = (le<E) ? (ca[j] + ba) : 0.f;
      SC[r][n_b] = (le<E) ? (cb[j] + bb) : 0.f;
    }
  }
  __syncthreads();
  if (tid < 128){
    const int c = tid;
    float run = 0.f; int prev = -1;
    for (int r=0; r<EPB; ++r){
      int le = le0 + r;
      int dn = (le<E) ? SD[r][1] : -1;
      if (dn != prev){
        if (prev >= 0) atomicAdd(&agg_s[(size_t)prev*128 + c], run);
        run = 0.f; prev = dn;
      }
      run += SC[r][c];
    }
    if (prev >= 0) atomicAdd(&agg_s[(size_t)prev*128 + c], run);
  }
}

// ---------- residual + tuple LayerNorm after aggregation ----------
__global__ __launch_bounds__(256) void k_ln0(
    const float* __restrict__ node_s, const float* __restrict__ node_v,
    const float* __restrict__ agg_s, const float* __restrict__ agg_v,
    const float* __restrict__ cnt,
    const float* __restrict__ g, const float* __restrict__ b,
    float* __restrict__ s_mid, float* __restrict__ v_mid, int N)
{
  int n = blockIdx.x*256 + threadIdx.x;
  if (n>=N) return;
  const float inv = 1.f/fmaxf(cnt[n], 1.f);
  float sum=0.f, ss=0.f;
  for (int i=0;i<128;++i){
    float x = node_s[(size_t)n*128+i] + agg_s[(size_t)n*128+i]*inv;
    sum += x; ss += x*x;
  }
  const float mu = sum*(1.f/128.f);
  const float var = fmaxf(ss*(1.f/128.f) - mu*mu, 0.f);
  const float rstd = rsqrtf(var + 1e-5f);
  for (int i=0;i<128;++i){
    float x = node_s[(size_t)n*128+i] + agg_s[(size_t)n*128+i]*inv;
    s_mid[(size_t)n*128+i] = (x-mu)*rstd*g[i] + b[i];
  }
  float vs=0.f;
  for (int vo=0;vo<32;++vo){
    float y0 = node_v[(size_t)n*96+vo*3+0] + agg_v[(size_t)n*96+vo*3+0]*inv;
    float y1 = node_v[(size_t)n*96+vo*3+1] + agg_v[(size_t)n*96+vo*3+1]*inv;
    float y2 = node_v[(size_t)n*96+vo*3+2] + agg_v[(size_t)n*96+vo*3+2]*inv;
    vs += fmaxf(y0*y0+y1*y1+y2*y2, 1e-8f);
  }
  const float scale = rsqrtf(vs*(1.f/32.f));
  for (int vo=0;vo<32;++vo){
    float y0 = node_v[(size_t)n*96+vo*3+0] + agg_v[(size_t)n*96+vo*3+0]*inv;
    float y1 = node_v[(size_t)n*96+vo*3+1] + agg_v[(size_t)n*96+vo*3+1]*inv;
    float y2 = node_v[(size_t)n*96+vo*3+2] + agg_v[(size_t)n*96+vo*3+2]*inv;
    v_mid[(size_t)n*96+vo]      = y0*scale;
    v_mid[(size_t)n*96+32+vo]   = y1*scale;
    v_mid[(size_t)n*96+64+vo]   = y2*scale;
  }
}

// ---------- node vector FF (batched MFMA) ----------
__global__ __launch_bounds__(256) void k_node_v(
    const float* __restrict__ v_mid, const u16* __restrict__ WVb,
    u16* __restrict__ vn0f, u16* __restrict__ vn1f, float* __restrict__ fv1, int N)
{
  __shared__ __align__(16) u16 B0[96][104];
  __shared__ __align__(16) u16 B1[96][104];
  const int tid = threadIdx.x;
  const int w = tid>>6, l = tid&63;
  const int n0 = blockIdx.x*32;

  for (int u=tid; u<96*8; u+=256){
    int r=u>>3, g=u&7, nd=r/3, d=r-nd*3;
    int n=n0+nd;
    short4 v = {0,0,0,0};
    if (n<N) v = pack4(*(const float4*)&v_mid[(size_t)n*96 + d*32 + 4*g]);
    *(short4*)&B0[r][4*g] = v;
  }
  __syncthreads();

  auto mm = [&](const u16 (*A)[104], int woff, int Kp, int NT, u16 (*C)[104]){
    const int nks = Kp>>5;
    for (int t=w; t<6*NT; t+=4){
      int mt = t % 6, nt = t / 6;
      f32x4 acc = {0.f,0.f,0.f,0.f};
      for (int ks=0; ks<nks; ++ks){
        bf16x8 af = *(const bf16x8*)&A[mt*16 + (l&15)][ks*32 + (l>>4)*8];
        bf16x8 bf = *(const bf16x8*)&WVb[woff + (size_t)(nt*16 + (l&15))*Kp + ks*32 + (l>>4)*8];
        acc = __builtin_amdgcn_mfma_f32_16x16x32_bf16(af, bf, acc, 0, 0, 0);
      }
      const int col = nt*16 + (l&15);
      const int r0 = mt*16 + (l>>4)*4;
      C[r0+0][col]=f2b(acc[0]); C[r0+1][col]=f2b(acc[1]);
      C[r0+2][col]=f2b(acc[2]); C[r0+3][col]=f2b(acc[3]);
    }
  };

  mm(B0, NV_FF0H, 32, 4, B1);
  __syncthreads();
  for (int u=tid; u<32*64; u+=256){
    int nd=u>>6, h=u&63;
    int n=n0+nd;
    if (n<N){
      float x0=b2f(B1[nd*3+0][h]), x1=b2f(B1[nd*3+1][h]), x2=b2f(B1[nd*3+2][h]);
      vn0f[(size_t)n*64+h] = f2b(sqrtf(fmaxf(x0*x0+x1*x1+x2*x2, 1e-8f)));
    }
  }
  mm(B1, NV_FF0V, 64, 4, B0);
  __syncthreads();
  for (int u=tid; u<32*64; u+=256){
    int nd=u>>6, vo=u&63;
    float x0=b2f(B0[nd*3+0][vo]), x1=b2f(B0[nd*3+1][vo]), x2=b2f(B0[nd*3+2][vo]);
    float nn=sqrtf(fmaxf(x0*x0+x1*x1+x2*x2, 1e-8f));
    float sg=1.f/(1.f+__expf(-nn));
    B0[nd*3+0][vo]=f2b(x0*sg); B0[nd*3+1][vo]=f2b(x1*sg); B0[nd*3+2][vo]=f2b(x2*sg);
  }
  __syncthreads();
  mm(B0, NV_FF1H, 64, 4, B1);
  __syncthreads();
  for (int u=tid; u<32*64; u+=256){
    int nd=u>>6, h=u&63;
    int n=n0+nd;
    if (n<N){
      float x0=b2f(B1[nd*3+0][h]), x1=b2f(B1[nd*3+1][h]), x2=b2f(B1[nd*3+2][h]);
      vn1f[(size_t)n*64+h] = f2b(sqrtf(fmaxf(x0*x0+x1*x1+x2*x2, 1e-8f)));
    }
  }
  for (int t=w; t<12; t+=4){
    int mt = t % 6, nt = t / 6;
    f32x4 acc = {0.f,0.f,0.f,0.f};
    for (int ks=0; ks<2; ++ks){
      bf16x8 af = *(const bf16x8*)&B1[mt*16 + (l&15)][ks*32 + (l>>4)*8];
      bf16x8 bf = *(const bf16x8*)&WVb[NV_FF1V + (size_t)(nt*16 + (l&15))*64 + ks*32 + (l>>4)*8];
      acc = __builtin_amdgcn_mfma_f32_16x16x32_bf16(af, bf, acc, 0, 0, 0);
    }
    const int vo = nt*16 + (l&15);
    const int r0 = mt*16 + (l>>4)*4;
    #pragma unroll
    for (int j=0;j<4;++j){
      int r = r0 + j;
      int nd = r/3, d = r - nd*3;
      int n = n0 + nd;
      if (n < N) fv1[(size_t)n*96 + d*32 + vo] = acc[j];
    }
  }
}

// ---------- node scalar FF (2 MFMA GEMMs) + fused final LN -> d_out ----------
__global__ __launch_bounds__(512) void k_node_s(
    const float* __restrict__ s_mid, const u16* __restrict__ vn0f, const u16* __restrict__ vn1f,
    const float* __restrict__ v_mid, const float* __restrict__ fv1,
    const u16* __restrict__ WB,
    const float* __restrict__ fb0, const float* __restrict__ fb1,
    const float* __restrict__ ln1g, const float* __restrict__ ln1b,
    float* __restrict__ out, int N)
{
  __shared__ __align__(16) char U1[16896];
  __shared__ __align__(16) u16 A2[32][584];
  u16 (*A1)[200] = (u16(*)[200])U1;
  float (*FS)[132] = (float(*)[132])U1;
  const int tid = threadIdx.x;
  const int n0 = blockIdx.x*32;

  for (int u=tid; u<32*48; u+=512){
    int nd = u/48, g = u - nd*48;
    int n = n0+nd;
    short4 v = {0,0,0,0};
    if (n<N){
      if (g < 32) v = pack4(*(const float4*)&s_mid[(size_t)n*128 + 4*g]);
      else        v = *(const short4*)&vn0f[(size_t)n*64 + 4*(g-32)];
    }
    *(short4*)&A1[nd][4*g] = v;
  }
  __syncthreads();

  const int w = tid>>6, l = tid&63;
  const int mt = w>>2, ng = w&3;
  const int kq = (l>>4)*8;
  const int ma = mt*16 + (l&15);
  const int r0 = mt*16 + (l>>4)*4;

  for (int nt2=0; nt2<8; ++nt2){
    const int nt = ng*8 + nt2;
    const int col = nt*16 + (l&15);
    f32x4 acc = {0.f,0.f,0.f,0.f};
    for (int ks=0; ks<6; ++ks){
      bf16x8 af = *(const bf16x8*)&A1[ma][ks*32 + kq];
      bf16x8 bf = *(const bf16x8*)&WB[WBF0 + (size_t)col*192 + ks*32 + kq];
      acc = __builtin_amdgcn_mfma_f32_16x16x32_bf16(af, bf, acc, 0, 0, 0);
    }
    float bias = fb0[col];
    #pragma unroll
    for (int j=0;j<4;++j) A2[r0+j][col] = f2b(fmaxf(acc[j] + bias, 0.f));
  }
  __syncthreads();
  for (int u=tid; u<32*16; u+=512){
    int nd=u>>4, q=u&15;
    int n=n0+nd;
    short4 v = {0,0,0,0};
    if (n<N) v = *(const short4*)&vn1f[(size_t)n*64 + 4*q];
    *(short4*)&A2[nd][512+4*q] = v;
  }
  __syncthreads();

  for (int nt2=0; nt2<2; ++nt2){
    const int nt = ng*2 + nt2;
    const int col = nt*16 + (l&15);
    f32x4 acc = {0.f,0.f,0.f,0.f};
    for (int ks=0; ks<18; ++ks){
      bf16x8 af = *(const bf16x8*)&A2[ma][ks*32 + kq];
      bf16x8 bf = *(const bf16x8*)&WB[WBF1 + (size_t)col*576 + ks*32 + kq];
      acc = __builtin_amdgcn_mfma_f32_16x16x32_bf16(af, bf, acc, 0, 0, 0);
    }
    float bias = fb1[col];
    #pragma unroll
    for (int j=0;j<4;++j) FS[r0+j][col] = acc[j] + bias;
  }
  __syncthreads();

  {
    const int nd = tid>>4, q = tid&15;
    const int n = n0 + nd;
    const bool live = n < N;
    float xs[8], sum=0.f, ss=0.f;
    #pragma unroll
    for (int j=0;j<8;++j){
      int c = q*8 + j;
      float x = 0.f;
      if (live) x = s_mid[(size_t)n*128 + c] + FS[nd][c];
      xs[j] = x; sum += x; ss += x*x;
    }
    #pragma unroll
    for (int m=1; m<16; m<<=1){ sum += __shfl_xor(sum, m); ss += __shfl_xor(ss, m); }
    const float mu = sum*(1.f/128.f);
    const float var = fmaxf(ss*(1.f/128.f) - mu*mu, 0.f);
    const float rstd = rsqrtf(var + 1e-5f);
    if (live){
      #pragma unroll
      for (int j=0;j<8;++j){
        int c = q*8 + j;
        out[(size_t)n*128 + c] = (xs[j]-mu)*rstd*ln1g[c] + ln1b[c];
      }
    }
    float z[2][3]; float vs = 0.f;
    #pragma unroll
    for (int j=0;j<2;++j){
      int vo = q + 16*j;
      #pragma unroll
      for (int d=0;d<3;++d){
        float y = live ? (v_mid[(size_t)n*96 + d*32 + vo] + fv1[(size_t)n*96 + d*32 + vo]) : 0.f;
        z[j][d] = y;
      }
      vs += fmaxf(z[j][0]*z[j][0]+z[j][1]*z[j][1]+z[j][2]*z[j][2], 1e-8f);
    }
    #pragma unroll
    for (int m=1; m<16; m<<=1) vs += __shfl_xor(vs, m);
    const float scale = rsqrtf(vs*(1.f/32.f));
    if (live){
      size_t base = (size_t)N*128 + (size_t)n*96;
      #pragma unroll
      for (int j=0;j<2;++j){
        int vo = q + 16*j;
        out[base + vo*3 + 0] = z[j][0]*scale;
        out[base + vo*3 + 1] = z[j][1]*scale;
        out[base + vo*3 + 2] = z[j][2]*scale;
      }
    }
  }
}

extern "C" void kernel_launch(void* const* d_in, const int* in_sizes, int n_in,
                              void* d_out, int out_size, void* d_ws, size_t ws_size,
                              hipStream_t stream)
{
  (void)n_in; (void)out_size; (void)ws_size;
  const int N = in_sizes[0]/128;
  const int E = in_sizes[4]/2;
  const int* ei = (const int*)d_in[4];

  size_t off = 0;
  auto alloc = [&](size_t bytes)->char*{
    size_t o = (off + 255) & ~(size_t)255;
    off = o + bytes;
    return (char*)d_ws + o;
  };
  u16*   WB      = (u16*)alloc((size_t)WB_TOTAL*2);
  u16*   WVb     = (u16*)alloc((size_t)WV_TOTAL*2);
  float* agg_s   = (float*)alloc((size_t)N*128*4);
  float* agg_v   = (float*)alloc((size_t)N*96*4);
  float* cnt     = (float*)alloc((size_t)N*4);
  size_t aggBytes = (size_t)((char*)(cnt+N) - (char*)agg_s);
  float* s_mid   = (float*)alloc((size_t)N*128*4);
  float* v_mid   = (float*)alloc((size_t)N*96*4);
  u16*   node_sb = (u16*)alloc((size_t)N*128*2);
  u16*   node_vb = (u16*)alloc((size_t)N*96*2);
  u16*   vn0f    = (u16*)alloc((size_t)N*64*2);
  u16*   vn1f    = (u16*)alloc((size_t)N*64*2);
  float* fv1     = (float*)alloc((size_t)N*96*4);
  int*   wpos    = (int*)alloc((size_t)N*4);
  int*   perm    = (int*)alloc((size_t)E*4);

  hipMemsetAsync(agg_s, 0, aggBytes, stream);
  k_wb<<<dim3((WB_TOTAL+255)/256), dim3(256), 0, stream>>>(
      (const float*)d_in[6], (const float*)d_in[10], (const float*)d_in[14],
      (const float*)d_in[20], (const float*)d_in[24], WB);
  k_wv<<<dim3((WV_TOTAL+255)/256), dim3(256), 0, stream>>>(
      (const float*)d_in[5], (const float*)d_in[8], (const float*)d_in[9],
      (const float*)d_in[12], (const float*)d_in[13], (const float*)d_in[16],
      (const float*)d_in[19], (const float*)d_in[22], (const float*)d_in[23],
      (const float*)d_in[26], WVb);
  k_prep<<<dim3((N*224+255)/256), dim3(256), 0, stream>>>(
      (const float*)d_in[0], (const float*)d_in[1], node_sb, node_vb, N);
  k_hist<<<dim3((E+255)/256), dim3(256), 0, stream>>>(ei, E, cnt);
  k_scan<<<dim3(1), dim3(256), 0, stream>>>(cnt, wpos, N);
  k_scatter<<<dim3((E+255)/256), dim3(256), 0, stream>>>(ei, E, wpos, perm);

  k_edge_fused<<<dim3((E+EPB-1)/EPB), dim3(512), 0, stream>>>(
      node_sb, node_vb, (const float*)d_in[2], (const float*)d_in[3],
      ei, E, perm, WB, WVb,
      (const float*)d_in[7], (const float*)d_in[11], (const float*)d_in[15],
      agg_s, agg_v);

  k_ln0<<<dim3((N+255)/256), dim3(256), 0, stream>>>(
      (const float*)d_in[0], (const float*)d_in[1], agg_s, agg_v, cnt,
      (const float*)d_in[17], (const float*)d_in[18], s_mid, v_mid, N);

  k_node_v<<<dim3((N+31)/32), dim3(256), 0, stream>>>(v_mid, WVb, vn0f, vn1f, fv1, N);
  k_node_s<<<dim3((N+31)/32), dim3(512), 0, stream>>>(
      s_mid, vn0f, vn1f, v_mid, fv1, WB,
      (const float*)d_in[21], (const float*)d_in[25],
      (const float*)d_in[27], (const float*)d_in[28],
      (float*)d_out, N);
}

// Round 14
// 523.658 us; speedup vs baseline: 78.7517x; 1.0858x over previous
//
#include <hip/hip_runtime.h>

typedef unsigned short u16;
typedef __attribute__((ext_vector_type(8))) short bf16x8;
typedef __attribute__((ext_vector_type(4))) float f32x4;

__device__ __forceinline__ float b2f(u16 h){ return __uint_as_float(((unsigned)h)<<16); }
__device__ __forceinline__ u16 f2b(float f){
  unsigned u = __float_as_uint(f);
  unsigned r = ((u>>16)&1u) + 0x7fffu;
  return (u16)((u+r)>>16);
}
__device__ __forceinline__ short4 pack4(float4 f){
  short4 s; s.x=(short)f2b(f.x); s.y=(short)f2b(f.y); s.z=(short)f2b(f.z); s.w=(short)f2b(f.w);
  return s;
}

// WB bf16 arena: s-path weights, [O][K] layout
#define WB0   0        // [128][384]
#define WB1   49152    // [128][160]
#define WB2   69632    // [128][160]
#define WBF0  90112    // [512][192]
#define WBF1  188416   // [128][576]
#define WB_TOTAL 262144

// WVb bf16 arena: v-path weights, [N_pad][K_pad]
#define V_WH0   0
#define V_WV0   7680
#define V_WH1   10752
#define V_WV1   11776
#define V_WH2   12800
#define V_WV2   13824
#define NV_FF0H 14848
#define NV_FF0V 16896
#define NV_FF1H 20992
#define NV_FF1V 25088
#define WV_TOTAL 27136

__global__ __launch_bounds__(256) void k_wb(const float* __restrict__ w0,
    const float* __restrict__ w1, const float* __restrict__ w2,
    const float* __restrict__ f0, const float* __restrict__ f1,
    u16* __restrict__ WB){
  int t = blockIdx.x*256 + threadIdx.x;
  if (t < 49152){
    int o = t/384, k = t - o*384;
    WB[WB0 + t] = f2b(k < 353 ? w0[(size_t)o*353 + k] : 0.f);
    return;
  }
  t -= 49152;
  if (t < 20480){ WB[WB1 + t] = f2b(w1[t]); return; }
  t -= 20480;
  if (t < 20480){ WB[WB2 + t] = f2b(w2[t]); return; }
  t -= 20480;
  if (t < 98304){ WB[WBF0 + t] = f2b(f0[t]); return; }
  t -= 98304;
  if (t < 73728){ WB[WBF1 + t] = f2b(f1[t]); return; }
}

__global__ __launch_bounds__(256) void k_wv(const float* __restrict__ wh0, const float* __restrict__ wv0,
    const float* __restrict__ wh1, const float* __restrict__ wv1,
    const float* __restrict__ wh2, const float* __restrict__ wv2,
    const float* __restrict__ nf0h, const float* __restrict__ nf0v,
    const float* __restrict__ nf1h, const float* __restrict__ nf1v,
    u16* __restrict__ WVb){
  int t = blockIdx.x*256 + threadIdx.x;
  if (t < 7680){
    int n=t/96, k=t-n*96;
    float v = 0.f;
    if (n < 65){
      if (k < 32)       v = wh0[(size_t)n*65 + k];
      else if (k < 64)  v = wh0[(size_t)n*65 + 33 + (k-32)];
      else if (k == 64) v = wh0[(size_t)n*65 + 32];
    }
    WVb[V_WH0+t] = f2b(v);
    return;
  }
  t -= 7680;
  if (t < 3072){
    int n=t/96, k=t-n*96;
    WVb[V_WV0+t] = f2b((k<65) ? wv0[(size_t)n*65+k] : 0.f);
    return;
  }
  t -= 3072;
  if (t < 1024){ WVb[V_WH1+t]=f2b(wh1[t]); return; }
  t -= 1024;
  if (t < 1024){ WVb[V_WV1+t]=f2b(wv1[t]); return; }
  t -= 1024;
  if (t < 1024){ WVb[V_WH2+t]=f2b(wh2[t]); return; }
  t -= 1024;
  if (t < 1024){ WVb[V_WV2+t]=f2b(wv2[t]); return; }
  t -= 1024;
  if (t < 2048){ WVb[NV_FF0H+t]=f2b(nf0h[t]); return; }
  t -= 2048;
  if (t < 4096){ WVb[NV_FF0V+t]=f2b(nf0v[t]); return; }
  t -= 4096;
  if (t < 4096){ WVb[NV_FF1H+t]=f2b(nf1h[t]); return; }
  t -= 4096;
  if (t < 2048){ WVb[NV_FF1V+t]=f2b(nf1v[t]); return; }
}

__global__ __launch_bounds__(256) void k_prep(const float* __restrict__ node_s,
    const float* __restrict__ node_v, u16* __restrict__ node_sb,
    u16* __restrict__ node_vb, int N){
  int t = blockIdx.x*256 + threadIdx.x;
  if (t < N*128){ node_sb[t] = f2b(node_s[t]); return; }
  t -= N*128;
  if (t < N*96){
    int n=t/96, r=t-n*96, d=r>>5, vo=r&31;
    node_vb[(size_t)n*96 + d*32 + vo] = f2b(node_v[(size_t)n*96 + vo*3 + d]);
  }
}

__global__ __launch_bounds__(256) void k_hist(const int* __restrict__ ei, int E,
                                              float* __restrict__ cnt){
  int e = blockIdx.x*256 + threadIdx.x;
  if (e < E) atomicAdd(&cnt[ei[(size_t)E + e]], 1.f);
}

__global__ __launch_bounds__(256) void k_scan(const float* __restrict__ cnt,
                                              int* __restrict__ wpos, int N){
  __shared__ int part[256];
  const int tid = threadIdx.x;
  const int per = (N + 255)/256;
  const int base = tid*per;
  int s = 0;
  for (int i=0;i<per;++i){ int n=base+i; if (n<N) s += (int)cnt[n]; }
  part[tid] = s; __syncthreads();
  for (int st=1; st<256; st<<=1){
    int v = (tid>=st) ? part[tid-st] : 0;
    __syncthreads();
    part[tid] += v;
    __syncthreads();
  }
  int run = part[tid] - s;
  for (int i=0;i<per;++i){ int n=base+i; if (n<N){ wpos[n]=run; run += (int)cnt[n]; } }
}

__global__ __launch_bounds__(256) void k_scatter(const int* __restrict__ ei, int E,
                                                 int* __restrict__ wpos, int* __restrict__ perm){
  int e = blockIdx.x*256 + threadIdx.x;
  if (e >= E) return;
  int d = ei[(size_t)E + e];
  int pos = atomicAdd(&wpos[d], 1);
  perm[pos] = e;
}

// ---------- pre-gather edge features into dst-sorted bf16 arenas ----------
__global__ __launch_bounds__(256) void k_sortedge(
    const float* __restrict__ es, const float* __restrict__ ev,
    const int* __restrict__ perm,
    u16* __restrict__ esb, u16* __restrict__ evb, int E)
{
  int t = blockIdx.x*256 + threadIdx.x;
  if (t >= E*9) return;
  int pos = t/9, p = t - pos*9;
  int e = perm[pos];
  if (p < 8){
    float4 f = *(const float4*)&es[(size_t)e*32 + 4*p];
    *(short4*)&esb[(size_t)pos*32 + 4*p] = pack4(f);
  } else {
    evb[(size_t)pos*4+0] = f2b(ev[(size_t)e*3+0]);
    evb[(size_t)pos*4+1] = f2b(ev[(size_t)e*3+1]);
    evb[(size_t)pos*4+2] = f2b(ev[(size_t)e*3+2]);
    evb[(size_t)pos*4+3] = 0;
  }
}

// ---------- fused edge kernel: v-path + s-path, dst-sorted, segmented agg ----------
#define EPB 32
__global__ __launch_bounds__(512) void k_edge_fused(
    const u16* __restrict__ node_sb, const u16* __restrict__ node_vb,
    const u16* __restrict__ esb, const u16* __restrict__ evb,
    const int* __restrict__ ei, int E, const int* __restrict__ perm,
    const u16* __restrict__ WB, const u16* __restrict__ WVb,
    const float* __restrict__ b0p, const float* __restrict__ b1p, const float* __restrict__ b2p,
    float* __restrict__ agg_s, float* __restrict__ agg_v)
{
  __shared__ __align__(16) char R1[42240];
  __shared__ __align__(16) u16 VN0[EPB][80];
  __shared__ __align__(16) u16 VN1[EPB][32];
  __shared__ __align__(16) u16 VN2[EPB][32];
  __shared__ int SD[EPB][2];
  u16 (*B0)[104]  = (u16(*)[104])R1;
  u16 (*B1)[104]  = (u16(*)[104])(R1 + 20480);
  float (*SCv)[33] = (float(*)[33])R1;
  u16 (*A)[392]   = (u16(*)[392])R1;
  float (*SC)[132] = (float(*)[132])R1;

  const int tid = threadIdx.x;
  const int w = tid>>6, l = tid&63;
  const int le0 = blockIdx.x*EPB;

  if (tid < EPB){
    int le = le0 + tid;
    int ge = (le<E) ? perm[le] : 0;
    SD[tid][0] = ei[ge];
    SD[tid][1] = ei[(size_t)E + ge];
  }
  __syncthreads();
  for (int u=tid; u<96*16; u+=512){
    int r=u>>4, g=u&15, ee=r/3, d=r-ee*3;
    int le=le0+ee;
    short4 v = {0,0,0,0};
    if (le<E){
      int node = (g<8) ? SD[ee][0] : SD[ee][1];
      v = *(const short4*)&node_vb[(size_t)node*96 + d*32 + 4*(g&7)];
    }
    *(short4*)&B0[r][4*g] = v;
  }
  for (int u=tid; u<96*8; u+=512){
    int r=u>>3, g=u&7, ee=r/3, d=r-ee*3;
    int le=le0+ee;
    short4 v = {0,0,0,0};
    if (g==0 && le<E) v.x = (short)evb[(size_t)le*4 + d];
    *(short4*)&B0[r][64+4*g] = v;
  }
  for (int u=tid; u<96*4; u+=512){
    int r=u>>2, g=u&3;
    *(short4*)&B1[r][80+4*g] = (short4){0,0,0,0};
  }
  __syncthreads();

  auto mm = [&](const u16 (*Ai)[104], int woff, int Kp, int NT, u16 (*C)[104]){
    const int nks = Kp>>5;
    for (int t=w; t<6*NT; t+=8){
      int mt = t % 6, nt = t / 6;
      f32x4 acc = {0.f,0.f,0.f,0.f};
      for (int ks=0; ks<nks; ++ks){
        bf16x8 af = *(const bf16x8*)&Ai[mt*16 + (l&15)][ks*32 + (l>>4)*8];
        bf16x8 bf = *(const bf16x8*)&WVb[woff + (size_t)(nt*16 + (l&15))*Kp + ks*32 + (l>>4)*8];
        acc = __builtin_amdgcn_mfma_f32_16x16x32_bf16(af, bf, acc, 0, 0, 0);
      }
      const int col = nt*16 + (l&15);
      const int r0 = mt*16 + (l>>4)*4;
      C[r0+0][col]=f2b(acc[0]); C[r0+1][col]=f2b(acc[1]);
      C[r0+2][col]=f2b(acc[2]); C[r0+3][col]=f2b(acc[3]);
    }
  };

  // ---- v-path ----
  mm(B0, V_WH0, 96, 5, B1);
  __syncthreads();
  for (int u=tid; u<EPB*80; u+=512){
    int ee=u/80, h=u-ee*80;
    u16 val = 0;
    if (h<65){
      float x0=b2f(B1[ee*3+0][h]), x1=b2f(B1[ee*3+1][h]), x2=b2f(B1[ee*3+2][h]);
      val = f2b(sqrtf(fmaxf(x0*x0+x1*x1+x2*x2, 1e-8f)));
    }
    VN0[ee][h] = val;
  }
  mm(B1, V_WV0, 96, 2, B0);
  __syncthreads();
  for (int u=tid; u<EPB*32; u+=512){
    int ee=u>>5, vo=u&31;
    float x0=b2f(B0[ee*3+0][vo]), x1=b2f(B0[ee*3+1][vo]), x2=b2f(B0[ee*3+2][vo]);
    float nn=sqrtf(fmaxf(x0*x0+x1*x1+x2*x2, 1e-8f));
    float sg=1.f/(1.f+__expf(-nn));
    B0[ee*3+0][vo]=f2b(x0*sg); B0[ee*3+1][vo]=f2b(x1*sg); B0[ee*3+2][vo]=f2b(x2*sg);
  }
  __syncthreads();
  mm(B0, V_WH1, 32, 2, B1);
  __syncthreads();
  for (int u=tid; u<EPB*32; u+=512){
    int ee=u>>5, h=u&31;
    float x0=b2f(B1[ee*3+0][h]), x1=b2f(B1[ee*3+1][h]), x2=b2f(B1[ee*3+2][h]);
    VN1[ee][h] = f2b(sqrtf(fmaxf(x0*x0+x1*x1+x2*x2, 1e-8f)));
  }
  mm(B1, V_WV1, 32, 2, B0);
  __syncthreads();
  for (int u=tid; u<EPB*32; u+=512){
    int ee=u>>5, vo=u&31;
    float x0=b2f(B0[ee*3+0][vo]), x1=b2f(B0[ee*3+1][vo]), x2=b2f(B0[ee*3+2][vo]);
    float nn=sqrtf(fmaxf(x0*x0+x1*x1+x2*x2, 1e-8f));
    float sg=1.f/(1.f+__expf(-nn));
    B0[ee*3+0][vo]=f2b(x0*sg); B0[ee*3+1][vo]=f2b(x1*sg); B0[ee*3+2][vo]=f2b(x2*sg);
  }
  __syncthreads();
  mm(B0, V_WH2, 32, 2, B1);
  __syncthreads();
  for (int u=tid; u<EPB*32; u+=512){
    int ee=u>>5, h=u&31;
    float x0=b2f(B1[ee*3+0][h]), x1=b2f(B1[ee*3+1][h]), x2=b2f(B1[ee*3+2][h]);
    VN2[ee][h] = f2b(sqrtf(fmaxf(x0*x0+x1*x1+x2*x2, 1e-8f)));
  }
  for (int t=w; t<12; t+=8){
    int mt = t % 6, nt = t / 6;
    f32x4 acc = {0.f,0.f,0.f,0.f};
    bf16x8 af = *(const bf16x8*)&B1[mt*16 + (l&15)][(l>>4)*8];
    bf16x8 bf = *(const bf16x8*)&WVb[V_WV2 + (size_t)(nt*16 + (l&15))*32 + (l>>4)*8];
    acc = __builtin_amdgcn_mfma_f32_16x16x32_bf16(af, bf, acc, 0, 0, 0);
    const int vo = nt*16 + (l&15);
    const int r0 = mt*16 + (l>>4)*4;
    #pragma unroll
    for (int j=0;j<4;++j){
      int r = r0 + j;
      int le = le0 + r/3;
      SCv[r][vo] = (le < E) ? acc[j] : 0.f;
    }
  }
  __syncthreads();
  if (tid < 96){
    const int vo = tid & 31, d = tid >> 5;
    float run = 0.f; int prev = -1;
    for (int ee=0; ee<EPB; ++ee){
      int le = le0 + ee;
      int dn = (le<E) ? SD[ee][1] : -1;
      if (dn != prev){
        if (prev >= 0) atomicAdd(&agg_v[(size_t)prev*96 + vo*3 + d], run);
        run = 0.f; prev = dn;
      }
      run += SCv[ee*3+d][vo];
    }
    if (prev >= 0) atomicAdd(&agg_v[(size_t)prev*96 + vo*3 + d], run);
  }
  __syncthreads();

  // ---- s-path staging (linear edge reads) ----
  for (int u=tid; u<EPB*98; u+=512){
    int ee = u/98, g = u - ee*98;
    int le = le0+ee;
    short4 v = {0,0,0,0};
    if (le<E){
      if (g < 32)      v = *(const short4*)&node_sb[(size_t)SD[ee][0]*128 + 4*g];
      else if (g < 40) v = *(const short4*)&esb[(size_t)le*32 + 4*(g-32)];
      else if (g < 72) v = *(const short4*)&node_sb[(size_t)SD[ee][1]*128 + 4*(g-40)];
      else if (g < 92) v = *(const short4*)&VN0[ee][4*(g-72)];
    }
    *(short4*)&A[ee][4*g] = v;
  }
  __syncthreads();

  const int mt = w>>2, nt = w&3;
  const int n_a = nt*32 + (l&15), n_b = n_a + 16;
  const int kq = (l>>4)*8;
  const int ma = mt*16 + (l&15);
  f32x4 ca = {0.f,0.f,0.f,0.f}, cb = {0.f,0.f,0.f,0.f};

  for (int kk=0; kk<384; kk+=32){
    bf16x8 af = *(const bf16x8*)&A[ma][kk + kq];
    bf16x8 b1 = *(const bf16x8*)&WB[WB0 + (size_t)n_a*384 + kk + kq];
    bf16x8 b2 = *(const bf16x8*)&WB[WB0 + (size_t)n_b*384 + kk + kq];
    ca = __builtin_amdgcn_mfma_f32_16x16x32_bf16(af, b1, ca, 0, 0, 0);
    cb = __builtin_amdgcn_mfma_f32_16x16x32_bf16(af, b2, cb, 0, 0, 0);
  }
  __syncthreads();
  {
    float ba = b0p[n_a], bb = b0p[n_b];
    #pragma unroll
    for (int j=0;j<4;++j){
      int r = mt*16 + (l>>4)*4 + j;
      A[r][n_a] = f2b(fmaxf(ca[j] + ba, 0.f));
      A[r][n_b] = f2b(fmaxf(cb[j] + bb, 0.f));
    }
  }
  for (int u=tid; u<EPB*8; u+=512){
    int ee=u>>3, q=u&7;
    *(short4*)&A[ee][128+4*q] = *(const short4*)&VN1[ee][4*q];
  }
  __syncthreads();

  ca = (f32x4){0.f,0.f,0.f,0.f}; cb = (f32x4){0.f,0.f,0.f,0.f};
  for (int kk=0; kk<160; kk+=32){
    bf16x8 af = *(const bf16x8*)&A[ma][kk + kq];
    bf16x8 b1 = *(const bf16x8*)&WB[WB1 + (size_t)n_a*160 + kk + kq];
    bf16x8 b2 = *(const bf16x8*)&WB[WB1 + (size_t)n_b*160 + kk + kq];
    ca = __builtin_amdgcn_mfma_f32_16x16x32_bf16(af, b1, ca, 0, 0, 0);
    cb = __builtin_amdgcn_mfma_f32_16x16x32_bf16(af, b2, cb, 0, 0, 0);
  }
  __syncthreads();
  {
    float ba = b1p[n_a], bb = b1p[n_b];
    #pragma unroll
    for (int j=0;j<4;++j){
      int r = mt*16 + (l>>4)*4 + j;
      A[r][n_a] = f2b(fmaxf(ca[j] + ba, 0.f));
      A[r][n_b] = f2b(fmaxf(cb[j] + bb, 0.f));
    }
  }
  for (int u=tid; u<EPB*8; u+=512){
    int ee=u>>3, q=u&7;
    *(short4*)&A[ee][128+4*q] = *(const short4*)&VN2[ee][4*q];
  }
  __syncthreads();

  ca = (f32x4){0.f,0.f,0.f,0.f}; cb = (f32x4){0.f,0.f,0.f,0.f};
  for (int kk=0; kk<160; kk+=32){
    bf16x8 af = *(const bf16x8*)&A[ma][kk + kq];
    bf16x8 b1 = *(const bf16x8*)&WB[WB2 + (size_t)n_a*160 + kk + kq];
    bf16x8 b2 = *(const bf16x8*)&WB[WB2 + (size_t)n_b*160 + kk + kq];
    ca = __builtin_amdgcn_mfma_f32_16x16x32_bf16(af, b1, ca, 0, 0, 0);
    cb = __builtin_amdgcn_mfma_f32_16x16x32_bf16(af, b2, cb, 0, 0, 0);
  }
  __syncthreads();
  {
    float ba = b2p[n_a], bb = b2p[n_b];
    #pragma unroll
    for (int j=0;j<4;++j){
      int r = mt*16 + (l>>4)*4 + j;
      int le = le0 + r;
      SC[r][n_a] = (le<E) ? (ca[j] + ba) : 0.f;
      SC[r][n_b] = (le<E) ? (cb[j] + bb) : 0.f;
    }
  }
  __syncthreads();
  if (tid < 128){
    const int c = tid;
    float run = 0.f; int prev = -1;
    for (int r=0; r<EPB; ++r){
      int le = le0 + r;
      int dn = (le<E) ? SD[r][1] : -1;
      if (dn != prev){
        if (prev >= 0) atomicAdd(&agg_s[(size_t)prev*128 + c], run);
        run = 0.f; prev = dn;
      }
      run += SC[r][c];
    }
    if (prev >= 0) atomicAdd(&agg_s[(size_t)prev*128 + c], run);
  }
}

// ---------- residual + tuple LayerNorm: 64 nodes/block, 4 threads/node, vectorized ----------
__global__ __launch_bounds__(256) void k_ln0(
    const float* __restrict__ node_s, const float* __restrict__ node_v,
    const float* __restrict__ agg_s, const float* __restrict__ agg_v,
    const float* __restrict__ cnt,
    const float* __restrict__ g, const float* __restrict__ b,
    float* __restrict__ s_mid, float* __restrict__ v_mid, int N)
{
  const int tid = threadIdx.x, q = tid&3;
  const int n = blockIdx.x*64 + (tid>>2);
  const bool live = n < N;
  const float inv = live ? 1.f/fmaxf(cnt[n], 1.f) : 1.f;
  float xs[32];
  float sum=0.f, ss=0.f;
  if (live){
    #pragma unroll
    for (int j=0;j<8;++j){
      float4 a = *(const float4*)&node_s[(size_t)n*128 + q*32 + 4*j];
      float4 c = *(const float4*)&agg_s[(size_t)n*128 + q*32 + 4*j];
      xs[4*j+0]=a.x+c.x*inv; xs[4*j+1]=a.y+c.y*inv; xs[4*j+2]=a.z+c.z*inv; xs[4*j+3]=a.w+c.w*inv;
      sum += xs[4*j+0]+xs[4*j+1]+xs[4*j+2]+xs[4*j+3];
      ss  += xs[4*j+0]*xs[4*j+0]+xs[4*j+1]*xs[4*j+1]+xs[4*j+2]*xs[4*j+2]+xs[4*j+3]*xs[4*j+3];
    }
  }
  sum += __shfl_xor(sum,1); sum += __shfl_xor(sum,2);
  ss  += __shfl_xor(ss,1);  ss  += __shfl_xor(ss,2);
  const float mu = sum*(1.f/128.f);
  const float var = fmaxf(ss*(1.f/128.f) - mu*mu, 0.f);
  const float rstd = rsqrtf(var + 1e-5f);
  if (live){
    #pragma unroll
    for (int j=0;j<8;++j){
      float4 gg = *(const float4*)&g[q*32 + 4*j];
      float4 bb = *(const float4*)&b[q*32 + 4*j];
      float4 o;
      o.x=(xs[4*j+0]-mu)*rstd*gg.x+bb.x; o.y=(xs[4*j+1]-mu)*rstd*gg.y+bb.y;
      o.z=(xs[4*j+2]-mu)*rstd*gg.z+bb.z; o.w=(xs[4*j+3]-mu)*rstd*gg.w+bb.w;
      *(float4*)&s_mid[(size_t)n*128 + q*32 + 4*j] = o;
    }
  }
  float yv[24]; float vs=0.f;
  if (live){
    #pragma unroll
    for (int j=0;j<6;++j){
      float4 a = *(const float4*)&node_v[(size_t)n*96 + q*24 + 4*j];
      float4 c = *(const float4*)&agg_v[(size_t)n*96 + q*24 + 4*j];
      yv[4*j+0]=a.x+c.x*inv; yv[4*j+1]=a.y+c.y*inv; yv[4*j+2]=a.z+c.z*inv; yv[4*j+3]=a.w+c.w*inv;
    }
    #pragma unroll
    for (int vv=0; vv<8; ++vv){
      float z0=yv[3*vv], z1=yv[3*vv+1], z2=yv[3*vv+2];
      vs += fmaxf(z0*z0+z1*z1+z2*z2, 1e-8f);
    }
  }
  vs += __shfl_xor(vs,1); vs += __shfl_xor(vs,2);
  const float scale = rsqrtf(vs*(1.f/32.f));
  if (live){
    #pragma unroll
    for (int vv=0; vv<8; ++vv){
      int vo = q*8 + vv;
      v_mid[(size_t)n*96 + vo]      = yv[3*vv]*scale;   // d-major
      v_mid[(size_t)n*96 + 32 + vo] = yv[3*vv+1]*scale;
      v_mid[(size_t)n*96 + 64 + vo] = yv[3*vv+2]*scale;
    }
  }
}

// ---------- node vector FF (batched MFMA) ----------
__global__ __launch_bounds__(256) void k_node_v(
    const float* __restrict__ v_mid, const u16* __restrict__ WVb,
    u16* __restrict__ vn0f, u16* __restrict__ vn1f, float* __restrict__ fv1, int N)
{
  __shared__ __align__(16) u16 B0[96][104];
  __shared__ __align__(16) u16 B1[96][104];
  const int tid = threadIdx.x;
  const int w = tid>>6, l = tid&63;
  const int n0 = blockIdx.x*32;

  for (int u=tid; u<96*8; u+=256){
    int r=u>>3, g=u&7, nd=r/3, d=r-nd*3;
    int n=n0+nd;
    short4 v = {0,0,0,0};
    if (n<N) v = pack4(*(const float4*)&v_mid[(size_t)n*96 + d*32 + 4*g]);
    *(short4*)&B0[r][4*g] = v;
  }
  __syncthreads();

  auto mm = [&](const u16 (*A)[104], int woff, int Kp, int NT, u16 (*C)[104]){
    const int nks = Kp>>5;
    for (int t=w; t<6*NT; t+=4){
      int mt = t % 6, nt = t / 6;
      f32x4 acc = {0.f,0.f,0.f,0.f};
      for (int ks=0; ks<nks; ++ks){
        bf16x8 af = *(const bf16x8*)&A[mt*16 + (l&15)][ks*32 + (l>>4)*8];
        bf16x8 bf = *(const bf16x8*)&WVb[woff + (size_t)(nt*16 + (l&15))*Kp + ks*32 + (l>>4)*8];
        acc = __builtin_amdgcn_mfma_f32_16x16x32_bf16(af, bf, acc, 0, 0, 0);
      }
      const int col = nt*16 + (l&15);
      const int r0 = mt*16 + (l>>4)*4;
      C[r0+0][col]=f2b(acc[0]); C[r0+1][col]=f2b(acc[1]);
      C[r0+2][col]=f2b(acc[2]); C[r0+3][col]=f2b(acc[3]);
    }
  };

  mm(B0, NV_FF0H, 32, 4, B1);
  __syncthreads();
  for (int u=tid; u<32*64; u+=256){
    int nd=u>>6, h=u&63;
    int n=n0+nd;
    if (n<N){
      float x0=b2f(B1[nd*3+0][h]), x1=b2f(B1[nd*3+1][h]), x2=b2f(B1[nd*3+2][h]);
      vn0f[(size_t)n*64+h] = f2b(sqrtf(fmaxf(x0*x0+x1*x1+x2*x2, 1e-8f)));
    }
  }
  mm(B1, NV_FF0V, 64, 4, B0);
  __syncthreads();
  for (int u=tid; u<32*64; u+=256){
    int nd=u>>6, vo=u&63;
    float x0=b2f(B0[nd*3+0][vo]), x1=b2f(B0[nd*3+1][vo]), x2=b2f(B0[nd*3+2][vo]);
    float nn=sqrtf(fmaxf(x0*x0+x1*x1+x2*x2, 1e-8f));
    float sg=1.f/(1.f+__expf(-nn));
    B0[nd*3+0][vo]=f2b(x0*sg); B0[nd*3+1][vo]=f2b(x1*sg); B0[nd*3+2][vo]=f2b(x2*sg);
  }
  __syncthreads();
  mm(B0, NV_FF1H, 64, 4, B1);
  __syncthreads();
  for (int u=tid; u<32*64; u+=256){
    int nd=u>>6, h=u&63;
    int n=n0+nd;
    if (n<N){
      float x0=b2f(B1[nd*3+0][h]), x1=b2f(B1[nd*3+1][h]), x2=b2f(B1[nd*3+2][h]);
      vn1f[(size_t)n*64+h] = f2b(sqrtf(fmaxf(x0*x0+x1*x1+x2*x2, 1e-8f)));
    }
  }
  for (int t=w; t<12; t+=4){
    int mt = t % 6, nt = t / 6;
    f32x4 acc = {0.f,0.f,0.f,0.f};
    for (int ks=0; ks<2; ++ks){
      bf16x8 af = *(const bf16x8*)&B1[mt*16 + (l&15)][ks*32 + (l>>4)*8];
      bf16x8 bf = *(const bf16x8*)&WVb[NV_FF1V + (size_t)(nt*16 + (l&15))*64 + ks*32 + (l>>4)*8];
      acc = __builtin_amdgcn_mfma_f32_16x16x32_bf16(af, bf, acc, 0, 0, 0);
    }
    const int vo = nt*16 + (l&15);
    const int r0 = mt*16 + (l>>4)*4;
    #pragma unroll
    for (int j=0;j<4;++j){
      int r = r0 + j;
      int nd = r/3, d = r - nd*3;
      int n = n0 + nd;
      if (n < N) fv1[(size_t)n*96 + d*32 + vo] = acc[j];
    }
  }
}

// ---------- node scalar FF (2 MFMA GEMMs) + fused final LN -> d_out ----------
__global__ __launch_bounds__(512) void k_node_s(
    const float* __restrict__ s_mid, const u16* __restrict__ vn0f, const u16* __restrict__ vn1f,
    const float* __restrict__ v_mid, const float* __restrict__ fv1,
    const u16* __restrict__ WB,
    const float* __restrict__ fb0, const float* __restrict__ fb1,
    const float* __restrict__ ln1g, const float* __restrict__ ln1b,
    float* __restrict__ out, int N)
{
  __shared__ __align__(16) char U1[16896];
  __shared__ __align__(16) u16 A2[32][584];
  u16 (*A1)[200] = (u16(*)[200])U1;
  float (*FS)[132] = (float(*)[132])U1;
  const int tid = threadIdx.x;
  const int n0 = blockIdx.x*32;

  for (int u=tid; u<32*48; u+=512){
    int nd = u/48, g = u - nd*48;
    int n = n0+nd;
    short4 v = {0,0,0,0};
    if (n<N){
      if (g < 32) v = pack4(*(const float4*)&s_mid[(size_t)n*128 + 4*g]);
      else        v = *(const short4*)&vn0f[(size_t)n*64 + 4*(g-32)];
    }
    *(short4*)&A1[nd][4*g] = v;
  }
  __syncthreads();

  const int w = tid>>6, l = tid&63;
  const int mt = w>>2, ng = w&3;
  const int kq = (l>>4)*8;
  const int ma = mt*16 + (l&15);
  const int r0 = mt*16 + (l>>4)*4;

  for (int nt2=0; nt2<8; ++nt2){
    const int nt = ng*8 + nt2;
    const int col = nt*16 + (l&15);
    f32x4 acc = {0.f,0.f,0.f,0.f};
    for (int ks=0; ks<6; ++ks){
      bf16x8 af = *(const bf16x8*)&A1[ma][ks*32 + kq];
      bf16x8 bf = *(const bf16x8*)&WB[WBF0 + (size_t)col*192 + ks*32 + kq];
      acc = __builtin_amdgcn_mfma_f32_16x16x32_bf16(af, bf, acc, 0, 0, 0);
    }
    float bias = fb0[col];
    #pragma unroll
    for (int j=0;j<4;++j) A2[r0+j][col] = f2b(fmaxf(acc[j] + bias, 0.f));
  }
  __syncthreads();
  for (int u=tid; u<32*16; u+=512){
    int nd=u>>4, q=u&15;
    int n=n0+nd;
    short4 v = {0,0,0,0};
    if (n<N) v = *(const short4*)&vn1f[(size_t)n*64 + 4*q];
    *(short4*)&A2[nd][512+4*q] = v;
  }
  __syncthreads();

  for (int nt2=0; nt2<2; ++nt2){
    const int nt = ng*2 + nt2;
    const int col = nt*16 + (l&15);
    f32x4 acc = {0.f,0.f,0.f,0.f};
    for (int ks=0; ks<18; ++ks){
      bf16x8 af = *(const bf16x8*)&A2[ma][ks*32 + kq];
      bf16x8 bf = *(const bf16x8*)&WB[WBF1 + (size_t)col*576 + ks*32 + kq];
      acc = __builtin_amdgcn_mfma_f32_16x16x32_bf16(af, bf, acc, 0, 0, 0);
    }
    float bias = fb1[col];
    #pragma unroll
    for (int j=0;j<4;++j) FS[r0+j][col] = acc[j] + bias;
  }
  __syncthreads();

  {
    const int nd = tid>>4, q = tid&15;
    const int n = n0 + nd;
    const bool live = n < N;
    float xs[8], sum=0.f, ss=0.f;
    #pragma unroll
    for (int j=0;j<8;++j){
      int c = q*8 + j;
      float x = 0.f;
      if (live) x = s_mid[(size_t)n*128 + c] + FS[nd][c];
      xs[j] = x; sum += x; ss += x*x;
    }
    #pragma unroll
    for (int m=1; m<16; m<<=1){ sum += __shfl_xor(sum, m); ss += __shfl_xor(ss, m); }
    const float mu = sum*(1.f/128.f);
    const float var = fmaxf(ss*(1.f/128.f) - mu*mu, 0.f);
    const float rstd = rsqrtf(var + 1e-5f);
    if (live){
      #pragma unroll
      for (int j=0;j<8;++j){
        int c = q*8 + j;
        out[(size_t)n*128 + c] = (xs[j]-mu)*rstd*ln1g[c] + ln1b[c];
      }
    }
    float z[2][3]; float vs = 0.f;
    #pragma unroll
    for (int j=0;j<2;++j){
      int vo = q + 16*j;
      #pragma unroll
      for (int d=0;d<3;++d){
        float y = live ? (v_mid[(size_t)n*96 + d*32 + vo] + fv1[(size_t)n*96 + d*32 + vo]) : 0.f;
        z[j][d] = y;
      }
      vs += fmaxf(z[j][0]*z[j][0]+z[j][1]*z[j][1]+z[j][2]*z[j][2], 1e-8f);
    }
    #pragma unroll
    for (int m=1; m<16; m<<=1) vs += __shfl_xor(vs, m);
    const float scale = rsqrtf(vs*(1.f/32.f));
    if (live){
      size_t base = (size_t)N*128 + (size_t)n*96;
      #pragma unroll
      for (int j=0;j<2;++j){
        int vo = q + 16*j;
        out[base + vo*3 + 0] = z[j][0]*scale;
        out[base + vo*3 + 1] = z[j][1]*scale;
        out[base + vo*3 + 2] = z[j][2]*scale;
      }
    }
  }
}

extern "C" void kernel_launch(void* const* d_in, const int* in_sizes, int n_in,
                              void* d_out, int out_size, void* d_ws, size_t ws_size,
                              hipStream_t stream)
{
  (void)n_in; (void)out_size; (void)ws_size;
  const int N = in_sizes[0]/128;
  const int E = in_sizes[4]/2;
  const int* ei = (const int*)d_in[4];

  size_t off = 0;
  auto alloc = [&](size_t bytes)->char*{
    size_t o = (off + 255) & ~(size_t)255;
    off = o + bytes;
    return (char*)d_ws + o;
  };
  u16*   WB      = (u16*)alloc((size_t)WB_TOTAL*2);
  u16*   WVb     = (u16*)alloc((size_t)WV_TOTAL*2);
  float* agg_s   = (float*)alloc((size_t)N*128*4);
  float* agg_v   = (float*)alloc((size_t)N*96*4);
  float* cnt     = (float*)alloc((size_t)N*4);
  size_t aggBytes = (size_t)((char*)(cnt+N) - (char*)agg_s);
  float* s_mid   = (float*)alloc((size_t)N*128*4);
  float* v_mid   = (float*)alloc((size_t)N*96*4);
  u16*   node_sb = (u16*)alloc((size_t)N*128*2);
  u16*   node_vb = (u16*)alloc((size_t)N*96*2);
  u16*   vn0f    = (u16*)alloc((size_t)N*64*2);
  u16*   vn1f    = (u16*)alloc((size_t)N*64*2);
  float* fv1     = (float*)alloc((size_t)N*96*4);
  int*   wpos    = (int*)alloc((size_t)N*4);
  int*   perm    = (int*)alloc((size_t)E*4);
  u16*   esb     = (u16*)alloc((size_t)E*32*2);
  u16*   evb     = (u16*)alloc((size_t)E*4*2);

  hipMemsetAsync(agg_s, 0, aggBytes, stream);
  k_wb<<<dim3((WB_TOTAL+255)/256), dim3(256), 0, stream>>>(
      (const float*)d_in[6], (const float*)d_in[10], (const float*)d_in[14],
      (const float*)d_in[20], (const float*)d_in[24], WB);
  k_wv<<<dim3((WV_TOTAL+255)/256), dim3(256), 0, stream>>>(
      (const float*)d_in[5], (const float*)d_in[8], (const float*)d_in[9],
      (const float*)d_in[12], (const float*)d_in[13], (const float*)d_in[16],
      (const float*)d_in[19], (const float*)d_in[22], (const float*)d_in[23],
      (const float*)d_in[26], WVb);
  k_prep<<<dim3((N*224+255)/256), dim3(256), 0, stream>>>(
      (const float*)d_in[0], (const float*)d_in[1], node_sb, node_vb, N);
  k_hist<<<dim3((E+255)/256), dim3(256), 0, stream>>>(ei, E, cnt);
  k_scan<<<dim3(1), dim3(256), 0, stream>>>(cnt, wpos, N);
  k_scatter<<<dim3((E+255)/256), dim3(256), 0, stream>>>(ei, E, wpos, perm);
  k_sortedge<<<dim3(((size_t)E*9+255)/256), dim3(256), 0, stream>>>(
      (const float*)d_in[2], (const float*)d_in[3], perm, esb, evb, E);

  k_edge_fused<<<dim3((E+EPB-1)/EPB), dim3(512), 0, stream>>>(
      node_sb, node_vb, esb, evb, ei, E, perm, WB, WVb,
      (const float*)d_in[7], (const float*)d_in[11], (const float*)d_in[15],
      agg_s, agg_v);

  k_ln0<<<dim3((N+63)/64), dim3(256), 0, stream>>>(
      (const float*)d_in[0], (const float*)d_in[1], agg_s, agg_v, cnt,
      (const float*)d_in[17], (const float*)d_in[18], s_mid, v_mid, N);

  k_node_v<<<dim3((N+31)/32), dim3(256), 0, stream>>>(v_mid, WVb, vn0f, vn1f, fv1, N);
  k_node_s<<<dim3((N+31)/32), dim3(512), 0, stream>>>(
      s_mid, vn0f, vn1f, v_mid, fv1, WB,
      (const float*)d_in[21], (const float*)d_in[25],
      (const float*)d_in[27], (const float*)d_in[28],
      (float*)d_out, N);
}

// Round 15
// 504.884 us; speedup vs baseline: 81.6801x; 1.0372x over previous
//
#include <hip/hip_runtime.h>

typedef unsigned short u16;
typedef __attribute__((ext_vector_type(8))) short bf16x8;
typedef __attribute__((ext_vector_type(4))) float f32x4;

__device__ __forceinline__ float b2f(u16 h){ return __uint_as_float(((unsigned)h)<<16); }
__device__ __forceinline__ u16 f2b(float f){
  unsigned u = __float_as_uint(f);
  unsigned r = ((u>>16)&1u) + 0x7fffu;
  return (u16)((u+r)>>16);
}
__device__ __forceinline__ short4 pack4(float4 f){
  short4 s; s.x=(short)f2b(f.x); s.y=(short)f2b(f.y); s.z=(short)f2b(f.z); s.w=(short)f2b(f.w);
  return s;
}

// WB bf16 arena: s-path weights, [O][K] layout
#define WB0   0        // [128][384]
#define WB1   49152    // [128][160]
#define WB2   69632    // [128][160]
#define WBF0  90112    // [512][192]
#define WBF1  188416   // [128][576]
#define WB_TOTAL 262144

// WVb bf16 arena: v-path weights, [N_pad][K_pad]
#define V_WH0   0
#define V_WV0   7680
#define V_WH1   10752
#define V_WV1   11776
#define V_WH2   12800
#define V_WV2   13824
#define NV_FF0H 14848
#define NV_FF0V 16896
#define NV_FF1H 20992
#define NV_FF1V 25088
#define WV_TOTAL 27136

__global__ __launch_bounds__(256) void k_wb(const float* __restrict__ w0,
    const float* __restrict__ w1, const float* __restrict__ w2,
    const float* __restrict__ f0, const float* __restrict__ f1,
    u16* __restrict__ WB){
  int t = blockIdx.x*256 + threadIdx.x;
  if (t < 49152){
    int o = t/384, k = t - o*384;
    WB[WB0 + t] = f2b(k < 353 ? w0[(size_t)o*353 + k] : 0.f);
    return;
  }
  t -= 49152;
  if (t < 20480){ WB[WB1 + t] = f2b(w1[t]); return; }
  t -= 20480;
  if (t < 20480){ WB[WB2 + t] = f2b(w2[t]); return; }
  t -= 20480;
  if (t < 98304){ WB[WBF0 + t] = f2b(f0[t]); return; }
  t -= 98304;
  if (t < 73728){ WB[WBF1 + t] = f2b(f1[t]); return; }
}

__global__ __launch_bounds__(256) void k_wv(const float* __restrict__ wh0, const float* __restrict__ wv0,
    const float* __restrict__ wh1, const float* __restrict__ wv1,
    const float* __restrict__ wh2, const float* __restrict__ wv2,
    const float* __restrict__ nf0h, const float* __restrict__ nf0v,
    const float* __restrict__ nf1h, const float* __restrict__ nf1v,
    u16* __restrict__ WVb){
  int t = blockIdx.x*256 + threadIdx.x;
  if (t < 7680){
    int n=t/96, k=t-n*96;
    float v = 0.f;
    if (n < 65){
      if (k < 32)       v = wh0[(size_t)n*65 + k];
      else if (k < 64)  v = wh0[(size_t)n*65 + 33 + (k-32)];
      else if (k == 64) v = wh0[(size_t)n*65 + 32];
    }
    WVb[V_WH0+t] = f2b(v);
    return;
  }
  t -= 7680;
  if (t < 3072){
    int n=t/96, k=t-n*96;
    WVb[V_WV0+t] = f2b((k<65) ? wv0[(size_t)n*65+k] : 0.f);
    return;
  }
  t -= 3072;
  if (t < 1024){ WVb[V_WH1+t]=f2b(wh1[t]); return; }
  t -= 1024;
  if (t < 1024){ WVb[V_WV1+t]=f2b(wv1[t]); return; }
  t -= 1024;
  if (t < 1024){ WVb[V_WH2+t]=f2b(wh2[t]); return; }
  t -= 1024;
  if (t < 1024){ WVb[V_WV2+t]=f2b(wv2[t]); return; }
  t -= 1024;
  if (t < 2048){ WVb[NV_FF0H+t]=f2b(nf0h[t]); return; }
  t -= 2048;
  if (t < 4096){ WVb[NV_FF0V+t]=f2b(nf0v[t]); return; }
  t -= 4096;
  if (t < 4096){ WVb[NV_FF1H+t]=f2b(nf1h[t]); return; }
  t -= 4096;
  if (t < 2048){ WVb[NV_FF1V+t]=f2b(nf1v[t]); return; }
}

// prep: node_s -> bf16; node_v -> bf16 d-major; edge_s -> bf16 (linear)
__global__ __launch_bounds__(256) void k_prep(const float* __restrict__ node_s,
    const float* __restrict__ node_v, const float* __restrict__ edge_s,
    u16* __restrict__ node_sb, u16* __restrict__ node_vb, u16* __restrict__ esb_lin,
    int N, int E){
  int t = blockIdx.x*256 + threadIdx.x;
  if (t < N*128){ node_sb[t] = f2b(node_s[t]); return; }
  t -= N*128;
  if (t < N*96){
    int n=t/96, r=t-n*96, d=r>>5, vo=r&31;
    node_vb[(size_t)n*96 + d*32 + vo] = f2b(node_v[(size_t)n*96 + vo*3 + d]);
    return;
  }
  t -= N*96;
  if (t < E*32){ esb_lin[t] = f2b(edge_s[t]); return; }
}

__global__ __launch_bounds__(256) void k_hist(const int* __restrict__ ei, int E,
                                              float* __restrict__ cnt){
  int e = blockIdx.x*256 + threadIdx.x;
  if (e < E) atomicAdd(&cnt[ei[(size_t)E + e]], 1.f);
}

__global__ __launch_bounds__(256) void k_scan(const float* __restrict__ cnt,
                                              int* __restrict__ wpos, int N){
  __shared__ int part[256];
  const int tid = threadIdx.x;
  const int per = (N + 255)/256;
  const int base = tid*per;
  int s = 0;
  for (int i=0;i<per;++i){ int n=base+i; if (n<N) s += (int)cnt[n]; }
  part[tid] = s; __syncthreads();
  for (int st=1; st<256; st<<=1){
    int v = (tid>=st) ? part[tid-st] : 0;
    __syncthreads();
    part[tid] += v;
    __syncthreads();
  }
  int run = part[tid] - s;
  for (int i=0;i<per;++i){ int n=base+i; if (n<N){ wpos[n]=run; run += (int)cnt[n]; } }
}

__global__ __launch_bounds__(256) void k_scatter(const int* __restrict__ ei, int E,
                                                 int* __restrict__ wpos, int* __restrict__ perm){
  int e = blockIdx.x*256 + threadIdx.x;
  if (e >= E) return;
  int d = ei[(size_t)E + e];
  int pos = atomicAdd(&wpos[d], 1);
  perm[pos] = e;
}

// pre-gather edge features into dst-sorted bf16 arenas (bf16 source for es)
__global__ __launch_bounds__(256) void k_sortedge(
    const u16* __restrict__ esb_lin, const float* __restrict__ ev,
    const int* __restrict__ perm,
    u16* __restrict__ esb, u16* __restrict__ evb, int E)
{
  int t = blockIdx.x*256 + threadIdx.x;
  if (t >= E*9) return;
  int pos = t/9, p = t - pos*9;
  int e = perm[pos];
  if (p < 8){
    *(short4*)&esb[(size_t)pos*32 + 4*p] = *(const short4*)&esb_lin[(size_t)e*32 + 4*p];
  } else {
    evb[(size_t)pos*4+0] = f2b(ev[(size_t)e*3+0]);
    evb[(size_t)pos*4+1] = f2b(ev[(size_t)e*3+1]);
    evb[(size_t)pos*4+2] = f2b(ev[(size_t)e*3+2]);
    evb[(size_t)pos*4+3] = 0;
  }
}

// ---------- fused edge kernel: v-path + s-path, T14 prefetch, parallel seg-reduce ----------
#define EPB 32
__global__ __launch_bounds__(512) void k_edge_fused(
    const u16* __restrict__ node_sb, const u16* __restrict__ node_vb,
    const u16* __restrict__ esb, const u16* __restrict__ evb,
    const int* __restrict__ ei, int E, const int* __restrict__ perm,
    const u16* __restrict__ WB, const u16* __restrict__ WVb,
    const float* __restrict__ b0p, const float* __restrict__ b1p, const float* __restrict__ b2p,
    float* __restrict__ agg_s, float* __restrict__ agg_v)
{
  __shared__ __align__(16) char R1[42240];
  __shared__ __align__(16) u16 VN0[EPB][80];
  __shared__ __align__(16) u16 VN1[EPB][32];
  __shared__ __align__(16) u16 VN2[EPB][32];
  __shared__ int SD[EPB][2];
  u16 (*B0)[104]  = (u16(*)[104])R1;
  u16 (*B1)[104]  = (u16(*)[104])(R1 + 20480);
  float (*SCv)[33] = (float(*)[33])R1;
  u16 (*A)[392]   = (u16(*)[392])R1;
  float (*SC)[132] = (float(*)[132])R1;

  const int tid = threadIdx.x;
  const int w = tid>>6, l = tid&63;
  const int le0 = blockIdx.x*EPB;

  if (tid < EPB){
    int le = le0 + tid;
    int ge = (le<E) ? perm[le] : 0;
    SD[tid][0] = ei[ge];
    SD[tid][1] = ei[(size_t)E + ge];
  }
  __syncthreads();

  // T14 prefetch: issue s-path gathers into registers NOW; LDS-write after v-path.
  short4 pre0={0,0,0,0}, pre1={0,0,0,0}, pre2={0,0,0,0}, pre3={0,0,0,0}, pre4={0,0,0,0};
  {
    auto ld = [&](int u)->short4{
      short4 v = {0,0,0,0};
      if (u < EPB*72){
        int ee = u/72, g = u - ee*72;
        int le = le0+ee;
        if (le<E){
          if (g < 32)      v = *(const short4*)&node_sb[(size_t)SD[ee][0]*128 + 4*g];
          else if (g < 40) v = *(const short4*)&esb[(size_t)le*32 + 4*(g-32)];
          else             v = *(const short4*)&node_sb[(size_t)SD[ee][1]*128 + 4*(g-40)];
        }
      }
      return v;
    };
    pre0 = ld(tid);          pre1 = ld(tid + 512);
    pre2 = ld(tid + 1024);   pre3 = ld(tid + 1536);
    pre4 = ld(tid + 2048);
  }

  // v-path staging
  for (int u=tid; u<96*16; u+=512){
    int r=u>>4, g=u&15, ee=r/3, d=r-ee*3;
    int le=le0+ee;
    short4 v = {0,0,0,0};
    if (le<E){
      int node = (g<8) ? SD[ee][0] : SD[ee][1];
      v = *(const short4*)&node_vb[(size_t)node*96 + d*32 + 4*(g&7)];
    }
    *(short4*)&B0[r][4*g] = v;
  }
  for (int u=tid; u<96*8; u+=512){
    int r=u>>3, g=u&7, ee=r/3, d=r-ee*3;
    int le=le0+ee;
    short4 v = {0,0,0,0};
    if (g==0 && le<E) v.x = (short)evb[(size_t)le*4 + d];
    *(short4*)&B0[r][64+4*g] = v;
  }
  for (int u=tid; u<96*4; u+=512){
    int r=u>>2, g=u&3;
    *(short4*)&B1[r][80+4*g] = (short4){0,0,0,0};
  }
  __syncthreads();

  auto mm = [&](const u16 (*Ai)[104], int woff, int Kp, int NT, u16 (*C)[104]){
    const int nks = Kp>>5;
    for (int t=w; t<6*NT; t+=8){
      int mt = t % 6, nt = t / 6;
      f32x4 acc = {0.f,0.f,0.f,0.f};
      for (int ks=0; ks<nks; ++ks){
        bf16x8 af = *(const bf16x8*)&Ai[mt*16 + (l&15)][ks*32 + (l>>4)*8];
        bf16x8 bf = *(const bf16x8*)&WVb[woff + (size_t)(nt*16 + (l&15))*Kp + ks*32 + (l>>4)*8];
        acc = __builtin_amdgcn_mfma_f32_16x16x32_bf16(af, bf, acc, 0, 0, 0);
      }
      const int col = nt*16 + (l&15);
      const int r0 = mt*16 + (l>>4)*4;
      C[r0+0][col]=f2b(acc[0]); C[r0+1][col]=f2b(acc[1]);
      C[r0+2][col]=f2b(acc[2]); C[r0+3][col]=f2b(acc[3]);
    }
  };

  // ---- v-path ----
  mm(B0, V_WH0, 96, 5, B1);
  __syncthreads();
  for (int u=tid; u<EPB*80; u+=512){
    int ee=u/80, h=u-ee*80;
    u16 val = 0;
    if (h<65){
      float x0=b2f(B1[ee*3+0][h]), x1=b2f(B1[ee*3+1][h]), x2=b2f(B1[ee*3+2][h]);
      val = f2b(sqrtf(fmaxf(x0*x0+x1*x1+x2*x2, 1e-8f)));
    }
    VN0[ee][h] = val;
  }
  mm(B1, V_WV0, 96, 2, B0);
  __syncthreads();
  for (int u=tid; u<EPB*32; u+=512){
    int ee=u>>5, vo=u&31;
    float x0=b2f(B0[ee*3+0][vo]), x1=b2f(B0[ee*3+1][vo]), x2=b2f(B0[ee*3+2][vo]);
    float nn=sqrtf(fmaxf(x0*x0+x1*x1+x2*x2, 1e-8f));
    float sg=1.f/(1.f+__expf(-nn));
    B0[ee*3+0][vo]=f2b(x0*sg); B0[ee*3+1][vo]=f2b(x1*sg); B0[ee*3+2][vo]=f2b(x2*sg);
  }
  __syncthreads();
  mm(B0, V_WH1, 32, 2, B1);
  __syncthreads();
  for (int u=tid; u<EPB*32; u+=512){
    int ee=u>>5, h=u&31;
    float x0=b2f(B1[ee*3+0][h]), x1=b2f(B1[ee*3+1][h]), x2=b2f(B1[ee*3+2][h]);
    VN1[ee][h] = f2b(sqrtf(fmaxf(x0*x0+x1*x1+x2*x2, 1e-8f)));
  }
  mm(B1, V_WV1, 32, 2, B0);
  __syncthreads();
  for (int u=tid; u<EPB*32; u+=512){
    int ee=u>>5, vo=u&31;
    float x0=b2f(B0[ee*3+0][vo]), x1=b2f(B0[ee*3+1][vo]), x2=b2f(B0[ee*3+2][vo]);
    float nn=sqrtf(fmaxf(x0*x0+x1*x1+x2*x2, 1e-8f));
    float sg=1.f/(1.f+__expf(-nn));
    B0[ee*3+0][vo]=f2b(x0*sg); B0[ee*3+1][vo]=f2b(x1*sg); B0[ee*3+2][vo]=f2b(x2*sg);
  }
  __syncthreads();
  mm(B0, V_WH2, 32, 2, B1);
  __syncthreads();
  for (int u=tid; u<EPB*32; u+=512){
    int ee=u>>5, h=u&31;
    float x0=b2f(B1[ee*3+0][h]), x1=b2f(B1[ee*3+1][h]), x2=b2f(B1[ee*3+2][h]);
    VN2[ee][h] = f2b(sqrtf(fmaxf(x0*x0+x1*x1+x2*x2, 1e-8f)));
  }
  for (int t=w; t<12; t+=8){
    int mt = t % 6, nt = t / 6;
    f32x4 acc = {0.f,0.f,0.f,0.f};
    bf16x8 af = *(const bf16x8*)&B1[mt*16 + (l&15)][(l>>4)*8];
    bf16x8 bf = *(const bf16x8*)&WVb[V_WV2 + (size_t)(nt*16 + (l&15))*32 + (l>>4)*8];
    acc = __builtin_amdgcn_mfma_f32_16x16x32_bf16(af, bf, acc, 0, 0, 0);
    const int vo = nt*16 + (l&15);
    const int r0 = mt*16 + (l>>4)*4;
    #pragma unroll
    for (int j=0;j<4;++j){
      int r = r0 + j;
      int le = le0 + r/3;
      SCv[r][vo] = (le < E) ? acc[j] : 0.f;
    }
  }
  __syncthreads();
  // parallel segmented reduction (4 row-parts x 96 (vo,d))
  if (tid < 384){
    const int part = tid / 96, vd = tid - part*96;
    const int vo = vd & 31, d = vd >> 5;
    float run = 0.f; int prev = -1;
    for (int ee=part*8; ee<part*8+8; ++ee){
      int le = le0 + ee;
      int dn = (le<E) ? SD[ee][1] : -1;
      if (dn != prev){
        if (prev >= 0) atomicAdd(&agg_v[(size_t)prev*96 + vo*3 + d], run);
        run = 0.f; prev = dn;
      }
      run += SCv[ee*3+d][vo];
    }
    if (prev >= 0) atomicAdd(&agg_v[(size_t)prev*96 + vo*3 + d], run);
  }
  __syncthreads();

  // ---- s-path staging: write prefetched registers + VN0 ----
  {
    auto st = [&](int u, short4 v){
      if (u < EPB*72){
        int ee = u/72, g = u - ee*72;
        *(short4*)&A[ee][4*g] = v;
      }
    };
    st(tid, pre0); st(tid+512, pre1); st(tid+1024, pre2); st(tid+1536, pre3); st(tid+2048, pre4);
  }
  for (int u=tid; u<EPB*26; u+=512){
    int ee = u/26, g = 72 + (u - ee*26);
    short4 v = {0,0,0,0};
    if (g < 92) v = *(const short4*)&VN0[ee][4*(g-72)];
    *(short4*)&A[ee][4*g] = v;
  }
  __syncthreads();

  const int mt = w>>2, nt = w&3;
  const int n_a = nt*32 + (l&15), n_b = n_a + 16;
  const int kq = (l>>4)*8;
  const int ma = mt*16 + (l&15);
  f32x4 ca = {0.f,0.f,0.f,0.f}, cb = {0.f,0.f,0.f,0.f};

  for (int kk=0; kk<384; kk+=32){
    bf16x8 af = *(const bf16x8*)&A[ma][kk + kq];
    bf16x8 b1 = *(const bf16x8*)&WB[WB0 + (size_t)n_a*384 + kk + kq];
    bf16x8 b2 = *(const bf16x8*)&WB[WB0 + (size_t)n_b*384 + kk + kq];
    ca = __builtin_amdgcn_mfma_f32_16x16x32_bf16(af, b1, ca, 0, 0, 0);
    cb = __builtin_amdgcn_mfma_f32_16x16x32_bf16(af, b2, cb, 0, 0, 0);
  }
  __syncthreads();
  {
    float ba = b0p[n_a], bb = b0p[n_b];
    #pragma unroll
    for (int j=0;j<4;++j){
      int r = mt*16 + (l>>4)*4 + j;
      A[r][n_a] = f2b(fmaxf(ca[j] + ba, 0.f));
      A[r][n_b] = f2b(fmaxf(cb[j] + bb, 0.f));
    }
  }
  for (int u=tid; u<EPB*8; u+=512){
    int ee=u>>3, q=u&7;
    *(short4*)&A[ee][128+4*q] = *(const short4*)&VN1[ee][4*q];
  }
  __syncthreads();

  ca = (f32x4){0.f,0.f,0.f,0.f}; cb = (f32x4){0.f,0.f,0.f,0.f};
  for (int kk=0; kk<160; kk+=32){
    bf16x8 af = *(const bf16x8*)&A[ma][kk + kq];
    bf16x8 b1 = *(const bf16x8*)&WB[WB1 + (size_t)n_a*160 + kk + kq];
    bf16x8 b2 = *(const bf16x8*)&WB[WB1 + (size_t)n_b*160 + kk + kq];
    ca = __builtin_amdgcn_mfma_f32_16x16x32_bf16(af, b1, ca, 0, 0, 0);
    cb = __builtin_amdgcn_mfma_f32_16x16x32_bf16(af, b2, cb, 0, 0, 0);
  }
  __syncthreads();
  {
    float ba = b1p[n_a], bb = b1p[n_b];
    #pragma unroll
    for (int j=0;j<4;++j){
      int r = mt*16 + (l>>4)*4 + j;
      A[r][n_a] = f2b(fmaxf(ca[j] + ba, 0.f));
      A[r][n_b] = f2b(fmaxf(cb[j] + bb, 0.f));
    }
  }
  for (int u=tid; u<EPB*8; u+=512){
    int ee=u>>3, q=u&7;
    *(short4*)&A[ee][128+4*q] = *(const short4*)&VN2[ee][4*q];
  }
  __syncthreads();

  ca = (f32x4){0.f,0.f,0.f,0.f}; cb = (f32x4){0.f,0.f,0.f,0.f};
  for (int kk=0; kk<160; kk+=32){
    bf16x8 af = *(const bf16x8*)&A[ma][kk + kq];
    bf16x8 b1 = *(const bf16x8*)&WB[WB2 + (size_t)n_a*160 + kk + kq];
    bf16x8 b2 = *(const bf16x8*)&WB[WB2 + (size_t)n_b*160 + kk + kq];
    ca = __builtin_amdgcn_mfma_f32_16x16x32_bf16(af, b1, ca, 0, 0, 0);
    cb = __builtin_amdgcn_mfma_f32_16x16x32_bf16(af, b2, cb, 0, 0, 0);
  }
  __syncthreads();
  {
    float ba = b2p[n_a], bb = b2p[n_b];
    #pragma unroll
    for (int j=0;j<4;++j){
      int r = mt*16 + (l>>4)*4 + j;
      int le = le0 + r;
      SC[r][n_a] = (le<E) ? (ca[j] + ba) : 0.f;
      SC[r][n_b] = (le<E) ? (cb[j] + bb) : 0.f;
    }
  }
  __syncthreads();
  // parallel segmented reduction (4 row-parts x 128 cols)
  {
    const int part = tid >> 7, c = tid & 127;
    float run = 0.f; int prev = -1;
    for (int r=part*8; r<part*8+8; ++r){
      int le = le0 + r;
      int dn = (le<E) ? SD[r][1] : -1;
      if (dn != prev){
        if (prev >= 0) atomicAdd(&agg_s[(size_t)prev*128 + c], run);
        run = 0.f; prev = dn;
      }
      run += SC[r][c];
    }
    if (prev >= 0) atomicAdd(&agg_s[(size_t)prev*128 + c], run);
  }
}

// ---------- residual + tuple LayerNorm: 64 nodes/block, 4 threads/node ----------
__global__ __launch_bounds__(256) void k_ln0(
    const float* __restrict__ node_s, const float* __restrict__ node_v,
    const float* __restrict__ agg_s, const float* __restrict__ agg_v,
    const float* __restrict__ cnt,
    const float* __restrict__ g, const float* __restrict__ b,
    float* __restrict__ s_mid, float* __restrict__ v_mid, int N)
{
  const int tid = threadIdx.x, q = tid&3;
  const int n = blockIdx.x*64 + (tid>>2);
  const bool live = n < N;
  const float inv = live ? 1.f/fmaxf(cnt[n], 1.f) : 1.f;
  float xs[32];
  float sum=0.f, ss=0.f;
  if (live){
    #pragma unroll
    for (int j=0;j<8;++j){
      float4 a = *(const float4*)&node_s[(size_t)n*128 + q*32 + 4*j];
      float4 c = *(const float4*)&agg_s[(size_t)n*128 + q*32 + 4*j];
      xs[4*j+0]=a.x+c.x*inv; xs[4*j+1]=a.y+c.y*inv; xs[4*j+2]=a.z+c.z*inv; xs[4*j+3]=a.w+c.w*inv;
      sum += xs[4*j+0]+xs[4*j+1]+xs[4*j+2]+xs[4*j+3];
      ss  += xs[4*j+0]*xs[4*j+0]+xs[4*j+1]*xs[4*j+1]+xs[4*j+2]*xs[4*j+2]+xs[4*j+3]*xs[4*j+3];
    }
  }
  sum += __shfl_xor(sum,1); sum += __shfl_xor(sum,2);
  ss  += __shfl_xor(ss,1);  ss  += __shfl_xor(ss,2);
  const float mu = sum*(1.f/128.f);
  const float var = fmaxf(ss*(1.f/128.f) - mu*mu, 0.f);
  const float rstd = rsqrtf(var + 1e-5f);
  if (live){
    #pragma unroll
    for (int j=0;j<8;++j){
      float4 gg = *(const float4*)&g[q*32 + 4*j];
      float4 bb = *(const float4*)&b[q*32 + 4*j];
      float4 o;
      o.x=(xs[4*j+0]-mu)*rstd*gg.x+bb.x; o.y=(xs[4*j+1]-mu)*rstd*gg.y+bb.y;
      o.z=(xs[4*j+2]-mu)*rstd*gg.z+bb.z; o.w=(xs[4*j+3]-mu)*rstd*gg.w+bb.w;
      *(float4*)&s_mid[(size_t)n*128 + q*32 + 4*j] = o;
    }
  }
  float yv[24]; float vs=0.f;
  if (live){
    #pragma unroll
    for (int j=0;j<6;++j){
      float4 a = *(const float4*)&node_v[(size_t)n*96 + q*24 + 4*j];
      float4 c = *(const float4*)&agg_v[(size_t)n*96 + q*24 + 4*j];
      yv[4*j+0]=a.x+c.x*inv; yv[4*j+1]=a.y+c.y*inv; yv[4*j+2]=a.z+c.z*inv; yv[4*j+3]=a.w+c.w*inv;
    }
    #pragma unroll
    for (int vv=0; vv<8; ++vv){
      float z0=yv[3*vv], z1=yv[3*vv+1], z2=yv[3*vv+2];
      vs += fmaxf(z0*z0+z1*z1+z2*z2, 1e-8f);
    }
  }
  vs += __shfl_xor(vs,1); vs += __shfl_xor(vs,2);
  const float scale = rsqrtf(vs*(1.f/32.f));
  if (live){
    #pragma unroll
    for (int vv=0; vv<8; ++vv){
      int vo = q*8 + vv;
      v_mid[(size_t)n*96 + vo]      = yv[3*vv]*scale;
      v_mid[(size_t)n*96 + 32 + vo] = yv[3*vv+1]*scale;
      v_mid[(size_t)n*96 + 64 + vo] = yv[3*vv+2]*scale;
    }
  }
}

// ---------- node vector FF (batched MFMA) ----------
__global__ __launch_bounds__(256) void k_node_v(
    const float* __restrict__ v_mid, const u16* __restrict__ WVb,
    u16* __restrict__ vn0f, u16* __restrict__ vn1f, float* __restrict__ fv1, int N)
{
  __shared__ __align__(16) u16 B0[96][104];
  __shared__ __align__(16) u16 B1[96][104];
  const int tid = threadIdx.x;
  const int w = tid>>6, l = tid&63;
  const int n0 = blockIdx.x*32;

  for (int u=tid; u<96*8; u+=256){
    int r=u>>3, g=u&7, nd=r/3, d=r-nd*3;
    int n=n0+nd;
    short4 v = {0,0,0,0};
    if (n<N) v = pack4(*(const float4*)&v_mid[(size_t)n*96 + d*32 + 4*g]);
    *(short4*)&B0[r][4*g] = v;
  }
  __syncthreads();

  auto mm = [&](const u16 (*A)[104], int woff, int Kp, int NT, u16 (*C)[104]){
    const int nks = Kp>>5;
    for (int t=w; t<6*NT; t+=4){
      int mt = t % 6, nt = t / 6;
      f32x4 acc = {0.f,0.f,0.f,0.f};
      for (int ks=0; ks<nks; ++ks){
        bf16x8 af = *(const bf16x8*)&A[mt*16 + (l&15)][ks*32 + (l>>4)*8];
        bf16x8 bf = *(const bf16x8*)&WVb[woff + (size_t)(nt*16 + (l&15))*Kp + ks*32 + (l>>4)*8];
        acc = __builtin_amdgcn_mfma_f32_16x16x32_bf16(af, bf, acc, 0, 0, 0);
      }
      const int col = nt*16 + (l&15);
      const int r0 = mt*16 + (l>>4)*4;
      C[r0+0][col]=f2b(acc[0]); C[r0+1][col]=f2b(acc[1]);
      C[r0+2][col]=f2b(acc[2]); C[r0+3][col]=f2b(acc[3]);
    }
  };

  mm(B0, NV_FF0H, 32, 4, B1);
  __syncthreads();
  for (int u=tid; u<32*64; u+=256){
    int nd=u>>6, h=u&63;
    int n=n0+nd;
    if (n<N){
      float x0=b2f(B1[nd*3+0][h]), x1=b2f(B1[nd*3+1][h]), x2=b2f(B1[nd*3+2][h]);
      vn0f[(size_t)n*64+h] = f2b(sqrtf(fmaxf(x0*x0+x1*x1+x2*x2, 1e-8f)));
    }
  }
  mm(B1, NV_FF0V, 64, 4, B0);
  __syncthreads();
  for (int u=tid; u<32*64; u+=256){
    int nd=u>>6, vo=u&63;
    float x0=b2f(B0[nd*3+0][vo]), x1=b2f(B0[nd*3+1][vo]), x2=b2f(B0[nd*3+2][vo]);
    float nn=sqrtf(fmaxf(x0*x0+x1*x1+x2*x2, 1e-8f));
    float sg=1.f/(1.f+__expf(-nn));
    B0[nd*3+0][vo]=f2b(x0*sg); B0[nd*3+1][vo]=f2b(x1*sg); B0[nd*3+2][vo]=f2b(x2*sg);
  }
  __syncthreads();
  mm(B0, NV_FF1H, 64, 4, B1);
  __syncthreads();
  for (int u=tid; u<32*64; u+=256){
    int nd=u>>6, h=u&63;
    int n=n0+nd;
    if (n<N){
      float x0=b2f(B1[nd*3+0][h]), x1=b2f(B1[nd*3+1][h]), x2=b2f(B1[nd*3+2][h]);
      vn1f[(size_t)n*64+h] = f2b(sqrtf(fmaxf(x0*x0+x1*x1+x2*x2, 1e-8f)));
    }
  }
  for (int t=w; t<12; t+=4){
    int mt = t % 6, nt = t / 6;
    f32x4 acc = {0.f,0.f,0.f,0.f};
    for (int ks=0; ks<2; ++ks){
      bf16x8 af = *(const bf16x8*)&B1[mt*16 + (l&15)][ks*32 + (l>>4)*8];
      bf16x8 bf = *(const bf16x8*)&WVb[NV_FF1V + (size_t)(nt*16 + (l&15))*64 + ks*32 + (l>>4)*8];
      acc = __builtin_amdgcn_mfma_f32_16x16x32_bf16(af, bf, acc, 0, 0, 0);
    }
    const int vo = nt*16 + (l&15);
    const int r0 = mt*16 + (l>>4)*4;
    #pragma unroll
    for (int j=0;j<4;++j){
      int r = r0 + j;
      int nd = r/3, d = r - nd*3;
      int n = n0 + nd;
      if (n < N) fv1[(size_t)n*96 + d*32 + vo] = acc[j];
    }
  }
}

// ---------- node scalar FF (2 MFMA GEMMs) + fused final LN -> d_out ----------
__global__ __launch_bounds__(512) void k_node_s(
    const float* __restrict__ s_mid, const u16* __restrict__ vn0f, const u16* __restrict__ vn1f,
    const float* __restrict__ v_mid, const float* __restrict__ fv1,
    const u16* __restrict__ WB,
    const float* __restrict__ fb0, const float* __restrict__ fb1,
    const float* __restrict__ ln1g, const float* __restrict__ ln1b,
    float* __restrict__ out, int N)
{
  __shared__ __align__(16) char U1[16896];
  __shared__ __align__(16) u16 A2[32][584];
  u16 (*A1)[200] = (u16(*)[200])U1;
  float (*FS)[132] = (float(*)[132])U1;
  const int tid = threadIdx.x;
  const int n0 = blockIdx.x*32;

  for (int u=tid; u<32*48; u+=512){
    int nd = u/48, g = u - nd*48;
    int n = n0+nd;
    short4 v = {0,0,0,0};
    if (n<N){
      if (g < 32) v = pack4(*(const float4*)&s_mid[(size_t)n*128 + 4*g]);
      else        v = *(const short4*)&vn0f[(size_t)n*64 + 4*(g-32)];
    }
    *(short4*)&A1[nd][4*g] = v;
  }
  __syncthreads();

  const int w = tid>>6, l = tid&63;
  const int mt = w>>2, ng = w&3;
  const int kq = (l>>4)*8;
  const int ma = mt*16 + (l&15);
  const int r0 = mt*16 + (l>>4)*4;

  for (int nt2=0; nt2<8; ++nt2){
    const int nt = ng*8 + nt2;
    const int col = nt*16 + (l&15);
    f32x4 acc = {0.f,0.f,0.f,0.f};
    for (int ks=0; ks<6; ++ks){
      bf16x8 af = *(const bf16x8*)&A1[ma][ks*32 + kq];
      bf16x8 bf = *(const bf16x8*)&WB[WBF0 + (size_t)col*192 + ks*32 + kq];
      acc = __builtin_amdgcn_mfma_f32_16x16x32_bf16(af, bf, acc, 0, 0, 0);
    }
    float bias = fb0[col];
    #pragma unroll
    for (int j=0;j<4;++j) A2[r0+j][col] = f2b(fmaxf(acc[j] + bias, 0.f));
  }
  __syncthreads();
  for (int u=tid; u<32*16; u+=512){
    int nd=u>>4, q=u&15;
    int n=n0+nd;
    short4 v = {0,0,0,0};
    if (n<N) v = *(const short4*)&vn1f[(size_t)n*64 + 4*q];
    *(short4*)&A2[nd][512+4*q] = v;
  }
  __syncthreads();

  for (int nt2=0; nt2<2; ++nt2){
    const int nt = ng*2 + nt2;
    const int col = nt*16 + (l&15);
    f32x4 acc = {0.f,0.f,0.f,0.f};
    for (int ks=0; ks<18; ++ks){
      bf16x8 af = *(const bf16x8*)&A2[ma][ks*32 + kq];
      bf16x8 bf = *(const bf16x8*)&WB[WBF1 + (size_t)col*576 + ks*32 + kq];
      acc = __builtin_amdgcn_mfma_f32_16x16x32_bf16(af, bf, acc, 0, 0, 0);
    }
    float bias = fb1[col];
    #pragma unroll
    for (int j=0;j<4;++j) FS[r0+j][col] = acc[j] + bias;
  }
  __syncthreads();

  {
    const int nd = tid>>4, q = tid&15;
    const int n = n0 + nd;
    const bool live = n < N;
    float xs[8], sum=0.f, ss=0.f;
    #pragma unroll
    for (int j=0;j<8;++j){
      int c = q*8 + j;
      float x = 0.f;
      if (live) x = s_mid[(size_t)n*128 + c] + FS[nd][c];
      xs[j] = x; sum += x; ss += x*x;
    }
    #pragma unroll
    for (int m=1; m<16; m<<=1){ sum += __shfl_xor(sum, m); ss += __shfl_xor(ss, m); }
    const float mu = sum*(1.f/128.f);
    const float var = fmaxf(ss*(1.f/128.f) - mu*mu, 0.f);
    const float rstd = rsqrtf(var + 1e-5f);
    if (live){
      #pragma unroll
      for (int j=0;j<8;++j){
        int c = q*8 + j;
        out[(size_t)n*128 + c] = (xs[j]-mu)*rstd*ln1g[c] + ln1b[c];
      }
    }
    float z[2][3]; float vs = 0.f;
    #pragma unroll
    for (int j=0;j<2;++j){
      int vo = q + 16*j;
      #pragma unroll
      for (int d=0;d<3;++d){
        float y = live ? (v_mid[(size_t)n*96 + d*32 + vo] + fv1[(size_t)n*96 + d*32 + vo]) : 0.f;
        z[j][d] = y;
      }
      vs += fmaxf(z[j][0]*z[j][0]+z[j][1]*z[j][1]+z[j][2]*z[j][2], 1e-8f);
    }
    #pragma unroll
    for (int m=1; m<16; m<<=1) vs += __shfl_xor(vs, m);
    const float scale = rsqrtf(vs*(1.f/32.f));
    if (live){
      size_t base = (size_t)N*128 + (size_t)n*96;
      #pragma unroll
      for (int j=0;j<2;++j){
        int vo = q + 16*j;
        out[base + vo*3 + 0] = z[j][0]*scale;
        out[base + vo*3 + 1] = z[j][1]*scale;
        out[base + vo*3 + 2] = z[j][2]*scale;
      }
    }
  }
}

extern "C" void kernel_launch(void* const* d_in, const int* in_sizes, int n_in,
                              void* d_out, int out_size, void* d_ws, size_t ws_size,
                              hipStream_t stream)
{
  (void)n_in; (void)out_size; (void)ws_size;
  const int N = in_sizes[0]/128;
  const int E = in_sizes[4]/2;
  const int* ei = (const int*)d_in[4];

  size_t off = 0;
  auto alloc = [&](size_t bytes)->char*{
    size_t o = (off + 255) & ~(size_t)255;
    off = o + bytes;
    return (char*)d_ws + o;
  };
  u16*   WB      = (u16*)alloc((size_t)WB_TOTAL*2);
  u16*   WVb     = (u16*)alloc((size_t)WV_TOTAL*2);
  float* agg_s   = (float*)alloc((size_t)N*128*4);
  float* agg_v   = (float*)alloc((size_t)N*96*4);
  float* cnt     = (float*)alloc((size_t)N*4);
  size_t aggBytes = (size_t)((char*)(cnt+N) - (char*)agg_s);
  float* s_mid   = (float*)alloc((size_t)N*128*4);
  float* v_mid   = (float*)alloc((size_t)N*96*4);
  u16*   node_sb = (u16*)alloc((size_t)N*128*2);
  u16*   node_vb = (u16*)alloc((size_t)N*96*2);
  u16*   vn0f    = (u16*)alloc((size_t)N*64*2);
  u16*   vn1f    = (u16*)alloc((size_t)N*64*2);
  float* fv1     = (float*)alloc((size_t)N*96*4);
  int*   wpos    = (int*)alloc((size_t)N*4);
  int*   perm    = (int*)alloc((size_t)E*4);
  u16*   esb_lin = (u16*)alloc((size_t)E*32*2);
  u16*   esb     = (u16*)alloc((size_t)E*32*2);
  u16*   evb     = (u16*)alloc((size_t)E*4*2);

  hipMemsetAsync(agg_s, 0, aggBytes, stream);
  k_wb<<<dim3((WB_TOTAL+255)/256), dim3(256), 0, stream>>>(
      (const float*)d_in[6], (const float*)d_in[10], (const float*)d_in[14],
      (const float*)d_in[20], (const float*)d_in[24], WB);
  k_wv<<<dim3((WV_TOTAL+255)/256), dim3(256), 0, stream>>>(
      (const float*)d_in[5], (const float*)d_in[8], (const float*)d_in[9],
      (const float*)d_in[12], (const float*)d_in[13], (const float*)d_in[16],
      (const float*)d_in[19], (const float*)d_in[22], (const float*)d_in[23],
      (const float*)d_in[26], WVb);
  k_prep<<<dim3(((size_t)N*224 + (size_t)E*32 + 255)/256), dim3(256), 0, stream>>>(
      (const float*)d_in[0], (const float*)d_in[1], (const float*)d_in[2],
      node_sb, node_vb, esb_lin, N, E);
  k_hist<<<dim3((E+255)/256), dim3(256), 0, stream>>>(ei, E, cnt);
  k_scan<<<dim3(1), dim3(256), 0, stream>>>(cnt, wpos, N);
  k_scatter<<<dim3((E+255)/256), dim3(256), 0, stream>>>(ei, E, wpos, perm);
  k_sortedge<<<dim3(((size_t)E*9+255)/256), dim3(256), 0, stream>>>(
      esb_lin, (const float*)d_in[3], perm, esb, evb, E);

  k_edge_fused<<<dim3((E+EPB-1)/EPB), dim3(512), 0, stream>>>(
      node_sb, node_vb, esb, evb, ei, E, perm, WB, WVb,
      (const float*)d_in[7], (const float*)d_in[11], (const float*)d_in[15],
      agg_s, agg_v);

  k_ln0<<<dim3((N+63)/64), dim3(256), 0, stream>>>(
      (const float*)d_in[0], (const float*)d_in[1], agg_s, agg_v, cnt,
      (const float*)d_in[17], (const float*)d_in[18], s_mid, v_mid, N);

  k_node_v<<<dim3((N+31)/32), dim3(256), 0, stream>>>(v_mid, WVb, vn0f, vn1f, fv1, N);
  k_node_s<<<dim3((N+31)/32), dim3(512), 0, stream>>>(
      s_mid, vn0f, vn1f, v_mid, fv1, WB,
      (const float*)d_in[21], (const float*)d_in[25],
      (const float*)d_in[27], (const float*)d_in[28],
      (float*)d_out, N);
}